// Round 4
// baseline (994.020 us; speedup 1.0000x reference)
//
#include <hip/hip_runtime.h>
#include <hip/hip_bf16.h>
#include <cstdint>
#include <cstddef>

// ---------------------------------------------------------------------------
// Problem constants
// ---------------------------------------------------------------------------
#define NB      128
#define RR      300
#define EMB     32
#define CENC    33

typedef __bf16 bf16x8 __attribute__((ext_vector_type(8)));
typedef float  f32x4  __attribute__((ext_vector_type(4)));
typedef unsigned short ushort8 __attribute__((ext_vector_type(8)));

__device__ __forceinline__ unsigned short f2bf(float f) {
    union { __hip_bfloat16 h; unsigned short u; } c;
    c.h = __float2bfloat16(f);
    return c.u;
}
__device__ __forceinline__ float bf2f(unsigned short u) {
    union { __hip_bfloat16 h; unsigned short u; } c;
    c.u = u;
    return __bfloat162float(c.h);
}

// ---------------------------------------------------------------------------
// 1) Pack room occupancy maps into uint64 bitmasks (bit b = dx*8+dy)
// ---------------------------------------------------------------------------
__global__ __launch_bounds__(256) void build_masks_k(
    const int* __restrict__ rm, unsigned long long* __restrict__ masks)
{
    int r = blockIdx.x * 256 + threadIdx.x;
    if (r >= RR) return;
    unsigned long long m = 0ull;
    #pragma unroll
    for (int b = 0; b < 64; ++b)
        if (rm[r * 64 + b]) m |= (1ull << b);
    masks[r] = m;
}

// ---------------------------------------------------------------------------
// 2) Zero-fill (uint4 grid-stride)
// ---------------------------------------------------------------------------
__global__ __launch_bounds__(256) void fillz_k(uint4* __restrict__ p, size_t n16)
{
    uint4 z = make_uint4(0, 0, 0, 0);
    for (size_t i = blockIdx.x * 256ull + threadIdx.x; i < n16;
         i += (size_t)gridDim.x * 256ull)
        p[i] = z;
}

// ---------------------------------------------------------------------------
// 3) Encode: scatter rooms into padded bf16 G[nl][c][76][76] (interior +2)
// ---------------------------------------------------------------------------
__global__ __launch_bounds__(256) void encode_k(
    const int* __restrict__ X, const unsigned long long* __restrict__ masks,
    const float* __restrict__ emb, unsigned short* __restrict__ G,
    int n0, int sampleStride)
{
    __shared__ float tile[72 * 72];
    const int nl = blockIdx.x;
    const int n  = n0 + nl;
    const int c  = blockIdx.y;

    for (int i = threadIdx.x; i < 72 * 72; i += 256) tile[i] = 0.0f;
    __syncthreads();

    const int2* Xp = reinterpret_cast<const int2*>(X);
    for (int r = threadIdx.x; r < RR; r += 256) {
        int2 pos = Xp[n * RR + r];
        float s = (c == 0) ? 1.0f : emb[r * EMB + (c - 1)];
        unsigned long long m = masks[r];
        if (s != 0.0f) {
            while (m) {
                int b = __builtin_ctzll(m);
                m &= (m - 1);
                int dx = b >> 3, dy = b & 7;
                atomicAdd(&tile[(pos.y + dy) * 72 + (pos.x + dx)], s);
            }
        }
    }
    __syncthreads();

    unsigned short* Gn = G + (size_t)nl * sampleStride + (size_t)c * (76 * 76);
    for (int i = threadIdx.x; i < 72 * 72; i += 256) {
        int y = i / 72, x = i % 72;
        Gn[(y + 2) * 76 + (x + 2)] = f2bf(tile[i]);
    }
}

// ---------------------------------------------------------------------------
// 4) Weight pack: fp32 w[oc][k] -> bf16 wPT[kb][oc][32], K padded w/ zeros
// ---------------------------------------------------------------------------
__global__ __launch_bounds__(256) void wpack_k(
    const float* __restrict__ w, unsigned short* __restrict__ wPT,
    int COUT, int Ktot, int total)
{
    int idx = blockIdx.x * 256 + threadIdx.x;
    if (idx >= total) return;
    int kk = idx & 31;
    int t  = idx >> 5;
    int oc = t % COUT;
    int kb = t / COUT;
    int k  = kb * 32 + kk;
    wPT[idx] = f2bf(k < Ktot ? w[(size_t)oc * Ktot + k] : 0.0f);
}

// ---------------------------------------------------------------------------
// 5) ktab: flat padded-input offset per k-index (k = ci*K*K + ky*K + kx)
// ---------------------------------------------------------------------------
__global__ __launch_bounds__(256) void ktab_k(
    int* __restrict__ kt, int Ktot, int Kpad, int K, int Wp, int HpWp)
{
    int k = blockIdx.x * 256 + threadIdx.x;
    if (k >= Kpad) return;
    int v = 0;
    if (k < Ktot) {
        int KK = K * K;
        int ci = k / KK;
        int r  = k - ci * KK;
        int ky = r / K;
        int kx = r - ky * K;
        v = ci * HpWp + ky * Wp + kx;
    }
    kt[k] = v;
}

// ---------------------------------------------------------------------------
// 6) Implicit-GEMM conv + bias + ReLU, bf16 MFMA 16x16x32.
//    NO LDS, NO barriers: each lane loads its A fragment (8 u16 gathers via
//    ktab) and B fragments (coalesced 16B of packed weights) directly from
//    global into registers. 256 threads = 4 waves; wave wv covers m rows
//    [wv*16, wv*16+16) of each 64-row m-fragment; NG*16 ocs per block.
// ---------------------------------------------------------------------------
template<int MFRAG, int NG>
__global__ __launch_bounds__(256) void conv_mfma_k(
    const unsigned short* __restrict__ inP,   // [B][CIN][Hp][Wp] bf16, halo=0
    const unsigned short* __restrict__ wPT,   // [ksteps][COUT][32] bf16
    const int* __restrict__ ktab,             // [ksteps*32]
    const float* __restrict__ bias,
    unsigned short* __restrict__ out,         // [B][COUT][Mpad] bf16
    int W, int Wp, int Mtot, int Mpad,
    int inSS, int outSS, int ksteps, int COUT)
{
    const int tid  = threadIdx.x;
    const int mb   = blockIdx.x;
    const int ocb  = blockIdx.y;
    const int nl   = blockIdx.z;

    const int lane = tid & 63;
    const int wv   = tid >> 6;
    const int frow = lane & 15;
    const int fq   = lane >> 4;          // 0..3
    constexpr int Mblk = MFRAG * 64;

    const unsigned short* in_n = inP + (size_t)nl * inSS;

    // per-m-fragment base pointers (clamped at tail; stores are guarded)
    const unsigned short* ab[MFRAG];
    #pragma unroll
    for (int mf = 0; mf < MFRAG; ++mf) {
        int p  = mb * Mblk + mf * 64 + wv * 16 + frow;
        int pc = p < Mtot ? p : (Mtot - 1);
        int y  = pc / W;
        int x  = pc - y * W;
        ab[mf] = in_n + y * Wp + x;
    }

    const int4* ktp = reinterpret_cast<const int4*>(ktab);
    // weight fragment base: oc row = ocb*NG*16 + ng*16 + frow, k chunk fq*8
    const unsigned short* wbase =
        wPT + ((size_t)(ocb * NG * 16 + frow)) * 32 + fq * 8;

    f32x4 acc[MFRAG][NG];
    #pragma unroll
    for (int mf = 0; mf < MFRAG; ++mf)
        #pragma unroll
        for (int ng = 0; ng < NG; ++ng)
            acc[mf][ng] = (f32x4){0.f, 0.f, 0.f, 0.f};

    for (int kb = 0; kb < ksteps; ++kb) {
        int4 k0 = ktp[kb * 8 + fq * 2];
        int4 k1 = ktp[kb * 8 + fq * 2 + 1];

        bf16x8 af[MFRAG];
        #pragma unroll
        for (int mf = 0; mf < MFRAG; ++mf) {
            const unsigned short* ap = ab[mf];
            union { ushort8 u; bf16x8 b; } cv;
            cv.u[0] = ap[k0.x]; cv.u[1] = ap[k0.y];
            cv.u[2] = ap[k0.z]; cv.u[3] = ap[k0.w];
            cv.u[4] = ap[k1.x]; cv.u[5] = ap[k1.y];
            cv.u[6] = ap[k1.z]; cv.u[7] = ap[k1.w];
            af[mf] = cv.b;
        }

        const unsigned short* wk = wbase + (size_t)kb * COUT * 32;
        #pragma unroll
        for (int ng = 0; ng < NG; ++ng) {
            union { ushort8 u; bf16x8 b; } wc;
            wc.u = *reinterpret_cast<const ushort8*>(wk + ng * 16 * 32);
            #pragma unroll
            for (int mf = 0; mf < MFRAG; ++mf)
                acc[mf][ng] = __builtin_amdgcn_mfma_f32_16x16x32_bf16(
                    af[mf], wc.b, acc[mf][ng], 0, 0, 0);
        }
    }

    // epilogue: bias + ReLU, direct packed stores from C layout.
    // D row (m within 16-tile) = fq*4 + reg  -> 4 consecutive m per lane.
    unsigned short* out_n = out + (size_t)nl * outSS;
    #pragma unroll
    for (int mf = 0; mf < MFRAG; ++mf) {
        int m0 = mb * Mblk + mf * 64 + wv * 16 + fq * 4;
        #pragma unroll
        for (int ng = 0; ng < NG; ++ng) {
            int oc = ocb * NG * 16 + ng * 16 + frow;
            float bv = bias[oc];
            unsigned short r[4];
            #pragma unroll
            for (int j = 0; j < 4; ++j)
                r[j] = f2bf(fmaxf(acc[mf][ng][j] + bv, 0.0f));
            unsigned short* op = out_n + (size_t)oc * Mpad + m0;
            if (m0 + 3 < Mtot) {
                uint2 pk;
                pk.x = (unsigned)r[0] | ((unsigned)r[1] << 16);
                pk.y = (unsigned)r[2] | ((unsigned)r[3] << 16);
                *reinterpret_cast<uint2*>(op) = pk;
            } else {
                #pragma unroll
                for (int j = 0; j < 4; ++j)
                    if (m0 + j < Mtot) op[j] = r[j];
            }
        }
    }
}

// ---------------------------------------------------------------------------
// 7) MaxPool 3x3 stride 2 (VALID), bf16 in/out, writes padded interior
// ---------------------------------------------------------------------------
__global__ __launch_bounds__(256) void maxpool_bf_k(
    const unsigned short* __restrict__ in, unsigned short* __restrict__ out,
    int C, int H, int W, int chS, int inSS,
    int HO, int WO, int Wpo, int po, int outChS, int outSS, int total)
{
    int idx = blockIdx.x * 256 + threadIdx.x;
    if (idx >= total) return;
    int x = idx % WO;
    int t = idx / WO;
    int y = t % HO;
    t /= HO;
    int c  = t % C;
    int nl = t / C;
    const unsigned short* p =
        in + (size_t)nl * inSS + (size_t)c * chS + (y * 2) * W + x * 2;
    float m = -3.402823466e38f;
    #pragma unroll
    for (int dy = 0; dy < 3; ++dy)
        #pragma unroll
        for (int dx = 0; dx < 3; ++dx)
            m = fmaxf(m, bf2f(p[dy * W + dx]));
    out[(size_t)nl * outSS + (size_t)c * outChS + (y + po) * Wpo + (x + po)] =
        f2bf(m);
}

// ---------------------------------------------------------------------------
// 8) Global average pool over 8x8 (bf16 in -> fp32 out)
// ---------------------------------------------------------------------------
__global__ __launch_bounds__(256) void gap_bf_k(
    const unsigned short* __restrict__ in, float* __restrict__ out,
    int inSS, int total)
{
    int idx = blockIdx.x * 256 + threadIdx.x;
    if (idx >= total) return;
    int c  = idx & 255;
    int nl = idx >> 8;
    const unsigned short* p = in + (size_t)nl * inSS + (size_t)c * 64;
    float s = 0.0f;
    #pragma unroll
    for (int i = 0; i < 64; ++i) s += bf2f(p[i]);
    out[idx] = s * (1.0f / 64.0f);
}

// ---------------------------------------------------------------------------
// 9) FC (fp32): out[n][o] = dot(in[n], w[o]) + b[o], optional ReLU
// ---------------------------------------------------------------------------
template<int CIN, bool RELU>
__global__ __launch_bounds__(256) void fc_k(
    const float* __restrict__ in, const float* __restrict__ w,
    const float* __restrict__ b, float* __restrict__ out, int COUT)
{
    __shared__ float s_in[CIN];
    const int n = blockIdx.x;
    for (int i = threadIdx.x; i < CIN; i += 256) s_in[i] = in[(size_t)n * CIN + i];
    __syncthreads();

    const int o = blockIdx.y * 64 + (threadIdx.x >> 2);
    const int l = threadIdx.x & 3;
    const float* wr = w + (size_t)o * CIN;
    float acc = 0.0f;
    #pragma unroll 4
    for (int i = l; i < CIN; i += 4) acc += s_in[i] * wr[i];
    acc += __shfl_xor(acc, 1);
    acc += __shfl_xor(acc, 2);
    if (l == 0) {
        float v = acc + b[o];
        out[(size_t)n * COUT + o] = RELU ? fmaxf(v, 0.0f) : v;
    }
}

// ---------------------------------------------------------------------------
// Launch
// Per-sample bf16 buffer sizes (ushorts):
//   A: G 33*76*76=190,608  (C1 128*1228=157,184 and P2 256*64=16,384 overlay)
//   B: C0 64*5184=331,776  (C2 256*292=74,752 overlays)
//   C: P0p 64*37*37=87,616 + P1p 128*19*19=46,208 = 133,824 (disjoint)
// ---------------------------------------------------------------------------
extern "C" void kernel_launch(void* const* d_in, const int* in_sizes, int n_in,
                              void* d_out, int out_size, void* d_ws, size_t ws_size,
                              hipStream_t stream)
{
    const int*   X   = (const int*)d_in[0];
    const int*   rm  = (const int*)d_in[1];
    const float* emb = (const float*)d_in[2];
    const float* cw0 = (const float*)d_in[3];
    const float* cb0 = (const float*)d_in[4];
    const float* cw1 = (const float*)d_in[5];
    const float* cb1 = (const float*)d_in[6];
    const float* cw2 = (const float*)d_in[7];
    const float* cb2 = (const float*)d_in[8];
    const float* fw0 = (const float*)d_in[9];
    const float* fb0 = (const float*)d_in[10];
    const float* fw1 = (const float*)d_in[11];
    const float* fb1 = (const float*)d_in[12];
    const float* fw2 = (const float*)d_in[13];
    const float* fb2 = (const float*)d_in[14];
    float* out = (float*)d_out;

    char* p = (char*)d_ws;
    auto alloc = [&](size_t bytes) -> char* {
        char* r = p; p += (bytes + 255) & ~(size_t)255; return r;
    };
    // conv K-dims: 33*25=825 -> 26 steps; 64*9=576 -> 18; 128*9=1152 -> 36
    unsigned short* WP0 = (unsigned short*)alloc((size_t)26 * 64 * 32 * 2);
    unsigned short* WP1 = (unsigned short*)alloc((size_t)18 * 128 * 32 * 2);
    unsigned short* WP2 = (unsigned short*)alloc((size_t)36 * 256 * 32 * 2);
    int* KT0 = (int*)alloc(26 * 32 * 4);
    int* KT1 = (int*)alloc(18 * 32 * 4);
    int* KT2 = (int*)alloc(36 * 32 * 4);
    unsigned long long* MASKS = (unsigned long long*)alloc(RR * 8);
    float* GAPB = (float*)alloc((size_t)NB * 256 * 4);
    float* F0   = (float*)alloc((size_t)NB * 512 * 4);
    float* F1   = (float*)alloc((size_t)NB * 256 * 4);
    size_t fixed_bytes = (size_t)(p - (char*)d_ws);

    const size_t A_FL = 190608, B_FL = 331776, C_FL = 133824;   // ushorts
    const size_t per_sample = (A_FL + B_FL + C_FL) * 2 + 3 * 256;
    int Bc = 32;
    while (Bc > 1 && fixed_bytes + (size_t)Bc * per_sample > ws_size) Bc >>= 1;

    unsigned short* bufA = (unsigned short*)alloc((size_t)Bc * A_FL * 2);
    unsigned short* bufB = (unsigned short*)alloc((size_t)Bc * B_FL * 2);
    unsigned short* bufC = (unsigned short*)alloc((size_t)Bc * C_FL * 2);

    // ---- one-time prep ----
    build_masks_k<<<2, 256, 0, stream>>>(rm, MASKS);
    wpack_k<<<(26 * 64 * 32 + 255) / 256, 256, 0, stream>>>(cw0, WP0, 64, 825, 26 * 64 * 32);
    wpack_k<<<(18 * 128 * 32 + 255) / 256, 256, 0, stream>>>(cw1, WP1, 128, 576, 18 * 128 * 32);
    wpack_k<<<(36 * 256 * 32 + 255) / 256, 256, 0, stream>>>(cw2, WP2, 256, 1152, 36 * 256 * 32);
    ktab_k<<<(26 * 32 + 255) / 256, 256, 0, stream>>>(KT0, 825, 26 * 32, 5, 76, 76 * 76);
    ktab_k<<<(18 * 32 + 255) / 256, 256, 0, stream>>>(KT1, 576, 18 * 32, 3, 37, 37 * 37);
    ktab_k<<<(36 * 32 + 255) / 256, 256, 0, stream>>>(KT2, 1152, 36 * 32, 3, 19, 19 * 19);

    // ---- chunked pipeline ----
    for (int n0 = 0; n0 < NB; n0 += Bc) {
        // zero padded buffers (halos)
        fillz_k<<<1024, 256, 0, stream>>>((uint4*)bufA, (size_t)Bc * A_FL * 2 / 16);
        fillz_k<<<1024, 256, 0, stream>>>((uint4*)bufC, (size_t)Bc * C_FL * 2 / 16);

        // encode -> A (G: Bc x 33 x 76 x 76, interior +2)
        encode_k<<<dim3(Bc, CENC), 256, 0, stream>>>(X, MASKS, emb, bufA, n0, (int)A_FL);

        // conv0: A -> B   (M=5184, Mblk=128 -> 41 mblocks, NG=4, COUT=64)
        conv_mfma_k<2, 4><<<dim3(41, 1, Bc), 256, 0, stream>>>(
            bufA, WP0, KT0, cb0, bufB, 72, 76, 5184, 5184,
            (int)A_FL, (int)B_FL, 26, 64);
        // pool0: B -> C(P0p @ +1, pitch 37)
        maxpool_bf_k<<<(Bc * 64 * 35 * 35 + 255) / 256, 256, 0, stream>>>(
            bufB, bufC, 64, 72, 72, 5184, (int)B_FL,
            35, 35, 37, 1, 37 * 37, (int)C_FL, Bc * 64 * 35 * 35);

        // conv1: C -> A   (M=1225, Mblk=64 -> 20 mblocks, NG=8, COUT=128)
        conv_mfma_k<1, 8><<<dim3(20, 1, Bc), 256, 0, stream>>>(
            bufC, WP1, KT1, cb1, bufA, 35, 37, 1225, 1228,
            (int)C_FL, (int)A_FL, 18, 128);
        // pool1: A -> C(P1p @ offset 87616, +1, pitch 19)
        maxpool_bf_k<<<(Bc * 128 * 17 * 17 + 255) / 256, 256, 0, stream>>>(
            bufA, bufC + 87616, 128, 35, 35, 1228, (int)A_FL,
            17, 17, 19, 1, 19 * 19, (int)C_FL, Bc * 128 * 17 * 17);

        // conv2: C -> B   (M=289, Mblk=64 -> 5 mblocks, NG=4, 4 oc-blocks)
        conv_mfma_k<1, 4><<<dim3(5, 4, Bc), 256, 0, stream>>>(
            bufC + 87616, WP2, KT2, cb2, bufB, 17, 19, 289, 292,
            (int)C_FL, (int)B_FL, 36, 256);
        // pool2: B -> A (P2: 256 x 8 x 8, unpadded)
        maxpool_bf_k<<<(Bc * 256 * 8 * 8 + 255) / 256, 256, 0, stream>>>(
            bufB, bufA, 256, 17, 17, 292, (int)B_FL,
            8, 8, 8, 0, 64, (int)A_FL, Bc * 256 * 8 * 8);

        // GAP: A -> GAPB[n0*256..]
        gap_bf_k<<<(Bc * 256 + 255) / 256, 256, 0, stream>>>(
            bufA, GAPB + (size_t)n0 * 256, (int)A_FL, Bc * 256);
    }

    // ---- FC stack (fp32) ----
    fc_k<256, true><<<dim3(NB, 8), 256, 0, stream>>>(GAPB, fw0, fb0, F0, 512);
    fc_k<512, true><<<dim3(NB, 4), 256, 0, stream>>>(F0, fw1, fb1, F1, 256);
    fc_k<256, false><<<dim3(NB, 8), 256, 0, stream>>>(F1, fw2, fb2, out, 512);
}

// Round 5
// 786.226 us; speedup vs baseline: 1.2643x; 1.2643x over previous
//
#include <hip/hip_runtime.h>
#include <hip/hip_bf16.h>
#include <cstdint>
#include <cstddef>

#define NB      128
#define RR      300
#define EMB     32

typedef __bf16 bf16x8 __attribute__((ext_vector_type(8)));
typedef float  f32x4  __attribute__((ext_vector_type(4)));
typedef unsigned short ushort8 __attribute__((ext_vector_type(8)));

__device__ __forceinline__ unsigned short f2bf(float f) {
    union { __hip_bfloat16 h; unsigned short u; } c;
    c.h = __float2bfloat16(f);
    return c.u;
}
__device__ __forceinline__ float bf2f(unsigned short u) {
    union { __hip_bfloat16 h; unsigned short u; } c;
    c.u = u;
    return __bfloat162float(c.h);
}

// ---------------------------------------------------------------------------
// 1) Room occupancy -> uint64 bitmask (bit b = dx*8+dy)
// ---------------------------------------------------------------------------
__global__ __launch_bounds__(256) void build_masks_k(
    const int* __restrict__ rm, unsigned long long* __restrict__ masks)
{
    int r = blockIdx.x * 256 + threadIdx.x;
    if (r >= RR) return;
    unsigned long long m = 0ull;
    #pragma unroll
    for (int b = 0; b < 64; ++b)
        if (rm[r * 64 + b]) m |= (1ull << b);
    masks[r] = m;
}

// ---------------------------------------------------------------------------
// 2) Zero-fill (uint4 grid-stride)
// ---------------------------------------------------------------------------
__global__ __launch_bounds__(256) void fillz_k(uint4* __restrict__ p, size_t n16)
{
    uint4 z = make_uint4(0, 0, 0, 0);
    for (size_t i = blockIdx.x * 256ull + threadIdx.x; i < n16;
         i += (size_t)gridDim.x * 256ull)
        p[i] = z;
}

// ---------------------------------------------------------------------------
// 3) Encode, banded HWC: block = (sample, 4-row band). LDS fp32 [4][72][33],
//    atomics within band, coalesced bf16 HWC write to G[76][76][40] (+2 halo).
// ---------------------------------------------------------------------------
__global__ __launch_bounds__(320) void encode_k(
    const int* __restrict__ X, const unsigned long long* __restrict__ masks,
    const float* __restrict__ emb, unsigned short* __restrict__ G,
    int n0, int sampleStride)
{
    __shared__ float tile[4][72][33];
    const int nl = blockIdx.x, band = blockIdx.y;
    const int by = band * 4;
    const int n  = n0 + nl;
    const int tid = threadIdx.x;

    float* tf = &tile[0][0][0];
    for (int i = tid; i < 4 * 72 * 33; i += 320) tf[i] = 0.0f;
    __syncthreads();

    const int dx = tid / 33;
    const int c  = tid - dx * 33;
    const int2* Xp = reinterpret_cast<const int2*>(X);

    for (int r = 0; r < RR; ++r) {
        int2 pos = Xp[n * RR + r];
        int y0 = pos.y;
        if (y0 > by + 3 || y0 + 7 < by) continue;   // block-uniform skip
        if (tid < 264) {
            float s = (c == 0) ? 1.0f : emb[r * EMB + (c - 1)];
            unsigned long long m = masks[r] >> (dx * 8);
            int x = pos.x + dx;
            #pragma unroll
            for (int dyb = 0; dyb < 4; ++dyb) {
                int dyr = by + dyb - y0;
                if ((unsigned)dyr < 8u && ((m >> dyr) & 1ull))
                    atomicAdd(&tile[dyb][x][c], s);
            }
        }
    }
    __syncthreads();

    unsigned short* Gn = G + (size_t)nl * sampleStride;
    for (int i = tid; i < 4 * 72 * 40; i += 320) {
        int c2 = i % 40;
        int t  = i / 40;
        int x  = t % 72;
        int dyb = t / 72;
        float v = (c2 < 33) ? tile[dyb][x][c2] : 0.0f;
        Gn[((size_t)(by + dyb + 2) * 76 + (x + 2)) * 40 + c2] = f2bf(v);
    }
}

// ---------------------------------------------------------------------------
// 4) Weight pack: w[oc][ci][K][K] fp32 -> bf16 wPT[kb][oc][32] with
//    k = (ky*K+kx)*Cpad + ci ordering, grouped 8-ci; zero-padded.
// ---------------------------------------------------------------------------
__global__ __launch_bounds__(256) void wpack_k(
    const float* __restrict__ w, unsigned short* __restrict__ wPT,
    int COUT, int CIN, int KK, int gpc, int total)
{
    int idx = blockIdx.x * 256 + threadIdx.x;
    if (idx >= total) return;
    int kk = idx & 31;
    int t  = idx >> 5;
    int oc = t % COUT;
    int kb = t / COUT;
    int g  = kb * 4 + (kk >> 3);
    int j  = kk & 7;
    int shift = g / gpc;
    int ci    = (g % gpc) * 8 + j;
    float v = (shift < KK && ci < CIN)
        ? w[(size_t)oc * CIN * KK + (size_t)ci * KK + shift] : 0.0f;
    wPT[idx] = f2bf(v);
}

// ---------------------------------------------------------------------------
// 5) ktab (group element-offsets) for all three convs in one launch
// ---------------------------------------------------------------------------
__global__ __launch_bounds__(256) void ktab_all_k(
    int* __restrict__ kt0, int* __restrict__ kt1, int* __restrict__ kt2)
{
    int t = threadIdx.x;
    int which = blockIdx.y;
    int ngr, gpc, K, Wp, CP;
    int* dst;
    if (which == 0)      { ngr = 128; gpc = 5;  K = 5; Wp = 76; CP = 40;  dst = kt0; }
    else if (which == 1) { ngr = 72;  gpc = 8;  K = 3; Wp = 37; CP = 64;  dst = kt1; }
    else                 { ngr = 144; gpc = 16; K = 3; Wp = 19; CP = 128; dst = kt2; }
    if (t >= ngr) return;
    int shift = t / gpc;
    int off = 0;
    if (shift < K * K) {
        int ky = shift / K, kx = shift % K;
        off = (ky * Wp + kx) * CP + (t % gpc) * 8;
    }
    dst[t] = off;
}

// ---------------------------------------------------------------------------
// 6) Implicit-GEMM conv + bias + ReLU, bf16 MFMA 16x16x32, HWC in/out.
//    No barriers in K-loop; every load is 16B. Epilogue: LDS transpose to
//    row-major [p][oc], wide coalesced HWC stores.
// ---------------------------------------------------------------------------
template<int MFRAG, int NG>
__global__ __launch_bounds__(256) void conv_mfma_k(
    const unsigned short* __restrict__ inP,   // [B][Hp][Wp][Cp] bf16
    const unsigned short* __restrict__ wPT,   // [ksteps][COUT][32] bf16
    const int* __restrict__ ktab,             // [ksteps*4] group offsets
    const float* __restrict__ bias,
    unsigned short* __restrict__ out,         // [B][Mtot][COUT] bf16
    int W, int PITCH, int XSTR,
    int Mtot, int inSS, int outSS, int ksteps, int COUT)
{
    constexpr int Mblk = MFRAG * 64;
    constexpr int NOC  = NG * 16;
    constexpr int SEGS = NOC / 16;
    constexpr int LP   = NOC + 8;     // LDS pitch (u16), 16B-aligned rows

    const int tid  = threadIdx.x;
    const int mb   = blockIdx.x;
    const int ocb  = blockIdx.y;
    const int nl   = blockIdx.z;
    const int lane = tid & 63;
    const int wv   = tid >> 6;
    const int frow = lane & 15;
    const int fq   = lane >> 4;

    const unsigned short* in_n = inP + (size_t)nl * inSS;
    const unsigned short* ab[MFRAG];
    #pragma unroll
    for (int mf = 0; mf < MFRAG; ++mf) {
        int p  = mb * Mblk + mf * 64 + wv * 16 + frow;
        int pc = p < Mtot ? p : (Mtot - 1);
        int y  = pc / W;
        int x  = pc - y * W;
        ab[mf] = in_n + y * PITCH + x * XSTR;
    }
    const unsigned short* wbase =
        wPT + ((size_t)(ocb * NOC + frow)) * 32 + fq * 8;

    f32x4 acc[MFRAG][NG];
    #pragma unroll
    for (int mf = 0; mf < MFRAG; ++mf)
        #pragma unroll
        for (int ng = 0; ng < NG; ++ng)
            acc[mf][ng] = (f32x4){0.f, 0.f, 0.f, 0.f};

    for (int kb = 0; kb < ksteps; ++kb) {
        int go = ktab[kb * 4 + fq];
        bf16x8 af[MFRAG];
        #pragma unroll
        for (int mf = 0; mf < MFRAG; ++mf)
            af[mf] = *reinterpret_cast<const bf16x8*>(ab[mf] + go);
        const unsigned short* wk = wbase + (size_t)kb * COUT * 32;
        #pragma unroll
        for (int ng = 0; ng < NG; ++ng) {
            bf16x8 bf = *reinterpret_cast<const bf16x8*>(wk + ng * 16 * 32);
            #pragma unroll
            for (int mf = 0; mf < MFRAG; ++mf)
                acc[mf][ng] = __builtin_amdgcn_mfma_f32_16x16x32_bf16(
                    af[mf], bf, acc[mf][ng], 0, 0, 0);
        }
    }

    // epilogue: per-mf LDS transpose + coalesced HWC store
    __shared__ unsigned short s_c[64 * LP];
    unsigned short* out_n = out + (size_t)nl * outSS;
    #pragma unroll
    for (int mf = 0; mf < MFRAG; ++mf) {
        __syncthreads();
        #pragma unroll
        for (int ng = 0; ng < NG; ++ng) {
            float bv = bias[ocb * NOC + ng * 16 + frow];
            #pragma unroll
            for (int j = 0; j < 4; ++j)
                s_c[(wv * 16 + fq * 4 + j) * LP + ng * 16 + frow] =
                    f2bf(fmaxf(acc[mf][ng][j] + bv, 0.0f));
        }
        __syncthreads();
        for (int t = tid; t < 64 * SEGS; t += 256) {
            int row = t / SEGS, seg = t % SEGS;
            int p = mb * Mblk + mf * 64 + row;
            if (p < Mtot) {
                ushort8 v0 = *reinterpret_cast<const ushort8*>(
                    &s_c[row * LP + seg * 16]);
                ushort8 v1 = *reinterpret_cast<const ushort8*>(
                    &s_c[row * LP + seg * 16 + 8]);
                unsigned short* op =
                    out_n + (size_t)p * COUT + ocb * NOC + seg * 16;
                *reinterpret_cast<ushort8*>(op) = v0;
                *reinterpret_cast<ushort8*>(op + 8) = v1;
            }
        }
    }
}

// ---------------------------------------------------------------------------
// 7) MaxPool 3x3 s2 VALID, HWC, ushort8 vector ops (post-ReLU: u16 max).
//    Writes padded interior (+1) of output.
// ---------------------------------------------------------------------------
__global__ __launch_bounds__(256) void pool_k(
    const unsigned short* __restrict__ in, unsigned short* __restrict__ out,
    int CG, int C, int W, int inSS,
    int HO, int WO, int Wpo, int outSS, int total)
{
    int idx = blockIdx.x * 256 + threadIdx.x;
    if (idx >= total) return;
    int cg = idx % CG;
    int t  = idx / CG;
    int x  = t % WO;
    t /= WO;
    int y  = t % HO;
    int nl = t / HO;

    const unsigned short* pin = in + (size_t)nl * inSS + cg * 8;
    ushort8 mx = {0,0,0,0,0,0,0,0};
    #pragma unroll
    for (int dy = 0; dy < 3; ++dy)
        #pragma unroll
        for (int dx = 0; dx < 3; ++dx) {
            ushort8 v = *reinterpret_cast<const ushort8*>(
                pin + ((size_t)(2 * y + dy) * W + (2 * x + dx)) * C);
            #pragma unroll
            for (int j = 0; j < 8; ++j) mx[j] = v[j] > mx[j] ? v[j] : mx[j];
        }
    *reinterpret_cast<ushort8*>(
        out + (size_t)nl * outSS +
        ((size_t)(y + 1) * Wpo + (x + 1)) * C + cg * 8) = mx;
}

// ---------------------------------------------------------------------------
// 8) Fused pool2 (3x3 s2 on [17][17][256]) + global average pool -> fp32
// ---------------------------------------------------------------------------
__global__ __launch_bounds__(512) void pool2gap_k(
    const unsigned short* __restrict__ in, float* __restrict__ out,
    int inSS, int n0)
{
    __shared__ float part[256];
    const int nl = blockIdx.x;
    const int c    = threadIdx.x & 255;
    const int half = threadIdx.x >> 8;
    const unsigned short* p = in + (size_t)nl * inSS + c;
    float s = 0.0f;
    for (int w = half * 32; w < half * 32 + 32; ++w) {
        int y = w >> 3, x = w & 7;
        unsigned short mx = 0;
        #pragma unroll
        for (int dy = 0; dy < 3; ++dy)
            #pragma unroll
            for (int dx = 0; dx < 3; ++dx) {
                unsigned short v = p[((size_t)(2*y+dy) * 17 + (2*x+dx)) * 256];
                mx = v > mx ? v : mx;
            }
        s += bf2f(mx);
    }
    if (half) part[c] = s;
    __syncthreads();
    if (!half) out[(size_t)(n0 + nl) * 256 + c] = (s + part[c]) * (1.0f / 64.0f);
}

// ---------------------------------------------------------------------------
// 9) FC weight transpose: w[o][i] -> wT[i][o]
// ---------------------------------------------------------------------------
__global__ __launch_bounds__(256) void fcT_k(
    const float* __restrict__ w, float* __restrict__ wT, int O, int I, int total)
{
    int idx = blockIdx.x * 256 + threadIdx.x;
    if (idx >= total) return;
    int i = idx % I, o = idx / I;
    wT[(size_t)i * O + o] = w[idx];
}

// ---------------------------------------------------------------------------
// 10) Fused 3-layer FC head (256->512->256->512), one block per sample
// ---------------------------------------------------------------------------
__global__ __launch_bounds__(256) void fc_fused_k(
    const float* __restrict__ in,
    const float* __restrict__ w0T, const float* __restrict__ b0,
    const float* __restrict__ w1T, const float* __restrict__ b1,
    const float* __restrict__ w2T, const float* __restrict__ b2,
    float* __restrict__ out)
{
    __shared__ float s_in[256], s_h0[512], s_h1[256];
    const int n = blockIdx.x, t = threadIdx.x;
    s_in[t] = in[(size_t)n * 256 + t];
    __syncthreads();
    float a0 = 0.f, a1 = 0.f;
    for (int i = 0; i < 256; ++i) {
        float v = s_in[i];
        a0 += v * w0T[i * 512 + t];
        a1 += v * w0T[i * 512 + t + 256];
    }
    s_h0[t]       = fmaxf(a0 + b0[t], 0.0f);
    s_h0[t + 256] = fmaxf(a1 + b0[t + 256], 0.0f);
    __syncthreads();
    float h = 0.f;
    for (int i = 0; i < 512; ++i) h += s_h0[i] * w1T[i * 256 + t];
    s_h1[t] = fmaxf(h + b1[t], 0.0f);
    __syncthreads();
    a0 = 0.f; a1 = 0.f;
    for (int i = 0; i < 256; ++i) {
        float v = s_h1[i];
        a0 += v * w2T[i * 512 + t];
        a1 += v * w2T[i * 512 + t + 256];
    }
    out[(size_t)n * 512 + t]       = a0 + b2[t];
    out[(size_t)n * 512 + t + 256] = a1 + b2[t + 256];
}

// ---------------------------------------------------------------------------
// Launch. Per-sample u16 sizes (HWC):
//   A: G [76][76][40] = 231,040   (overlay: C1 [1225][128]=156,800)
//   B: C0 [5184][64]  = 331,776   (overlay: C2 [289][256]=73,984)
//   C: P0p [37][37][64]=87,616 + P1p [19][19][128]=46,208 = 133,824
// ---------------------------------------------------------------------------
extern "C" void kernel_launch(void* const* d_in, const int* in_sizes, int n_in,
                              void* d_out, int out_size, void* d_ws, size_t ws_size,
                              hipStream_t stream)
{
    const int*   X   = (const int*)d_in[0];
    const int*   rm  = (const int*)d_in[1];
    const float* emb = (const float*)d_in[2];
    const float* cw0 = (const float*)d_in[3];
    const float* cb0 = (const float*)d_in[4];
    const float* cw1 = (const float*)d_in[5];
    const float* cb1 = (const float*)d_in[6];
    const float* cw2 = (const float*)d_in[7];
    const float* cb2 = (const float*)d_in[8];
    const float* fw0 = (const float*)d_in[9];
    const float* fb0 = (const float*)d_in[10];
    const float* fw1 = (const float*)d_in[11];
    const float* fb1 = (const float*)d_in[12];
    const float* fw2 = (const float*)d_in[13];
    const float* fb2 = (const float*)d_in[14];
    float* out = (float*)d_out;

    char* p = (char*)d_ws;
    auto alloc = [&](size_t bytes) -> char* {
        char* r = p; p += (bytes + 255) & ~(size_t)255; return r;
    };
    // packed weights: conv0 32 ksteps, conv1 18, conv2 36
    unsigned short* WP0 = (unsigned short*)alloc((size_t)32 * 64 * 32 * 2);
    unsigned short* WP1 = (unsigned short*)alloc((size_t)18 * 128 * 32 * 2);
    unsigned short* WP2 = (unsigned short*)alloc((size_t)36 * 256 * 32 * 2);
    int* KT0 = (int*)alloc(128 * 4);
    int* KT1 = (int*)alloc(72 * 4);
    int* KT2 = (int*)alloc(144 * 4);
    unsigned long long* MASKS = (unsigned long long*)alloc(RR * 8);
    float* W0T  = (float*)alloc((size_t)256 * 512 * 4);
    float* W1T  = (float*)alloc((size_t)512 * 256 * 4);
    float* W2T  = (float*)alloc((size_t)256 * 512 * 4);
    float* GAPB = (float*)alloc((size_t)NB * 256 * 4);
    size_t fixed_bytes = (size_t)(p - (char*)d_ws);

    const size_t A_FL = 231040, B_FL = 331776, C_FL = 133824;   // u16
    const size_t per_sample = (A_FL + B_FL + C_FL) * 2 + 768;
    int Bc = 128;
    while (Bc > 1 && fixed_bytes + (size_t)Bc * per_sample > ws_size) Bc >>= 1;

    unsigned short* bufA = (unsigned short*)alloc((size_t)Bc * A_FL * 2);
    unsigned short* bufC = (unsigned short*)alloc((size_t)Bc * C_FL * 2);
    unsigned short* bufB = (unsigned short*)alloc((size_t)Bc * B_FL * 2);

    // ---- one-time prep (runs every call; graph-safe) ----
    build_masks_k<<<2, 256, 0, stream>>>(rm, MASKS);
    wpack_k<<<(32 * 64 * 32 + 255) / 256, 256, 0, stream>>>(
        cw0, WP0, 64, 33, 25, 5, 32 * 64 * 32);
    wpack_k<<<(18 * 128 * 32 + 255) / 256, 256, 0, stream>>>(
        cw1, WP1, 128, 64, 9, 8, 18 * 128 * 32);
    wpack_k<<<(36 * 256 * 32 + 255) / 256, 256, 0, stream>>>(
        cw2, WP2, 256, 128, 9, 16, 36 * 256 * 32);
    ktab_all_k<<<dim3(1, 3), 256, 0, stream>>>(KT0, KT1, KT2);
    fcT_k<<<(512 * 256 + 255) / 256, 256, 0, stream>>>(fw0, W0T, 512, 256, 512 * 256);
    fcT_k<<<(256 * 512 + 255) / 256, 256, 0, stream>>>(fw1, W1T, 256, 512, 256 * 512);
    fcT_k<<<(512 * 256 + 255) / 256, 256, 0, stream>>>(fw2, W2T, 512, 256, 512 * 256);

    // ---- chunked pipeline ----
    for (int n0 = 0; n0 < NB; n0 += Bc) {
        // zero A+C (contiguous allocs): halos + channel padding
        size_t n16 = (size_t)Bc * (A_FL + C_FL) * 2 / 16;
        fillz_k<<<4096, 256, 0, stream>>>((uint4*)bufA, n16);

        // encode -> A (HWC G [76][76][40], interior +2)
        encode_k<<<dim3(Bc, 18), 320, 0, stream>>>(X, MASKS, emb, bufA, n0, (int)A_FL);

        // conv0: A -> B  (M=5184, Mblk=128 -> 41, COUT=64, 32 ksteps)
        conv_mfma_k<2, 4><<<dim3(41, 1, Bc), 256, 0, stream>>>(
            bufA, WP0, KT0, cb0, bufB, 72, 76 * 40, 40,
            5184, (int)A_FL, (int)B_FL, 32, 64);
        // pool0: B [72][72][64] -> C P0p [37][37][64] interior +1
        pool_k<<<(Bc * 35 * 35 * 8 + 255) / 256, 256, 0, stream>>>(
            bufB, bufC, 8, 64, 72, (int)B_FL,
            35, 35, 37, (int)C_FL, Bc * 35 * 35 * 8);

        // conv1: C -> A  (M=1225, Mblk=128 -> 10, COUT=128, 18 ksteps)
        conv_mfma_k<2, 8><<<dim3(10, 1, Bc), 256, 0, stream>>>(
            bufC, WP1, KT1, cb1, bufA, 35, 37 * 64, 64,
            1225, (int)C_FL, (int)A_FL, 18, 128);
        // pool1: A [35][35][128] -> C+87616 P1p [19][19][128] interior +1
        pool_k<<<(Bc * 17 * 17 * 16 + 255) / 256, 256, 0, stream>>>(
            bufA, bufC + 87616, 16, 128, 35, (int)A_FL,
            17, 17, 19, (int)C_FL, Bc * 17 * 17 * 16);

        // conv2: C+87616 -> B  (M=289, Mblk=64 -> 5, COUT=256, 2 oc-blocks)
        conv_mfma_k<1, 8><<<dim3(5, 2, Bc), 256, 0, stream>>>(
            bufC + 87616, WP2, KT2, cb2, bufB, 17, 19 * 128, 128,
            289, (int)C_FL, (int)B_FL, 36, 256);

        // fused pool2 + GAP: B [17][17][256] -> GAPB fp32
        pool2gap_k<<<Bc, 512, 0, stream>>>(bufB, GAPB, (int)B_FL, n0);
    }

    // fused FC head
    fc_fused_k<<<NB, 256, 0, stream>>>(GAPB, W0T, fb0, W1T, fb1, W2T, fb2, out);
}

// Round 6
// 747.834 us; speedup vs baseline: 1.3292x; 1.0513x over previous
//
#include <hip/hip_runtime.h>
#include <hip/hip_bf16.h>
#include <cstdint>
#include <cstddef>

#define NB      128
#define RR      300
#define EMB     32

typedef __bf16 bf16x8 __attribute__((ext_vector_type(8)));
typedef float  f32x4  __attribute__((ext_vector_type(4)));
typedef unsigned short ushort8 __attribute__((ext_vector_type(8)));

__device__ __forceinline__ unsigned short f2bf(float f) {
    union { __hip_bfloat16 h; unsigned short u; } c;
    c.h = __float2bfloat16(f);
    return c.u;
}
__device__ __forceinline__ float bf2f(unsigned short u) {
    union { __hip_bfloat16 h; unsigned short u; } c;
    c.u = u;
    return __bfloat162float(c.h);
}

// ---------------------------------------------------------------------------
// 1) Room occupancy -> uint64 bitmask (bit b = dx*8+dy)
// ---------------------------------------------------------------------------
__global__ __launch_bounds__(256) void build_masks_k(
    const int* __restrict__ rm, unsigned long long* __restrict__ masks)
{
    int r = blockIdx.x * 256 + threadIdx.x;
    if (r >= RR) return;
    unsigned long long m = 0ull;
    #pragma unroll
    for (int b = 0; b < 64; ++b)
        if (rm[r * 64 + b]) m |= (1ull << b);
    masks[r] = m;
}

// ---------------------------------------------------------------------------
// 2) Zero-fill (uint4 grid-stride)
// ---------------------------------------------------------------------------
__global__ __launch_bounds__(256) void fillz_k(uint4* __restrict__ p, size_t n16)
{
    uint4 z = make_uint4(0, 0, 0, 0);
    for (size_t i = blockIdx.x * 256ull + threadIdx.x; i < n16;
         i += (size_t)gridDim.x * 256ull)
        p[i] = z;
}

// ---------------------------------------------------------------------------
// 3) Encode, banded HWC: block = (sample, 4-row band). LDS fp32 [4][72][33],
//    atomics within band, coalesced bf16 HWC write to G[76][76][40] (+2 halo).
// ---------------------------------------------------------------------------
__global__ __launch_bounds__(320) void encode_k(
    const int* __restrict__ X, const unsigned long long* __restrict__ masks,
    const float* __restrict__ emb, unsigned short* __restrict__ G,
    int n0, int sampleStride)
{
    __shared__ float tile[4][72][33];
    const int nl = blockIdx.x, band = blockIdx.y;
    const int by = band * 4;
    const int n  = n0 + nl;
    const int tid = threadIdx.x;

    float* tf = &tile[0][0][0];
    for (int i = tid; i < 4 * 72 * 33; i += 320) tf[i] = 0.0f;
    __syncthreads();

    const int dx = tid / 33;
    const int c  = tid - dx * 33;
    const int2* Xp = reinterpret_cast<const int2*>(X);

    for (int r = 0; r < RR; ++r) {
        int2 pos = Xp[n * RR + r];
        int y0 = pos.y;
        if (y0 > by + 3 || y0 + 7 < by) continue;   // block-uniform skip
        if (tid < 264) {
            float s = (c == 0) ? 1.0f : emb[r * EMB + (c - 1)];
            unsigned long long m = masks[r] >> (dx * 8);
            int x = pos.x + dx;
            #pragma unroll
            for (int dyb = 0; dyb < 4; ++dyb) {
                int dyr = by + dyb - y0;
                if ((unsigned)dyr < 8u && ((m >> dyr) & 1ull))
                    atomicAdd(&tile[dyb][x][c], s);
            }
        }
    }
    __syncthreads();

    unsigned short* Gn = G + (size_t)nl * sampleStride;
    for (int i = tid; i < 4 * 72 * 40; i += 320) {
        int c2 = i % 40;
        int t  = i / 40;
        int x  = t % 72;
        int dyb = t / 72;
        float v = (c2 < 33) ? tile[dyb][x][c2] : 0.0f;
        Gn[((size_t)(by + dyb + 2) * 76 + (x + 2)) * 40 + c2] = f2bf(v);
    }
}

// ---------------------------------------------------------------------------
// 4) Weight pack: w[oc][ci][K][K] fp32 -> bf16 wPT[kb][oc][32] with
//    k = (ky*K+kx)*Cpad + ci ordering, grouped 8-ci; zero-padded.
// ---------------------------------------------------------------------------
__global__ __launch_bounds__(256) void wpack_k(
    const float* __restrict__ w, unsigned short* __restrict__ wPT,
    int COUT, int CIN, int KK, int gpc, int total)
{
    int idx = blockIdx.x * 256 + threadIdx.x;
    if (idx >= total) return;
    int kk = idx & 31;
    int t  = idx >> 5;
    int oc = t % COUT;
    int kb = t / COUT;
    int g  = kb * 4 + (kk >> 3);
    int j  = kk & 7;
    int shift = g / gpc;
    int ci    = (g % gpc) * 8 + j;
    float v = (shift < KK && ci < CIN)
        ? w[(size_t)oc * CIN * KK + (size_t)ci * KK + shift] : 0.0f;
    wPT[idx] = f2bf(v);
}

// ---------------------------------------------------------------------------
// 5) ktab: LDS-space group offsets (elem units, padded pixel stride CL)
// ---------------------------------------------------------------------------
__global__ __launch_bounds__(256) void ktab_all_k(
    int* __restrict__ kt0, int* __restrict__ kt1, int* __restrict__ kt2)
{
    int t = threadIdx.x;
    int which = blockIdx.y;
    int ngr, gpc, K, Wp, CL;
    int* dst;
    if (which == 0)      { ngr = 128; gpc = 5;  K = 5; Wp = 76; CL = 40;  dst = kt0; }
    else if (which == 1) { ngr = 72;  gpc = 8;  K = 3; Wp = 37; CL = 72;  dst = kt1; }
    else                 { ngr = 144; gpc = 16; K = 3; Wp = 19; CL = 136; dst = kt2; }
    if (t >= ngr) return;
    int shift = t / gpc;
    int off = 0;
    if (shift < K * K) {
        int ky = shift / K, kx = shift % K;
        off = (ky * Wp + kx) * CL + (t % gpc) * 8;
    }
    dst[t] = off;
}

// ---------------------------------------------------------------------------
// 6) Implicit-GEMM conv + bias + ReLU, bf16 MFMA 16x16x32, HWC in/out.
//    Input slab (<=7 padded rows, whole K dim) staged ONCE to LDS with
//    coalesced uint4 loads; K-loop = ds_read_b128 (A) + L1-resident B loads
//    + MFMA, no barriers. Epilogue: LDS transpose (aliases slab) + wide
//    coalesced HWC stores.
//    CPG = global channels/8, CL = LDS pixel stride (elems), SLAB = max elems.
// ---------------------------------------------------------------------------
template<int MFRAG, int NG, int KH, int CPG, int CL, int SLAB>
__global__ __launch_bounds__(256) void conv_mfma_k(
    const unsigned short* __restrict__ inP,   // [B][Hp][Wp][Cp] bf16
    const unsigned short* __restrict__ wPT,   // [ksteps][COUT][32] bf16
    const int* __restrict__ ktab,             // [ksteps*4] LDS group offsets
    const float* __restrict__ bias,
    unsigned short* __restrict__ out,         // [B][Mtot][COUT] bf16
    int W, int Wp, int Mtot, int inSS, int outSS, int ksteps, int COUT)
{
    constexpr int Mblk = MFRAG * 64;
    constexpr int NOC  = NG * 16;
    constexpr int SEGS = NOC / 16;
    constexpr int LP   = NOC + 8;
    constexpr int CP   = CPG * 8;
    constexpr int SMEM = (SLAB * 2 > 64 * LP * 2) ? SLAB * 2 : 64 * LP * 2;
    __shared__ __align__(16) char smem[SMEM];
    unsigned short* slab = reinterpret_cast<unsigned short*>(smem);
    unsigned short* s_c  = reinterpret_cast<unsigned short*>(smem);

    const int tid  = threadIdx.x;
    const int mb   = blockIdx.x;
    const int ocb  = blockIdx.y;
    const int nl   = blockIdx.z;
    const int lane = tid & 63;
    const int wv   = tid >> 6;
    const int frow = lane & 15;
    const int fq   = lane >> 4;

    const int p0    = mb * Mblk;
    const int y0    = p0 / W;
    const int plast = (p0 + Mblk < Mtot ? p0 + Mblk : Mtot) - 1;
    const int rows  = plast / W - y0 + KH;

    // ---- stage slab: rows [y0, y0+rows) of padded input, re-pitched to CL
    const unsigned short* in_n =
        inP + (size_t)nl * inSS + (size_t)y0 * Wp * CP;
    const int nchunks = rows * Wp * CPG;
    for (int q = tid; q < nchunks; q += 256) {
        int pix = q / CPG, c8 = q - pix * CPG;
        uint4 v = reinterpret_cast<const uint4*>(in_n)[q];
        *reinterpret_cast<uint4*>(&slab[pix * CL + c8 * 8]) = v;
    }

    // ---- per-lane LDS bases (m positions, clamped at tail)
    int ldsb[MFRAG];
    #pragma unroll
    for (int mf = 0; mf < MFRAG; ++mf) {
        int p  = p0 + mf * 64 + wv * 16 + frow;
        int pc = p < Mtot ? p : (Mtot - 1);
        int y  = pc / W;
        int x  = pc - y * W;
        ldsb[mf] = ((y - y0) * Wp + x) * CL;
    }
    const unsigned short* wbase =
        wPT + ((size_t)(ocb * NOC + frow)) * 32 + fq * 8;

    f32x4 acc[MFRAG][NG];
    #pragma unroll
    for (int mf = 0; mf < MFRAG; ++mf)
        #pragma unroll
        for (int ng = 0; ng < NG; ++ng)
            acc[mf][ng] = (f32x4){0.f, 0.f, 0.f, 0.f};

    __syncthreads();

    for (int kb = 0; kb < ksteps; ++kb) {
        int go = ktab[kb * 4 + fq];
        bf16x8 af[MFRAG];
        #pragma unroll
        for (int mf = 0; mf < MFRAG; ++mf)
            af[mf] = *reinterpret_cast<const bf16x8*>(&slab[ldsb[mf] + go]);
        const unsigned short* wk = wbase + (size_t)kb * COUT * 32;
        #pragma unroll
        for (int ng = 0; ng < NG; ++ng) {
            bf16x8 bf = *reinterpret_cast<const bf16x8*>(wk + ng * 16 * 32);
            #pragma unroll
            for (int mf = 0; mf < MFRAG; ++mf)
                acc[mf][ng] = __builtin_amdgcn_mfma_f32_16x16x32_bf16(
                    af[mf], bf, acc[mf][ng], 0, 0, 0);
        }
    }

    // ---- epilogue: per-mf LDS transpose + coalesced HWC store
    unsigned short* out_n = out + (size_t)nl * outSS;
    #pragma unroll
    for (int mf = 0; mf < MFRAG; ++mf) {
        __syncthreads();
        #pragma unroll
        for (int ng = 0; ng < NG; ++ng) {
            float bv = bias[ocb * NOC + ng * 16 + frow];
            #pragma unroll
            for (int j = 0; j < 4; ++j)
                s_c[(wv * 16 + fq * 4 + j) * LP + ng * 16 + frow] =
                    f2bf(fmaxf(acc[mf][ng][j] + bv, 0.0f));
        }
        __syncthreads();
        for (int t = tid; t < 64 * SEGS; t += 256) {
            int row = t / SEGS, seg = t % SEGS;
            int p = p0 + mf * 64 + row;
            if (p < Mtot) {
                ushort8 v0 = *reinterpret_cast<const ushort8*>(
                    &s_c[row * LP + seg * 16]);
                ushort8 v1 = *reinterpret_cast<const ushort8*>(
                    &s_c[row * LP + seg * 16 + 8]);
                unsigned short* op =
                    out_n + (size_t)p * COUT + ocb * NOC + seg * 16;
                *reinterpret_cast<ushort8*>(op) = v0;
                *reinterpret_cast<ushort8*>(op + 8) = v1;
            }
        }
    }
}

// ---------------------------------------------------------------------------
// 7) MaxPool 3x3 s2 VALID, HWC, ushort8 vector ops (post-ReLU: u16 max).
//    Writes padded interior (+1) of output.
// ---------------------------------------------------------------------------
__global__ __launch_bounds__(256) void pool_k(
    const unsigned short* __restrict__ in, unsigned short* __restrict__ out,
    int CG, int C, int W, int inSS,
    int HO, int WO, int Wpo, int outSS, int total)
{
    int idx = blockIdx.x * 256 + threadIdx.x;
    if (idx >= total) return;
    int cg = idx % CG;
    int t  = idx / CG;
    int x  = t % WO;
    t /= WO;
    int y  = t % HO;
    int nl = t / HO;

    const unsigned short* pin = in + (size_t)nl * inSS + cg * 8;
    ushort8 mx = {0,0,0,0,0,0,0,0};
    #pragma unroll
    for (int dy = 0; dy < 3; ++dy)
        #pragma unroll
        for (int dx = 0; dx < 3; ++dx) {
            ushort8 v = *reinterpret_cast<const ushort8*>(
                pin + ((size_t)(2 * y + dy) * W + (2 * x + dx)) * C);
            #pragma unroll
            for (int j = 0; j < 8; ++j) mx[j] = v[j] > mx[j] ? v[j] : mx[j];
        }
    *reinterpret_cast<ushort8*>(
        out + (size_t)nl * outSS +
        ((size_t)(y + 1) * Wpo + (x + 1)) * C + cg * 8) = mx;
}

// ---------------------------------------------------------------------------
// 8) Fused pool2 (3x3 s2 on [17][17][256]) + global average pool -> fp32
// ---------------------------------------------------------------------------
__global__ __launch_bounds__(512) void pool2gap_k(
    const unsigned short* __restrict__ in, float* __restrict__ out,
    int inSS, int n0)
{
    __shared__ float part[256];
    const int nl = blockIdx.x;
    const int c    = threadIdx.x & 255;
    const int half = threadIdx.x >> 8;
    const unsigned short* p = in + (size_t)nl * inSS + c;
    float s = 0.0f;
    for (int w = half * 32; w < half * 32 + 32; ++w) {
        int y = w >> 3, x = w & 7;
        unsigned short mx = 0;
        #pragma unroll
        for (int dy = 0; dy < 3; ++dy)
            #pragma unroll
            for (int dx = 0; dx < 3; ++dx) {
                unsigned short v = p[((size_t)(2*y+dy) * 17 + (2*x+dx)) * 256];
                mx = v > mx ? v : mx;
            }
        s += bf2f(mx);
    }
    if (half) part[c] = s;
    __syncthreads();
    if (!half) out[(size_t)(n0 + nl) * 256 + c] = (s + part[c]) * (1.0f / 64.0f);
}

// ---------------------------------------------------------------------------
// 9) FC weight transpose: w[o][i] -> wT[i][o]
// ---------------------------------------------------------------------------
__global__ __launch_bounds__(256) void fcT_k(
    const float* __restrict__ w, float* __restrict__ wT, int O, int I, int total)
{
    int idx = blockIdx.x * 256 + threadIdx.x;
    if (idx >= total) return;
    int i = idx % I, o = idx / I;
    wT[(size_t)i * O + o] = w[idx];
}

// ---------------------------------------------------------------------------
// 10) Fused 3-layer FC head (256->512->256->512), one block per sample
// ---------------------------------------------------------------------------
__global__ __launch_bounds__(256) void fc_fused_k(
    const float* __restrict__ in,
    const float* __restrict__ w0T, const float* __restrict__ b0,
    const float* __restrict__ w1T, const float* __restrict__ b1,
    const float* __restrict__ w2T, const float* __restrict__ b2,
    float* __restrict__ out)
{
    __shared__ float s_in[256], s_h0[512], s_h1[256];
    const int n = blockIdx.x, t = threadIdx.x;
    s_in[t] = in[(size_t)n * 256 + t];
    __syncthreads();
    float a0 = 0.f, a1 = 0.f;
    for (int i = 0; i < 256; ++i) {
        float v = s_in[i];
        a0 += v * w0T[i * 512 + t];
        a1 += v * w0T[i * 512 + t + 256];
    }
    s_h0[t]       = fmaxf(a0 + b0[t], 0.0f);
    s_h0[t + 256] = fmaxf(a1 + b0[t + 256], 0.0f);
    __syncthreads();
    float h = 0.f;
    for (int i = 0; i < 512; ++i) h += s_h0[i] * w1T[i * 256 + t];
    s_h1[t] = fmaxf(h + b1[t], 0.0f);
    __syncthreads();
    a0 = 0.f; a1 = 0.f;
    for (int i = 0; i < 256; ++i) {
        float v = s_h1[i];
        a0 += v * w2T[i * 512 + t];
        a1 += v * w2T[i * 512 + t + 256];
    }
    out[(size_t)n * 512 + t]       = a0 + b2[t];
    out[(size_t)n * 512 + t + 256] = a1 + b2[t + 256];
}

// ---------------------------------------------------------------------------
// Launch. Per-sample u16 sizes (HWC):
//   A: G [76][76][40] = 231,040   (overlay: C1 [1225][128]=156,800)
//   B: C0 [5184][64]  = 331,776   (overlay: C2 [289][256]=73,984)
//   C: P0p [37][37][64]=87,616 + P1p [19][19][128]=46,208 = 133,824
// ---------------------------------------------------------------------------
extern "C" void kernel_launch(void* const* d_in, const int* in_sizes, int n_in,
                              void* d_out, int out_size, void* d_ws, size_t ws_size,
                              hipStream_t stream)
{
    const int*   X   = (const int*)d_in[0];
    const int*   rm  = (const int*)d_in[1];
    const float* emb = (const float*)d_in[2];
    const float* cw0 = (const float*)d_in[3];
    const float* cb0 = (const float*)d_in[4];
    const float* cw1 = (const float*)d_in[5];
    const float* cb1 = (const float*)d_in[6];
    const float* cw2 = (const float*)d_in[7];
    const float* cb2 = (const float*)d_in[8];
    const float* fw0 = (const float*)d_in[9];
    const float* fb0 = (const float*)d_in[10];
    const float* fw1 = (const float*)d_in[11];
    const float* fb1 = (const float*)d_in[12];
    const float* fw2 = (const float*)d_in[13];
    const float* fb2 = (const float*)d_in[14];
    float* out = (float*)d_out;

    char* p = (char*)d_ws;
    auto alloc = [&](size_t bytes) -> char* {
        char* r = p; p += (bytes + 255) & ~(size_t)255; return r;
    };
    // packed weights: conv0 32 ksteps, conv1 18, conv2 36
    unsigned short* WP0 = (unsigned short*)alloc((size_t)32 * 64 * 32 * 2);
    unsigned short* WP1 = (unsigned short*)alloc((size_t)18 * 128 * 32 * 2);
    unsigned short* WP2 = (unsigned short*)alloc((size_t)36 * 256 * 32 * 2);
    int* KT0 = (int*)alloc(128 * 4);
    int* KT1 = (int*)alloc(72 * 4);
    int* KT2 = (int*)alloc(144 * 4);
    unsigned long long* MASKS = (unsigned long long*)alloc(RR * 8);
    float* W0T  = (float*)alloc((size_t)256 * 512 * 4);
    float* W1T  = (float*)alloc((size_t)512 * 256 * 4);
    float* W2T  = (float*)alloc((size_t)256 * 512 * 4);
    float* GAPB = (float*)alloc((size_t)NB * 256 * 4);
    size_t fixed_bytes = (size_t)(p - (char*)d_ws);

    const size_t A_FL = 231040, B_FL = 331776, C_FL = 133824;   // u16
    const size_t per_sample = (A_FL + B_FL + C_FL) * 2 + 768;
    int Bc = 128;
    while (Bc > 1 && fixed_bytes + (size_t)Bc * per_sample > ws_size) Bc >>= 1;

    unsigned short* bufA = (unsigned short*)alloc((size_t)Bc * A_FL * 2);
    unsigned short* bufC = (unsigned short*)alloc((size_t)Bc * C_FL * 2);
    unsigned short* bufB = (unsigned short*)alloc((size_t)Bc * B_FL * 2);

    // ---- one-time prep (runs every call; graph-safe) ----
    build_masks_k<<<2, 256, 0, stream>>>(rm, MASKS);
    wpack_k<<<(32 * 64 * 32 + 255) / 256, 256, 0, stream>>>(
        cw0, WP0, 64, 33, 25, 5, 32 * 64 * 32);
    wpack_k<<<(18 * 128 * 32 + 255) / 256, 256, 0, stream>>>(
        cw1, WP1, 128, 64, 9, 8, 18 * 128 * 32);
    wpack_k<<<(36 * 256 * 32 + 255) / 256, 256, 0, stream>>>(
        cw2, WP2, 256, 128, 9, 16, 36 * 256 * 32);
    ktab_all_k<<<dim3(1, 3), 256, 0, stream>>>(KT0, KT1, KT2);
    fcT_k<<<(512 * 256 + 255) / 256, 256, 0, stream>>>(fw0, W0T, 512, 256, 512 * 256);
    fcT_k<<<(256 * 512 + 255) / 256, 256, 0, stream>>>(fw1, W1T, 256, 512, 256 * 512);
    fcT_k<<<(512 * 256 + 255) / 256, 256, 0, stream>>>(fw2, W2T, 512, 256, 512 * 256);

    // ---- chunked pipeline ----
    for (int n0 = 0; n0 < NB; n0 += Bc) {
        // zero A+C (contiguous allocs): halos + channel padding
        size_t n16 = (size_t)Bc * (A_FL + C_FL) * 2 / 16;
        fillz_k<<<4096, 256, 0, stream>>>((uint4*)bufA, n16);

        // encode -> A (HWC G [76][76][40], interior +2)
        encode_k<<<dim3(Bc, 18), 320, 0, stream>>>(X, MASKS, emb, bufA, n0, (int)A_FL);

        // conv0: A -> B  (M=5184, Mblk=128 -> 41, COUT=64, 32 ksteps)
        conv_mfma_k<2, 4, 5, 5, 40, 21280><<<dim3(41, 1, Bc), 256, 0, stream>>>(
            bufA, WP0, KT0, cb0, bufB, 72, 76,
            5184, (int)A_FL, (int)B_FL, 32, 64);
        // pool0: B [72][72][64] -> C P0p [37][37][64] interior +1
        pool_k<<<(Bc * 35 * 35 * 8 + 255) / 256, 256, 0, stream>>>(
            bufB, bufC, 8, 64, 72, (int)B_FL,
            35, 35, 37, (int)C_FL, Bc * 35 * 35 * 8);

        // conv1: C -> A  (M=1225, Mblk=128 -> 10, COUT=128, 18 ksteps)
        conv_mfma_k<2, 8, 3, 8, 72, 18648><<<dim3(10, 1, Bc), 256, 0, stream>>>(
            bufC, WP1, KT1, cb1, bufA, 35, 37,
            1225, (int)C_FL, (int)A_FL, 18, 128);
        // pool1: A [35][35][128] -> C+87616 P1p [19][19][128] interior +1
        pool_k<<<(Bc * 17 * 17 * 16 + 255) / 256, 256, 0, stream>>>(
            bufA, bufC + 87616, 16, 128, 35, (int)A_FL,
            17, 17, 19, (int)C_FL, Bc * 17 * 17 * 16);

        // conv2: C+87616 -> B  (M=289, Mblk=64 -> 5, COUT=256, 2 oc-blocks)
        conv_mfma_k<1, 8, 3, 16, 136, 18088><<<dim3(5, 2, Bc), 256, 0, stream>>>(
            bufC + 87616, WP2, KT2, cb2, bufB, 17, 19,
            289, (int)C_FL, (int)B_FL, 36, 256);

        // fused pool2 + GAP: B [17][17][256] -> GAPB fp32
        pool2gap_k<<<Bc, 512, 0, stream>>>(bufB, GAPB, (int)B_FL, n0);
    }

    // fused FC head
    fc_fused_k<<<NB, 256, 0, stream>>>(GAPB, W0T, fb0, W1T, fb1, W2T, fb2, out);
}

// Round 7
// 687.290 us; speedup vs baseline: 1.4463x; 1.0881x over previous
//
#include <hip/hip_runtime.h>
#include <hip/hip_bf16.h>
#include <cstdint>
#include <cstddef>

#define NB      128
#define RR      300
#define EMB     32

typedef __bf16 bf16x8 __attribute__((ext_vector_type(8)));
typedef float  f32x4  __attribute__((ext_vector_type(4)));
typedef unsigned short ushort8 __attribute__((ext_vector_type(8)));

__device__ __forceinline__ unsigned short f2bf(float f) {
    union { __hip_bfloat16 h; unsigned short u; } c;
    c.h = __float2bfloat16(f);
    return c.u;
}
__device__ __forceinline__ float bf2f(unsigned short u) {
    union { __hip_bfloat16 h; unsigned short u; } c;
    c.u = u;
    return __bfloat162float(c.h);
}

// ---------------------------------------------------------------------------
// 1) Room occupancy -> uint64 bitmask (bit b = dx*8+dy)
// ---------------------------------------------------------------------------
__global__ __launch_bounds__(256) void build_masks_k(
    const int* __restrict__ rm, unsigned long long* __restrict__ masks)
{
    int r = blockIdx.x * 256 + threadIdx.x;
    if (r >= RR) return;
    unsigned long long m = 0ull;
    #pragma unroll
    for (int b = 0; b < 64; ++b)
        if (rm[r * 64 + b]) m |= (1ull << b);
    masks[r] = m;
}

// ---------------------------------------------------------------------------
// 2) Zero-fill (uint4 grid-stride)
// ---------------------------------------------------------------------------
__global__ __launch_bounds__(256) void fillz_k(uint4* __restrict__ p, size_t n16)
{
    uint4 z = make_uint4(0, 0, 0, 0);
    for (size_t i = blockIdx.x * 256ull + threadIdx.x; i < n16;
         i += (size_t)gridDim.x * 256ull)
        p[i] = z;
}

// ---------------------------------------------------------------------------
// 3) Encode, banded HWC: block = (sample, 4-row band). LDS fp32 [4][72][33],
//    atomics within band, coalesced bf16 HWC write to G[76][76][40] (+2 halo).
// ---------------------------------------------------------------------------
__global__ __launch_bounds__(320) void encode_k(
    const int* __restrict__ X, const unsigned long long* __restrict__ masks,
    const float* __restrict__ emb, unsigned short* __restrict__ G,
    int n0, int sampleStride)
{
    __shared__ float tile[4][72][33];
    const int nl = blockIdx.x, band = blockIdx.y;
    const int by = band * 4;
    const int n  = n0 + nl;
    const int tid = threadIdx.x;

    float* tf = &tile[0][0][0];
    for (int i = tid; i < 4 * 72 * 33; i += 320) tf[i] = 0.0f;
    __syncthreads();

    const int dx = tid / 33;
    const int c  = tid - dx * 33;
    const int2* Xp = reinterpret_cast<const int2*>(X);

    for (int r = 0; r < RR; ++r) {
        int2 pos = Xp[n * RR + r];
        int y0 = pos.y;
        if (y0 > by + 3 || y0 + 7 < by) continue;   // block-uniform skip
        if (tid < 264) {
            float s = (c == 0) ? 1.0f : emb[r * EMB + (c - 1)];
            unsigned long long m = masks[r] >> (dx * 8);
            int x = pos.x + dx;
            #pragma unroll
            for (int dyb = 0; dyb < 4; ++dyb) {
                int dyr = by + dyb - y0;
                if ((unsigned)dyr < 8u && ((m >> dyr) & 1ull))
                    atomicAdd(&tile[dyb][x][c], s);
            }
        }
    }
    __syncthreads();

    unsigned short* Gn = G + (size_t)nl * sampleStride;
    for (int i = tid; i < 4 * 72 * 40; i += 320) {
        int c2 = i % 40;
        int t  = i / 40;
        int x  = t % 72;
        int dyb = t / 72;
        float v = (c2 < 33) ? tile[dyb][x][c2] : 0.0f;
        Gn[((size_t)(by + dyb + 2) * 76 + (x + 2)) * 40 + c2] = f2bf(v);
    }
}

// ---------------------------------------------------------------------------
// 4) Weight pack: w[oc][ci][K][K] fp32 -> bf16 wPT[kb][oc][32] with
//    k = (ky*K+kx)*Cpad + ci ordering, grouped 8-ci; zero-padded.
// ---------------------------------------------------------------------------
__global__ __launch_bounds__(256) void wpack_k(
    const float* __restrict__ w, unsigned short* __restrict__ wPT,
    int COUT, int CIN, int KK, int gpc, int total)
{
    int idx = blockIdx.x * 256 + threadIdx.x;
    if (idx >= total) return;
    int kk = idx & 31;
    int t  = idx >> 5;
    int oc = t % COUT;
    int kb = t / COUT;
    int g  = kb * 4 + (kk >> 3);
    int j  = kk & 7;
    int shift = g / gpc;
    int ci    = (g % gpc) * 8 + j;
    float v = (shift < KK && ci < CIN)
        ? w[(size_t)oc * CIN * KK + (size_t)ci * KK + shift] : 0.0f;
    wPT[idx] = f2bf(v);
}

// ---------------------------------------------------------------------------
// 5) ktab: LDS-space group offsets (elem units). Entry 0 uses LDS pixel
//    pitch 20 (conv0 2D tile); entries 1/2 use row-slab pitches.
// ---------------------------------------------------------------------------
__global__ __launch_bounds__(256) void ktab_all_k(
    int* __restrict__ kt0, int* __restrict__ kt1, int* __restrict__ kt2)
{
    int t = threadIdx.x;
    int which = blockIdx.y;
    int ngr, gpc, K, Wp, CL;
    int* dst;
    if (which == 0)      { ngr = 128; gpc = 5;  K = 5; Wp = 20; CL = 40;  dst = kt0; }
    else if (which == 1) { ngr = 72;  gpc = 8;  K = 3; Wp = 37; CL = 72;  dst = kt1; }
    else                 { ngr = 144; gpc = 16; K = 3; Wp = 19; CL = 136; dst = kt2; }
    if (t >= ngr) return;
    int shift = t / gpc;
    int off = 0;
    if (shift < K * K) {
        int ky = shift / K, kx = shift % K;
        off = (ky * Wp + kx) * CL + (t % gpc) * 8;
    }
    dst[t] = off;
}

// ---------------------------------------------------------------------------
// 6a) conv0: dedicated 16x16-spatial-tile implicit-GEMM, bf16 MFMA 16x16x32.
//     M=256 (16 tile rows x 16 cols), NOC=64 (all ocs), slab 20x20x40 = 32KB
//     staged once (linear dst). No barriers in K-loop.
// ---------------------------------------------------------------------------
template<int KSTEPS>
__global__ __launch_bounds__(256) void conv0_tile_k(
    const unsigned short* __restrict__ inP,   // [B][76][76][40] bf16
    const unsigned short* __restrict__ wPT,   // [KSTEPS][64][32] bf16
    const int* __restrict__ ktab,             // [KSTEPS*4] LDS offsets
    const float* __restrict__ bias,
    unsigned short* __restrict__ out,         // [B][5184][64] bf16
    int inSS, int outSS)
{
    constexpr int CL = 40;
    constexpr int LP = 72;
    __shared__ __align__(16) unsigned short slab[20 * 20 * CL];  // 32000 B
    unsigned short* s_c = slab;

    const int tid = threadIdx.x;
    const int tl  = blockIdx.x;           // 0..24
    const int nl  = blockIdx.y;
    const int tyi = tl / 5, txi = tl % 5;
    const int y0 = tyi < 4 ? tyi * 16 : 56;
    const int x0 = txi < 4 ? txi * 16 : 56;

    const int lane = tid & 63, wv = tid >> 6, frow = lane & 15, fq = lane >> 4;

    const unsigned short* in_n = inP + (size_t)nl * inSS;
    {
        const uint4* src = reinterpret_cast<const uint4*>(in_n);
        uint4* dst = reinterpret_cast<uint4*>(slab);
        #pragma unroll
        for (int it = 0; it < 8; ++it) {
            int q = tid + it * 256;
            if (q < 2000) {
                int r = q / 100, c = q - r * 100;     // row, 16B-chunk in row
                dst[q] = src[((y0 + r) * 76 + x0) * 5 + c];
            }
        }
    }

    int ldsb[4];
    #pragma unroll
    for (int mf = 0; mf < 4; ++mf)
        ldsb[mf] = ((mf * 4 + wv) * 20 + frow) * CL;   // pixel (ty, tx=frow)

    const unsigned short* wbase = wPT + (size_t)frow * 32 + fq * 8;

    f32x4 acc[4][4];
    #pragma unroll
    for (int a = 0; a < 4; ++a)
        #pragma unroll
        for (int b = 0; b < 4; ++b) acc[a][b] = (f32x4){0.f, 0.f, 0.f, 0.f};

    __syncthreads();

    #pragma unroll 2
    for (int kb = 0; kb < KSTEPS; ++kb) {
        int go = ktab[kb * 4 + fq];
        bf16x8 af[4];
        #pragma unroll
        for (int mf = 0; mf < 4; ++mf)
            af[mf] = *reinterpret_cast<const bf16x8*>(&slab[ldsb[mf] + go]);
        const unsigned short* wk = wbase + (size_t)kb * 64 * 32;
        #pragma unroll
        for (int ng = 0; ng < 4; ++ng) {
            bf16x8 bf = *reinterpret_cast<const bf16x8*>(wk + ng * 16 * 32);
            #pragma unroll
            for (int mf = 0; mf < 4; ++mf)
                acc[mf][ng] = __builtin_amdgcn_mfma_f32_16x16x32_bf16(
                    af[mf], bf, acc[mf][ng], 0, 0, 0);
        }
    }

    unsigned short* out_n = out + (size_t)nl * outSS;
    const int erow = tid >> 2, eseg = tid & 3;        // 64 rows x 4 segs
    #pragma unroll
    for (int mf = 0; mf < 4; ++mf) {
        __syncthreads();
        #pragma unroll
        for (int ng = 0; ng < 4; ++ng) {
            float bv = bias[ng * 16 + frow];
            #pragma unroll
            for (int j = 0; j < 4; ++j)
                s_c[(wv * 16 + fq * 4 + j) * LP + ng * 16 + frow] =
                    f2bf(fmaxf(acc[mf][ng][j] + bv, 0.0f));
        }
        __syncthreads();
        {
            int ty = mf * 4 + (erow >> 4);
            int tx = erow & 15;
            int pos = (y0 + ty) * 72 + (x0 + tx);
            ushort8 v0 = *reinterpret_cast<const ushort8*>(
                &s_c[erow * LP + eseg * 16]);
            ushort8 v1 = *reinterpret_cast<const ushort8*>(
                &s_c[erow * LP + eseg * 16 + 8]);
            unsigned short* op = out_n + (size_t)pos * 64 + eseg * 16;
            *reinterpret_cast<ushort8*>(op) = v0;
            *reinterpret_cast<ushort8*>(op + 8) = v1;
        }
    }
}

// ---------------------------------------------------------------------------
// 6b) Generic row-slab implicit-GEMM conv (conv1/conv2), bf16 MFMA 16x16x32.
// ---------------------------------------------------------------------------
template<int MFRAG, int NG, int KH, int CPG, int CL, int SLAB, int KSTEPS>
__global__ __launch_bounds__(256) void conv_mfma_k(
    const unsigned short* __restrict__ inP,   // [B][Hp][Wp][Cp] bf16
    const unsigned short* __restrict__ wPT,   // [KSTEPS][COUT][32] bf16
    const int* __restrict__ ktab,             // [KSTEPS*4] LDS group offsets
    const float* __restrict__ bias,
    unsigned short* __restrict__ out,         // [B][Mtot][COUT] bf16
    int W, int Wp, int Mtot, int inSS, int outSS, int COUT)
{
    constexpr int Mblk = MFRAG * 64;
    constexpr int NOC  = NG * 16;
    constexpr int SEGS = NOC / 16;
    constexpr int LP   = NOC + 8;
    constexpr int CP   = CPG * 8;
    constexpr int SMEM = (SLAB * 2 > 64 * LP * 2) ? SLAB * 2 : 64 * LP * 2;
    __shared__ __align__(16) char smem[SMEM];
    unsigned short* slab = reinterpret_cast<unsigned short*>(smem);
    unsigned short* s_c  = reinterpret_cast<unsigned short*>(smem);

    const int tid  = threadIdx.x;
    const int mb   = blockIdx.x;
    const int ocb  = blockIdx.y;
    const int nl   = blockIdx.z;
    const int lane = tid & 63;
    const int wv   = tid >> 6;
    const int frow = lane & 15;
    const int fq   = lane >> 4;

    const int p0    = mb * Mblk;
    const int y0    = p0 / W;
    const int plast = (p0 + Mblk < Mtot ? p0 + Mblk : Mtot) - 1;
    const int rows  = plast / W - y0 + KH;

    const unsigned short* in_n =
        inP + (size_t)nl * inSS + (size_t)y0 * Wp * CP;
    const int nchunks = rows * Wp * CPG;
    for (int q = tid; q < nchunks; q += 256) {
        int pix = q / CPG, c8 = q - pix * CPG;
        uint4 v = reinterpret_cast<const uint4*>(in_n)[q];
        *reinterpret_cast<uint4*>(&slab[pix * CL + c8 * 8]) = v;
    }

    int ldsb[MFRAG];
    #pragma unroll
    for (int mf = 0; mf < MFRAG; ++mf) {
        int p  = p0 + mf * 64 + wv * 16 + frow;
        int pc = p < Mtot ? p : (Mtot - 1);
        int y  = pc / W;
        int x  = pc - y * W;
        ldsb[mf] = ((y - y0) * Wp + x) * CL;
    }
    const unsigned short* wbase =
        wPT + ((size_t)(ocb * NOC + frow)) * 32 + fq * 8;

    f32x4 acc[MFRAG][NG];
    #pragma unroll
    for (int mf = 0; mf < MFRAG; ++mf)
        #pragma unroll
        for (int ng = 0; ng < NG; ++ng)
            acc[mf][ng] = (f32x4){0.f, 0.f, 0.f, 0.f};

    __syncthreads();

    for (int kb = 0; kb < KSTEPS; ++kb) {
        int go = ktab[kb * 4 + fq];
        bf16x8 af[MFRAG];
        #pragma unroll
        for (int mf = 0; mf < MFRAG; ++mf)
            af[mf] = *reinterpret_cast<const bf16x8*>(&slab[ldsb[mf] + go]);
        const unsigned short* wk = wbase + (size_t)kb * COUT * 32;
        #pragma unroll
        for (int ng = 0; ng < NG; ++ng) {
            bf16x8 bf = *reinterpret_cast<const bf16x8*>(wk + ng * 16 * 32);
            #pragma unroll
            for (int mf = 0; mf < MFRAG; ++mf)
                acc[mf][ng] = __builtin_amdgcn_mfma_f32_16x16x32_bf16(
                    af[mf], bf, acc[mf][ng], 0, 0, 0);
        }
    }

    unsigned short* out_n = out + (size_t)nl * outSS;
    #pragma unroll
    for (int mf = 0; mf < MFRAG; ++mf) {
        __syncthreads();
        #pragma unroll
        for (int ng = 0; ng < NG; ++ng) {
            float bv = bias[ocb * NOC + ng * 16 + frow];
            #pragma unroll
            for (int j = 0; j < 4; ++j)
                s_c[(wv * 16 + fq * 4 + j) * LP + ng * 16 + frow] =
                    f2bf(fmaxf(acc[mf][ng][j] + bv, 0.0f));
        }
        __syncthreads();
        for (int t = tid; t < 64 * SEGS; t += 256) {
            int row = t / SEGS, seg = t % SEGS;
            int p = p0 + mf * 64 + row;
            if (p < Mtot) {
                ushort8 v0 = *reinterpret_cast<const ushort8*>(
                    &s_c[row * LP + seg * 16]);
                ushort8 v1 = *reinterpret_cast<const ushort8*>(
                    &s_c[row * LP + seg * 16 + 8]);
                unsigned short* op =
                    out_n + (size_t)p * COUT + ocb * NOC + seg * 16;
                *reinterpret_cast<ushort8*>(op) = v0;
                *reinterpret_cast<ushort8*>(op + 8) = v1;
            }
        }
    }
}

// ---------------------------------------------------------------------------
// 7) MaxPool 3x3 s2 VALID, HWC, ushort8 vector ops (post-ReLU: u16 max).
// ---------------------------------------------------------------------------
__global__ __launch_bounds__(256) void pool_k(
    const unsigned short* __restrict__ in, unsigned short* __restrict__ out,
    int CG, int C, int W, int inSS,
    int HO, int WO, int Wpo, int outSS, int total)
{
    int idx = blockIdx.x * 256 + threadIdx.x;
    if (idx >= total) return;
    int cg = idx % CG;
    int t  = idx / CG;
    int x  = t % WO;
    t /= WO;
    int y  = t % HO;
    int nl = t / HO;

    const unsigned short* pin = in + (size_t)nl * inSS + cg * 8;
    ushort8 mx = {0,0,0,0,0,0,0,0};
    #pragma unroll
    for (int dy = 0; dy < 3; ++dy)
        #pragma unroll
        for (int dx = 0; dx < 3; ++dx) {
            ushort8 v = *reinterpret_cast<const ushort8*>(
                pin + ((size_t)(2 * y + dy) * W + (2 * x + dx)) * C);
            #pragma unroll
            for (int j = 0; j < 8; ++j) mx[j] = v[j] > mx[j] ? v[j] : mx[j];
        }
    *reinterpret_cast<ushort8*>(
        out + (size_t)nl * outSS +
        ((size_t)(y + 1) * Wpo + (x + 1)) * C + cg * 8) = mx;
}

// ---------------------------------------------------------------------------
// 8) Fused pool2 (3x3 s2 on [17][17][256]) + global average pool -> fp32
// ---------------------------------------------------------------------------
__global__ __launch_bounds__(512) void pool2gap_k(
    const unsigned short* __restrict__ in, float* __restrict__ out,
    int inSS, int n0)
{
    __shared__ float part[256];
    const int nl = blockIdx.x;
    const int c    = threadIdx.x & 255;
    const int half = threadIdx.x >> 8;
    const unsigned short* p = in + (size_t)nl * inSS + c;
    float s = 0.0f;
    for (int w = half * 32; w < half * 32 + 32; ++w) {
        int y = w >> 3, x = w & 7;
        unsigned short mx = 0;
        #pragma unroll
        for (int dy = 0; dy < 3; ++dy)
            #pragma unroll
            for (int dx = 0; dx < 3; ++dx) {
                unsigned short v = p[((size_t)(2*y+dy) * 17 + (2*x+dx)) * 256];
                mx = v > mx ? v : mx;
            }
        s += bf2f(mx);
    }
    if (half) part[c] = s;
    __syncthreads();
    if (!half) out[(size_t)(n0 + nl) * 256 + c] = (s + part[c]) * (1.0f / 64.0f);
}

// ---------------------------------------------------------------------------
// 9) FC weight transpose: w[o][i] -> wT[i][o]
// ---------------------------------------------------------------------------
__global__ __launch_bounds__(256) void fcT_k(
    const float* __restrict__ w, float* __restrict__ wT, int O, int I, int total)
{
    int idx = blockIdx.x * 256 + threadIdx.x;
    if (idx >= total) return;
    int i = idx % I, o = idx / I;
    wT[(size_t)i * O + o] = w[idx];
}

// ---------------------------------------------------------------------------
// 10) Fused 3-layer FC head (256->512->256->512), one block per sample
// ---------------------------------------------------------------------------
__global__ __launch_bounds__(256) void fc_fused_k(
    const float* __restrict__ in,
    const float* __restrict__ w0T, const float* __restrict__ b0,
    const float* __restrict__ w1T, const float* __restrict__ b1,
    const float* __restrict__ w2T, const float* __restrict__ b2,
    float* __restrict__ out)
{
    __shared__ float s_in[256], s_h0[512], s_h1[256];
    const int n = blockIdx.x, t = threadIdx.x;
    s_in[t] = in[(size_t)n * 256 + t];
    __syncthreads();
    float a0 = 0.f, a1 = 0.f;
    for (int i = 0; i < 256; ++i) {
        float v = s_in[i];
        a0 += v * w0T[i * 512 + t];
        a1 += v * w0T[i * 512 + t + 256];
    }
    s_h0[t]       = fmaxf(a0 + b0[t], 0.0f);
    s_h0[t + 256] = fmaxf(a1 + b0[t + 256], 0.0f);
    __syncthreads();
    float h = 0.f;
    for (int i = 0; i < 512; ++i) h += s_h0[i] * w1T[i * 256 + t];
    s_h1[t] = fmaxf(h + b1[t], 0.0f);
    __syncthreads();
    a0 = 0.f; a1 = 0.f;
    for (int i = 0; i < 256; ++i) {
        float v = s_h1[i];
        a0 += v * w2T[i * 512 + t];
        a1 += v * w2T[i * 512 + t + 256];
    }
    out[(size_t)n * 512 + t]       = a0 + b2[t];
    out[(size_t)n * 512 + t + 256] = a1 + b2[t + 256];
}

// ---------------------------------------------------------------------------
// Launch. Per-sample u16 sizes (HWC):
//   A: G [76][76][40] = 231,040   (overlay: C1 [1225][128]=156,800)
//   B: C0 [5184][64]  = 331,776   (overlay: C2 [289][256]=73,984)
//   C: P0p [37][37][64]=87,616 + P1p [19][19][128]=46,208 = 133,824
// ---------------------------------------------------------------------------
extern "C" void kernel_launch(void* const* d_in, const int* in_sizes, int n_in,
                              void* d_out, int out_size, void* d_ws, size_t ws_size,
                              hipStream_t stream)
{
    const int*   X   = (const int*)d_in[0];
    const int*   rm  = (const int*)d_in[1];
    const float* emb = (const float*)d_in[2];
    const float* cw0 = (const float*)d_in[3];
    const float* cb0 = (const float*)d_in[4];
    const float* cw1 = (const float*)d_in[5];
    const float* cb1 = (const float*)d_in[6];
    const float* cw2 = (const float*)d_in[7];
    const float* cb2 = (const float*)d_in[8];
    const float* fw0 = (const float*)d_in[9];
    const float* fb0 = (const float*)d_in[10];
    const float* fw1 = (const float*)d_in[11];
    const float* fb1 = (const float*)d_in[12];
    const float* fw2 = (const float*)d_in[13];
    const float* fb2 = (const float*)d_in[14];
    float* out = (float*)d_out;

    char* p = (char*)d_ws;
    auto alloc = [&](size_t bytes) -> char* {
        char* r = p; p += (bytes + 255) & ~(size_t)255; return r;
    };
    unsigned short* WP0 = (unsigned short*)alloc((size_t)32 * 64 * 32 * 2);
    unsigned short* WP1 = (unsigned short*)alloc((size_t)18 * 128 * 32 * 2);
    unsigned short* WP2 = (unsigned short*)alloc((size_t)36 * 256 * 32 * 2);
    int* KT0 = (int*)alloc(128 * 4);
    int* KT1 = (int*)alloc(72 * 4);
    int* KT2 = (int*)alloc(144 * 4);
    unsigned long long* MASKS = (unsigned long long*)alloc(RR * 8);
    float* W0T  = (float*)alloc((size_t)256 * 512 * 4);
    float* W1T  = (float*)alloc((size_t)512 * 256 * 4);
    float* W2T  = (float*)alloc((size_t)256 * 512 * 4);
    float* GAPB = (float*)alloc((size_t)NB * 256 * 4);
    size_t fixed_bytes = (size_t)(p - (char*)d_ws);

    const size_t A_FL = 231040, B_FL = 331776, C_FL = 133824;   // u16
    const size_t per_sample = (A_FL + B_FL + C_FL) * 2 + 768;
    int Bc = 128;
    while (Bc > 1 && fixed_bytes + (size_t)Bc * per_sample > ws_size) Bc >>= 1;

    unsigned short* bufA = (unsigned short*)alloc((size_t)Bc * A_FL * 2);
    unsigned short* bufC = (unsigned short*)alloc((size_t)Bc * C_FL * 2);
    unsigned short* bufB = (unsigned short*)alloc((size_t)Bc * B_FL * 2);

    // ---- one-time prep (runs every call; graph-safe) ----
    build_masks_k<<<2, 256, 0, stream>>>(rm, MASKS);
    wpack_k<<<(32 * 64 * 32 + 255) / 256, 256, 0, stream>>>(
        cw0, WP0, 64, 33, 25, 5, 32 * 64 * 32);
    wpack_k<<<(18 * 128 * 32 + 255) / 256, 256, 0, stream>>>(
        cw1, WP1, 128, 64, 9, 8, 18 * 128 * 32);
    wpack_k<<<(36 * 256 * 32 + 255) / 256, 256, 0, stream>>>(
        cw2, WP2, 256, 128, 9, 16, 36 * 256 * 32);
    ktab_all_k<<<dim3(1, 3), 256, 0, stream>>>(KT0, KT1, KT2);
    fcT_k<<<(512 * 256 + 255) / 256, 256, 0, stream>>>(fw0, W0T, 512, 256, 512 * 256);
    fcT_k<<<(256 * 512 + 255) / 256, 256, 0, stream>>>(fw1, W1T, 256, 512, 256 * 512);
    fcT_k<<<(512 * 256 + 255) / 256, 256, 0, stream>>>(fw2, W2T, 512, 256, 512 * 256);

    // ---- chunked pipeline ----
    for (int n0 = 0; n0 < NB; n0 += Bc) {
        size_t n16 = (size_t)Bc * (A_FL + C_FL) * 2 / 16;
        fillz_k<<<4096, 256, 0, stream>>>((uint4*)bufA, n16);

        // encode -> A (HWC G [76][76][40], interior +2)
        encode_k<<<dim3(Bc, 18), 320, 0, stream>>>(X, MASKS, emb, bufA, n0, (int)A_FL);

        // conv0: A -> B  (25 16x16 tiles/sample, COUT=64, 32 ksteps)
        conv0_tile_k<32><<<dim3(25, Bc), 256, 0, stream>>>(
            bufA, WP0, KT0, cb0, bufB, (int)A_FL, (int)B_FL);
        // pool0: B [72][72][64] -> C P0p [37][37][64] interior +1
        pool_k<<<(Bc * 35 * 35 * 8 + 255) / 256, 256, 0, stream>>>(
            bufB, bufC, 8, 64, 72, (int)B_FL,
            35, 35, 37, (int)C_FL, Bc * 35 * 35 * 8);

        // conv1: C -> A  (M=1225, Mblk=256 -> 5 mblocks, COUT=128)
        conv_mfma_k<4, 8, 3, 8, 72, 29304, 18><<<dim3(5, 1, Bc), 256, 0, stream>>>(
            bufC, WP1, KT1, cb1, bufA, 35, 37,
            1225, (int)C_FL, (int)A_FL, 128);
        // pool1: A [35][35][128] -> C+87616 P1p [19][19][128] interior +1
        pool_k<<<(Bc * 17 * 17 * 16 + 255) / 256, 256, 0, stream>>>(
            bufA, bufC + 87616, 16, 128, 35, (int)A_FL,
            17, 17, 19, (int)C_FL, Bc * 17 * 17 * 16);

        // conv2: C+87616 -> B  (M=289, Mblk=128 -> 3 mblocks, 2 oc-blocks)
        conv_mfma_k<2, 8, 3, 16, 136, 28424, 36><<<dim3(3, 2, Bc), 256, 0, stream>>>(
            bufC + 87616, WP2, KT2, cb2, bufB, 17, 19,
            289, (int)C_FL, (int)B_FL, 256);

        // fused pool2 + GAP: B [17][17][256] -> GAPB fp32
        pool2gap_k<<<Bc, 512, 0, stream>>>(bufB, GAPB, (int)B_FL, n0);
    }

    // fused FC head
    fc_fused_k<<<NB, 256, 0, stream>>>(GAPB, W0T, fb0, W1T, fb1, W2T, fb2, out);
}

// Round 8
// 648.174 us; speedup vs baseline: 1.5336x; 1.0603x over previous
//
#include <hip/hip_runtime.h>
#include <hip/hip_bf16.h>
#include <cstdint>
#include <cstddef>

#define NB      128
#define RR      300
#define EMB     32

typedef __bf16 bf16x8 __attribute__((ext_vector_type(8)));
typedef float  f32x4  __attribute__((ext_vector_type(4)));
typedef unsigned short ushort8 __attribute__((ext_vector_type(8)));

__device__ __forceinline__ unsigned short f2bf(float f) {
    union { __hip_bfloat16 h; unsigned short u; } c;
    c.h = __float2bfloat16(f);
    return c.u;
}
__device__ __forceinline__ float bf2f(unsigned short u) {
    union { __hip_bfloat16 h; unsigned short u; } c;
    c.u = u;
    return __bfloat162float(c.h);
}

// ---------------------------------------------------------------------------
// 1) Room occupancy -> uint64 bitmask (bit b = dx*8+dy)
// ---------------------------------------------------------------------------
__global__ __launch_bounds__(256) void build_masks_k(
    const int* __restrict__ rm, unsigned long long* __restrict__ masks)
{
    int r = blockIdx.x * 256 + threadIdx.x;
    if (r >= RR) return;
    unsigned long long m = 0ull;
    #pragma unroll
    for (int b = 0; b < 64; ++b)
        if (rm[r * 64 + b]) m |= (1ull << b);
    masks[r] = m;
}

// ---------------------------------------------------------------------------
// 2) Zero-fill (uint4 grid-stride)
// ---------------------------------------------------------------------------
__global__ __launch_bounds__(256) void fillz_k(uint4* __restrict__ p, size_t n16)
{
    uint4 z = make_uint4(0, 0, 0, 0);
    for (size_t i = blockIdx.x * 256ull + threadIdx.x; i < n16;
         i += (size_t)gridDim.x * 256ull)
        p[i] = z;
}

// ---------------------------------------------------------------------------
// 3) Encode, banded HWC with LDS room cache + hot bitmap.
//    Phase 1: coalesced preload of pos/mask to LDS; per-wave ballot of the
//    band-hot predicate into a 5-word bitmap.
//    Phase 2: ctz-walk only hot rooms (~46/band), all operands from LDS.
//    Write-out: bf16 HWC via uint2 (4ch) stores to G[76][76][40] (+2 halo).
// ---------------------------------------------------------------------------
__global__ __launch_bounds__(320) void encode_k(
    const int* __restrict__ X, const unsigned long long* __restrict__ masks,
    const float* __restrict__ emb, unsigned short* __restrict__ G,
    int n0, int sampleStride)
{
    __shared__ float tile[4][72][33];
    __shared__ unsigned s_pos[RR];
    __shared__ unsigned long long s_mask[RR];
    __shared__ unsigned long long s_hot[5];

    const int nl = blockIdx.x, band = blockIdx.y;
    const int by = band * 4;
    const int n  = n0 + nl;
    const int tid = threadIdx.x;

    float* tf = &tile[0][0][0];
    for (int i = tid; i < 4 * 72 * 33; i += 320) tf[i] = 0.0f;

    // phase 1: preload rooms, ballot hot predicate
    const int2* Xp = reinterpret_cast<const int2*>(X);
    bool hot = false;
    if (tid < RR) {
        int2 pos = Xp[n * RR + tid];
        s_pos[tid]  = (unsigned)pos.x | ((unsigned)pos.y << 16);
        s_mask[tid] = masks[tid];
        hot = (pos.y <= by + 3) && (pos.y + 7 >= by);
    }
    unsigned long long bal = __ballot(hot);
    if ((tid & 63) == 0) s_hot[tid >> 6] = bal;
    __syncthreads();

    // phase 2: walk hot rooms only
    const int dx = tid / 33;
    const int c  = tid - dx * 33;
    for (int w = 0; w < 5; ++w) {
        unsigned long long hm = s_hot[w];
        while (hm) {
            int b = __builtin_ctzll(hm);
            hm &= (hm - 1);
            int r = w * 64 + b;
            unsigned pxy = s_pos[r];
            int px = pxy & 0xffff, py = pxy >> 16;
            if (tid < 264) {
                float s = (c == 0) ? 1.0f : emb[r * EMB + (c - 1)];
                unsigned long long mm = s_mask[r] >> (dx * 8);
                int x = px + dx;
                #pragma unroll
                for (int dyb = 0; dyb < 4; ++dyb) {
                    int dyr = by + dyb - py;
                    if ((unsigned)dyr < 8u && ((mm >> dyr) & 1ull))
                        atomicAdd(&tile[dyb][x][c], s);
                }
            }
        }
    }
    __syncthreads();

    // write-out: 4 rows x 72 px x 40ch as uint2 (4ch) chunks
    unsigned short* Gn = G + (size_t)nl * sampleStride;
    for (int i = tid; i < 4 * 72 * 10; i += 320) {
        int cc = i % 10;
        int t  = i / 10;
        int x  = t % 72;
        int dyb = t / 72;
        int c0 = cc * 4;
        unsigned short r[4];
        #pragma unroll
        for (int j = 0; j < 4; ++j)
            r[j] = (c0 + j < 33) ? f2bf(tile[dyb][x][c0 + j]) : 0;
        uint2 pk;
        pk.x = (unsigned)r[0] | ((unsigned)r[1] << 16);
        pk.y = (unsigned)r[2] | ((unsigned)r[3] << 16);
        *reinterpret_cast<uint2*>(
            &Gn[((size_t)(by + dyb + 2) * 76 + (x + 2)) * 40 + c0]) = pk;
    }
}

// ---------------------------------------------------------------------------
// 4) Weight pack: w[oc][ci][K][K] fp32 -> bf16 wPT[kb][oc][32] with
//    k = (ky*K+kx)*Cpad + ci ordering, grouped 8-ci; zero-padded.
// ---------------------------------------------------------------------------
__global__ __launch_bounds__(256) void wpack_k(
    const float* __restrict__ w, unsigned short* __restrict__ wPT,
    int COUT, int CIN, int KK, int gpc, int total)
{
    int idx = blockIdx.x * 256 + threadIdx.x;
    if (idx >= total) return;
    int kk = idx & 31;
    int t  = idx >> 5;
    int oc = t % COUT;
    int kb = t / COUT;
    int g  = kb * 4 + (kk >> 3);
    int j  = kk & 7;
    int shift = g / gpc;
    int ci    = (g % gpc) * 8 + j;
    float v = (shift < KK && ci < CIN)
        ? w[(size_t)oc * CIN * KK + (size_t)ci * KK + shift] : 0.0f;
    wPT[idx] = f2bf(v);
}

// ---------------------------------------------------------------------------
// 5) ktab: LDS-space group offsets (elem units). Entry 0 uses LDS pixel
//    pitch 20 (conv0 2D tile); entries 1/2 use row-slab pitches.
// ---------------------------------------------------------------------------
__global__ __launch_bounds__(256) void ktab_all_k(
    int* __restrict__ kt0, int* __restrict__ kt1, int* __restrict__ kt2)
{
    int t = threadIdx.x;
    int which = blockIdx.y;
    int ngr, gpc, K, Wp, CL;
    int* dst;
    if (which == 0)      { ngr = 128; gpc = 5;  K = 5; Wp = 20; CL = 40;  dst = kt0; }
    else if (which == 1) { ngr = 72;  gpc = 8;  K = 3; Wp = 37; CL = 72;  dst = kt1; }
    else                 { ngr = 144; gpc = 16; K = 3; Wp = 19; CL = 136; dst = kt2; }
    if (t >= ngr) return;
    int shift = t / gpc;
    int off = 0;
    if (shift < K * K) {
        int ky = shift / K, kx = shift % K;
        off = (ky * Wp + kx) * CL + (t % gpc) * 8;
    }
    dst[t] = off;
}

// ---------------------------------------------------------------------------
// 6a) conv0: dedicated 16x16-spatial-tile implicit-GEMM, bf16 MFMA 16x16x32.
//     M=256 (16 tile rows x 16 cols), NOC=64 (all ocs), slab 20x20x40 = 32KB
//     staged once (linear dst). No barriers in K-loop.
// ---------------------------------------------------------------------------
template<int KSTEPS>
__global__ __launch_bounds__(256) void conv0_tile_k(
    const unsigned short* __restrict__ inP,   // [B][76][76][40] bf16
    const unsigned short* __restrict__ wPT,   // [KSTEPS][64][32] bf16
    const int* __restrict__ ktab,             // [KSTEPS*4] LDS offsets
    const float* __restrict__ bias,
    unsigned short* __restrict__ out,         // [B][5184][64] bf16
    int inSS, int outSS)
{
    constexpr int CL = 40;
    constexpr int LP = 72;
    __shared__ __align__(16) unsigned short slab[20 * 20 * CL];  // 32000 B
    unsigned short* s_c = slab;

    const int tid = threadIdx.x;
    const int tl  = blockIdx.x;           // 0..24
    const int nl  = blockIdx.y;
    const int tyi = tl / 5, txi = tl % 5;
    const int y0 = tyi < 4 ? tyi * 16 : 56;
    const int x0 = txi < 4 ? txi * 16 : 56;

    const int lane = tid & 63, wv = tid >> 6, frow = lane & 15, fq = lane >> 4;

    const unsigned short* in_n = inP + (size_t)nl * inSS;
    {
        const uint4* src = reinterpret_cast<const uint4*>(in_n);
        uint4* dst = reinterpret_cast<uint4*>(slab);
        #pragma unroll
        for (int it = 0; it < 8; ++it) {
            int q = tid + it * 256;
            if (q < 2000) {
                int r = q / 100, c = q - r * 100;     // row, 16B-chunk in row
                dst[q] = src[((y0 + r) * 76 + x0) * 5 + c];
            }
        }
    }

    int ldsb[4];
    #pragma unroll
    for (int mf = 0; mf < 4; ++mf)
        ldsb[mf] = ((mf * 4 + wv) * 20 + frow) * CL;   // pixel (ty, tx=frow)

    const unsigned short* wbase = wPT + (size_t)frow * 32 + fq * 8;

    f32x4 acc[4][4];
    #pragma unroll
    for (int a = 0; a < 4; ++a)
        #pragma unroll
        for (int b = 0; b < 4; ++b) acc[a][b] = (f32x4){0.f, 0.f, 0.f, 0.f};

    __syncthreads();

    #pragma unroll 2
    for (int kb = 0; kb < KSTEPS; ++kb) {
        int go = ktab[kb * 4 + fq];
        bf16x8 af[4];
        #pragma unroll
        for (int mf = 0; mf < 4; ++mf)
            af[mf] = *reinterpret_cast<const bf16x8*>(&slab[ldsb[mf] + go]);
        const unsigned short* wk = wbase + (size_t)kb * 64 * 32;
        #pragma unroll
        for (int ng = 0; ng < 4; ++ng) {
            bf16x8 bf = *reinterpret_cast<const bf16x8*>(wk + ng * 16 * 32);
            #pragma unroll
            for (int mf = 0; mf < 4; ++mf)
                acc[mf][ng] = __builtin_amdgcn_mfma_f32_16x16x32_bf16(
                    af[mf], bf, acc[mf][ng], 0, 0, 0);
        }
    }

    unsigned short* out_n = out + (size_t)nl * outSS;
    const int erow = tid >> 2, eseg = tid & 3;        // 64 rows x 4 segs
    #pragma unroll
    for (int mf = 0; mf < 4; ++mf) {
        __syncthreads();
        #pragma unroll
        for (int ng = 0; ng < 4; ++ng) {
            float bv = bias[ng * 16 + frow];
            #pragma unroll
            for (int j = 0; j < 4; ++j)
                s_c[(wv * 16 + fq * 4 + j) * LP + ng * 16 + frow] =
                    f2bf(fmaxf(acc[mf][ng][j] + bv, 0.0f));
        }
        __syncthreads();
        {
            int ty = mf * 4 + (erow >> 4);
            int tx = erow & 15;
            int pos = (y0 + ty) * 72 + (x0 + tx);
            ushort8 v0 = *reinterpret_cast<const ushort8*>(
                &s_c[erow * LP + eseg * 16]);
            ushort8 v1 = *reinterpret_cast<const ushort8*>(
                &s_c[erow * LP + eseg * 16 + 8]);
            unsigned short* op = out_n + (size_t)pos * 64 + eseg * 16;
            *reinterpret_cast<ushort8*>(op) = v0;
            *reinterpret_cast<ushort8*>(op + 8) = v1;
        }
    }
}

// ---------------------------------------------------------------------------
// 6b) Generic row-slab implicit-GEMM conv (conv1/conv2), bf16 MFMA 16x16x32.
// ---------------------------------------------------------------------------
template<int MFRAG, int NG, int KH, int CPG, int CL, int SLAB, int KSTEPS>
__global__ __launch_bounds__(256) void conv_mfma_k(
    const unsigned short* __restrict__ inP,   // [B][Hp][Wp][Cp] bf16
    const unsigned short* __restrict__ wPT,   // [KSTEPS][COUT][32] bf16
    const int* __restrict__ ktab,             // [KSTEPS*4] LDS group offsets
    const float* __restrict__ bias,
    unsigned short* __restrict__ out,         // [B][Mtot][COUT] bf16
    int W, int Wp, int Mtot, int inSS, int outSS, int COUT)
{
    constexpr int Mblk = MFRAG * 64;
    constexpr int NOC  = NG * 16;
    constexpr int SEGS = NOC / 16;
    constexpr int LP   = NOC + 8;
    constexpr int CP   = CPG * 8;
    constexpr int SMEM = (SLAB * 2 > 64 * LP * 2) ? SLAB * 2 : 64 * LP * 2;
    __shared__ __align__(16) char smem[SMEM];
    unsigned short* slab = reinterpret_cast<unsigned short*>(smem);
    unsigned short* s_c  = reinterpret_cast<unsigned short*>(smem);

    const int tid  = threadIdx.x;
    const int mb   = blockIdx.x;
    const int ocb  = blockIdx.y;
    const int nl   = blockIdx.z;
    const int lane = tid & 63;
    const int wv   = tid >> 6;
    const int frow = lane & 15;
    const int fq   = lane >> 4;

    const int p0    = mb * Mblk;
    const int y0    = p0 / W;
    const int plast = (p0 + Mblk < Mtot ? p0 + Mblk : Mtot) - 1;
    const int rows  = plast / W - y0 + KH;

    const unsigned short* in_n =
        inP + (size_t)nl * inSS + (size_t)y0 * Wp * CP;
    const int nchunks = rows * Wp * CPG;
    for (int q = tid; q < nchunks; q += 256) {
        int pix = q / CPG, c8 = q - pix * CPG;
        uint4 v = reinterpret_cast<const uint4*>(in_n)[q];
        *reinterpret_cast<uint4*>(&slab[pix * CL + c8 * 8]) = v;
    }

    int ldsb[MFRAG];
    #pragma unroll
    for (int mf = 0; mf < MFRAG; ++mf) {
        int p  = p0 + mf * 64 + wv * 16 + frow;
        int pc = p < Mtot ? p : (Mtot - 1);
        int y  = pc / W;
        int x  = pc - y * W;
        ldsb[mf] = ((y - y0) * Wp + x) * CL;
    }
    const unsigned short* wbase =
        wPT + ((size_t)(ocb * NOC + frow)) * 32 + fq * 8;

    f32x4 acc[MFRAG][NG];
    #pragma unroll
    for (int mf = 0; mf < MFRAG; ++mf)
        #pragma unroll
        for (int ng = 0; ng < NG; ++ng)
            acc[mf][ng] = (f32x4){0.f, 0.f, 0.f, 0.f};

    __syncthreads();

    for (int kb = 0; kb < KSTEPS; ++kb) {
        int go = ktab[kb * 4 + fq];
        bf16x8 af[MFRAG];
        #pragma unroll
        for (int mf = 0; mf < MFRAG; ++mf)
            af[mf] = *reinterpret_cast<const bf16x8*>(&slab[ldsb[mf] + go]);
        const unsigned short* wk = wbase + (size_t)kb * COUT * 32;
        #pragma unroll
        for (int ng = 0; ng < NG; ++ng) {
            bf16x8 bf = *reinterpret_cast<const bf16x8*>(wk + ng * 16 * 32);
            #pragma unroll
            for (int mf = 0; mf < MFRAG; ++mf)
                acc[mf][ng] = __builtin_amdgcn_mfma_f32_16x16x32_bf16(
                    af[mf], bf, acc[mf][ng], 0, 0, 0);
        }
    }

    unsigned short* out_n = out + (size_t)nl * outSS;
    #pragma unroll
    for (int mf = 0; mf < MFRAG; ++mf) {
        __syncthreads();
        #pragma unroll
        for (int ng = 0; ng < NG; ++ng) {
            float bv = bias[ocb * NOC + ng * 16 + frow];
            #pragma unroll
            for (int j = 0; j < 4; ++j)
                s_c[(wv * 16 + fq * 4 + j) * LP + ng * 16 + frow] =
                    f2bf(fmaxf(acc[mf][ng][j] + bv, 0.0f));
        }
        __syncthreads();
        for (int t = tid; t < 64 * SEGS; t += 256) {
            int row = t / SEGS, seg = t % SEGS;
            int p = p0 + mf * 64 + row;
            if (p < Mtot) {
                ushort8 v0 = *reinterpret_cast<const ushort8*>(
                    &s_c[row * LP + seg * 16]);
                ushort8 v1 = *reinterpret_cast<const ushort8*>(
                    &s_c[row * LP + seg * 16 + 8]);
                unsigned short* op =
                    out_n + (size_t)p * COUT + ocb * NOC + seg * 16;
                *reinterpret_cast<ushort8*>(op) = v0;
                *reinterpret_cast<ushort8*>(op + 8) = v1;
            }
        }
    }
}

// ---------------------------------------------------------------------------
// 7) MaxPool 3x3 s2 VALID, HWC, ushort8 vector ops (post-ReLU: u16 max).
// ---------------------------------------------------------------------------
__global__ __launch_bounds__(256) void pool_k(
    const unsigned short* __restrict__ in, unsigned short* __restrict__ out,
    int CG, int C, int W, int inSS,
    int HO, int WO, int Wpo, int outSS, int total)
{
    int idx = blockIdx.x * 256 + threadIdx.x;
    if (idx >= total) return;
    int cg = idx % CG;
    int t  = idx / CG;
    int x  = t % WO;
    t /= WO;
    int y  = t % HO;
    int nl = t / HO;

    const unsigned short* pin = in + (size_t)nl * inSS + cg * 8;
    ushort8 mx = {0,0,0,0,0,0,0,0};
    #pragma unroll
    for (int dy = 0; dy < 3; ++dy)
        #pragma unroll
        for (int dx = 0; dx < 3; ++dx) {
            ushort8 v = *reinterpret_cast<const ushort8*>(
                pin + ((size_t)(2 * y + dy) * W + (2 * x + dx)) * C);
            #pragma unroll
            for (int j = 0; j < 8; ++j) mx[j] = v[j] > mx[j] ? v[j] : mx[j];
        }
    *reinterpret_cast<ushort8*>(
        out + (size_t)nl * outSS +
        ((size_t)(y + 1) * Wpo + (x + 1)) * C + cg * 8) = mx;
}

// ---------------------------------------------------------------------------
// 8) Fused pool2 (3x3 s2 on [17][17][256]) + global average pool -> fp32
// ---------------------------------------------------------------------------
__global__ __launch_bounds__(512) void pool2gap_k(
    const unsigned short* __restrict__ in, float* __restrict__ out,
    int inSS, int n0)
{
    __shared__ float part[256];
    const int nl = blockIdx.x;
    const int c    = threadIdx.x & 255;
    const int half = threadIdx.x >> 8;
    const unsigned short* p = in + (size_t)nl * inSS + c;
    float s = 0.0f;
    for (int w = half * 32; w < half * 32 + 32; ++w) {
        int y = w >> 3, x = w & 7;
        unsigned short mx = 0;
        #pragma unroll
        for (int dy = 0; dy < 3; ++dy)
            #pragma unroll
            for (int dx = 0; dx < 3; ++dx) {
                unsigned short v = p[((size_t)(2*y+dy) * 17 + (2*x+dx)) * 256];
                mx = v > mx ? v : mx;
            }
        s += bf2f(mx);
    }
    if (half) part[c] = s;
    __syncthreads();
    if (!half) out[(size_t)(n0 + nl) * 256 + c] = (s + part[c]) * (1.0f / 64.0f);
}

// ---------------------------------------------------------------------------
// 9) FC weight transpose: w[o][i] -> wT[i][o]
// ---------------------------------------------------------------------------
__global__ __launch_bounds__(256) void fcT_k(
    const float* __restrict__ w, float* __restrict__ wT, int O, int I, int total)
{
    int idx = blockIdx.x * 256 + threadIdx.x;
    if (idx >= total) return;
    int i = idx % I, o = idx / I;
    wT[(size_t)i * O + o] = w[idx];
}

// ---------------------------------------------------------------------------
// 10) Fused 3-layer FC head (256->512->256->512), one block per sample
// ---------------------------------------------------------------------------
__global__ __launch_bounds__(256) void fc_fused_k(
    const float* __restrict__ in,
    const float* __restrict__ w0T, const float* __restrict__ b0,
    const float* __restrict__ w1T, const float* __restrict__ b1,
    const float* __restrict__ w2T, const float* __restrict__ b2,
    float* __restrict__ out)
{
    __shared__ float s_in[256], s_h0[512], s_h1[256];
    const int n = blockIdx.x, t = threadIdx.x;
    s_in[t] = in[(size_t)n * 256 + t];
    __syncthreads();
    float a0 = 0.f, a1 = 0.f;
    for (int i = 0; i < 256; ++i) {
        float v = s_in[i];
        a0 += v * w0T[i * 512 + t];
        a1 += v * w0T[i * 512 + t + 256];
    }
    s_h0[t]       = fmaxf(a0 + b0[t], 0.0f);
    s_h0[t + 256] = fmaxf(a1 + b0[t + 256], 0.0f);
    __syncthreads();
    float h = 0.f;
    for (int i = 0; i < 512; ++i) h += s_h0[i] * w1T[i * 256 + t];
    s_h1[t] = fmaxf(h + b1[t], 0.0f);
    __syncthreads();
    a0 = 0.f; a1 = 0.f;
    for (int i = 0; i < 256; ++i) {
        float v = s_h1[i];
        a0 += v * w2T[i * 512 + t];
        a1 += v * w2T[i * 512 + t + 256];
    }
    out[(size_t)n * 512 + t]       = a0 + b2[t];
    out[(size_t)n * 512 + t + 256] = a1 + b2[t + 256];
}

// ---------------------------------------------------------------------------
// Launch. Per-sample u16 sizes (HWC):
//   A: G [76][76][40] = 231,040   (overlay: C1 [1225][128]=156,800)
//   B: C0 [5184][64]  = 331,776   (overlay: C2 [289][256]=73,984)
//   C: P0p [37][37][64]=87,616 + P1p [19][19][128]=46,208 = 133,824
// ---------------------------------------------------------------------------
extern "C" void kernel_launch(void* const* d_in, const int* in_sizes, int n_in,
                              void* d_out, int out_size, void* d_ws, size_t ws_size,
                              hipStream_t stream)
{
    const int*   X   = (const int*)d_in[0];
    const int*   rm  = (const int*)d_in[1];
    const float* emb = (const float*)d_in[2];
    const float* cw0 = (const float*)d_in[3];
    const float* cb0 = (const float*)d_in[4];
    const float* cw1 = (const float*)d_in[5];
    const float* cb1 = (const float*)d_in[6];
    const float* cw2 = (const float*)d_in[7];
    const float* cb2 = (const float*)d_in[8];
    const float* fw0 = (const float*)d_in[9];
    const float* fb0 = (const float*)d_in[10];
    const float* fw1 = (const float*)d_in[11];
    const float* fb1 = (const float*)d_in[12];
    const float* fw2 = (const float*)d_in[13];
    const float* fb2 = (const float*)d_in[14];
    float* out = (float*)d_out;

    char* p = (char*)d_ws;
    auto alloc = [&](size_t bytes) -> char* {
        char* r = p; p += (bytes + 255) & ~(size_t)255; return r;
    };
    unsigned short* WP0 = (unsigned short*)alloc((size_t)32 * 64 * 32 * 2);
    unsigned short* WP1 = (unsigned short*)alloc((size_t)18 * 128 * 32 * 2);
    unsigned short* WP2 = (unsigned short*)alloc((size_t)36 * 256 * 32 * 2);
    int* KT0 = (int*)alloc(128 * 4);
    int* KT1 = (int*)alloc(72 * 4);
    int* KT2 = (int*)alloc(144 * 4);
    unsigned long long* MASKS = (unsigned long long*)alloc(RR * 8);
    float* W0T  = (float*)alloc((size_t)256 * 512 * 4);
    float* W1T  = (float*)alloc((size_t)512 * 256 * 4);
    float* W2T  = (float*)alloc((size_t)256 * 512 * 4);
    float* GAPB = (float*)alloc((size_t)NB * 256 * 4);
    size_t fixed_bytes = (size_t)(p - (char*)d_ws);

    const size_t A_FL = 231040, B_FL = 331776, C_FL = 133824;   // u16
    const size_t per_sample = (A_FL + B_FL + C_FL) * 2 + 768;
    int Bc = 128;
    while (Bc > 1 && fixed_bytes + (size_t)Bc * per_sample > ws_size) Bc >>= 1;

    unsigned short* bufA = (unsigned short*)alloc((size_t)Bc * A_FL * 2);
    unsigned short* bufC = (unsigned short*)alloc((size_t)Bc * C_FL * 2);
    unsigned short* bufB = (unsigned short*)alloc((size_t)Bc * B_FL * 2);

    // ---- one-time prep (runs every call; graph-safe) ----
    build_masks_k<<<2, 256, 0, stream>>>(rm, MASKS);
    wpack_k<<<(32 * 64 * 32 + 255) / 256, 256, 0, stream>>>(
        cw0, WP0, 64, 33, 25, 5, 32 * 64 * 32);
    wpack_k<<<(18 * 128 * 32 + 255) / 256, 256, 0, stream>>>(
        cw1, WP1, 128, 64, 9, 8, 18 * 128 * 32);
    wpack_k<<<(36 * 256 * 32 + 255) / 256, 256, 0, stream>>>(
        cw2, WP2, 256, 128, 9, 16, 36 * 256 * 32);
    ktab_all_k<<<dim3(1, 3), 256, 0, stream>>>(KT0, KT1, KT2);
    fcT_k<<<(512 * 256 + 255) / 256, 256, 0, stream>>>(fw0, W0T, 512, 256, 512 * 256);
    fcT_k<<<(256 * 512 + 255) / 256, 256, 0, stream>>>(fw1, W1T, 256, 512, 256 * 512);
    fcT_k<<<(512 * 256 + 255) / 256, 256, 0, stream>>>(fw2, W2T, 512, 256, 512 * 256);

    // ---- chunked pipeline ----
    for (int n0 = 0; n0 < NB; n0 += Bc) {
        size_t n16 = (size_t)Bc * (A_FL + C_FL) * 2 / 16;
        fillz_k<<<4096, 256, 0, stream>>>((uint4*)bufA, n16);

        // encode -> A (HWC G [76][76][40], interior +2)
        encode_k<<<dim3(Bc, 18), 320, 0, stream>>>(X, MASKS, emb, bufA, n0, (int)A_FL);

        // conv0: A -> B  (25 16x16 tiles/sample, COUT=64, 32 ksteps)
        conv0_tile_k<32><<<dim3(25, Bc), 256, 0, stream>>>(
            bufA, WP0, KT0, cb0, bufB, (int)A_FL, (int)B_FL);
        // pool0: B [72][72][64] -> C P0p [37][37][64] interior +1
        pool_k<<<(Bc * 35 * 35 * 8 + 255) / 256, 256, 0, stream>>>(
            bufB, bufC, 8, 64, 72, (int)B_FL,
            35, 35, 37, (int)C_FL, Bc * 35 * 35 * 8);

        // conv1: C -> A  (M=1225, Mblk=256 -> 5 mblocks, COUT=128)
        conv_mfma_k<4, 8, 3, 8, 72, 29304, 18><<<dim3(5, 1, Bc), 256, 0, stream>>>(
            bufC, WP1, KT1, cb1, bufA, 35, 37,
            1225, (int)C_FL, (int)A_FL, 128);
        // pool1: A [35][35][128] -> C+87616 P1p [19][19][128] interior +1
        pool_k<<<(Bc * 17 * 17 * 16 + 255) / 256, 256, 0, stream>>>(
            bufA, bufC + 87616, 16, 128, 35, (int)A_FL,
            17, 17, 19, (int)C_FL, Bc * 17 * 17 * 16);

        // conv2: C+87616 -> B  (M=289, Mblk=128 -> 3 mblocks, 2 oc-blocks)
        conv_mfma_k<2, 8, 3, 16, 136, 28424, 36><<<dim3(3, 2, Bc), 256, 0, stream>>>(
            bufC + 87616, WP2, KT2, cb2, bufB, 17, 19,
            289, (int)C_FL, (int)B_FL, 256);

        // fused pool2 + GAP: B [17][17][256] -> GAPB fp32
        pool2gap_k<<<Bc, 512, 0, stream>>>(bufB, GAPB, (int)B_FL, n0);
    }

    // fused FC head
    fc_fused_k<<<NB, 256, 0, stream>>>(GAPB, W0T, fb0, W1T, fb1, W2T, fb2, out);
}

// Round 9
// 600.505 us; speedup vs baseline: 1.6553x; 1.0794x over previous
//
#include <hip/hip_runtime.h>
#include <hip/hip_bf16.h>
#include <cstdint>
#include <cstddef>

#define NB      128
#define RR      300
#define EMB     32

typedef __bf16 bf16x8 __attribute__((ext_vector_type(8)));
typedef float  f32x4  __attribute__((ext_vector_type(4)));
typedef unsigned short ushort8 __attribute__((ext_vector_type(8)));

__device__ __forceinline__ unsigned short f2bf(float f) {
    union { __hip_bfloat16 h; unsigned short u; } c;
    c.h = __float2bfloat16(f);
    return c.u;
}
__device__ __forceinline__ float bf2f(unsigned short u) {
    union { __hip_bfloat16 h; unsigned short u; } c;
    c.u = u;
    return __bfloat162float(c.h);
}

// ---------------------------------------------------------------------------
// 1) Room occupancy -> uint64 bitmask (bit b = dx*8+dy)
// ---------------------------------------------------------------------------
__global__ __launch_bounds__(256) void build_masks_k(
    const int* __restrict__ rm, unsigned long long* __restrict__ masks)
{
    int r = blockIdx.x * 256 + threadIdx.x;
    if (r >= RR) return;
    unsigned long long m = 0ull;
    #pragma unroll
    for (int b = 0; b < 64; ++b)
        if (rm[r * 64 + b]) m |= (1ull << b);
    masks[r] = m;
}

// ---------------------------------------------------------------------------
// 2) Border zero: zeroes only the halo pixels of a padded HWC buffer.
//    Interior is fully overwritten by encode/pool each call.
// ---------------------------------------------------------------------------
__global__ __launch_bounds__(256) void border_k(
    unsigned short* __restrict__ base, int Hp, int Wp, int CPG, int pad,
    int sampleStride, int nborder, int total)
{
    int idx = blockIdx.x * 256 + threadIdx.x;
    if (idx >= total) return;
    int c8 = idx % CPG;
    int t  = idx / CPG;
    int bi = t % nborder;
    int nl = t / nborder;

    int topN = pad * Wp;
    int y, x;
    if (bi < topN) {                       // top rows
        y = bi / Wp; x = bi - y * Wp;
    } else if (bi < 2 * topN) {            // bottom rows
        int b2 = bi - topN;
        y = Hp - pad + b2 / Wp; x = b2 % Wp;
    } else {                               // left/right strips
        int mid = bi - 2 * topN;
        int rowlen = 2 * pad;
        y = pad + mid / rowlen;
        int r = mid % rowlen;
        x = r < pad ? r : Wp - pad + (r - pad);
    }
    uint4 z = make_uint4(0, 0, 0, 0);
    *reinterpret_cast<uint4*>(
        &base[((size_t)nl * sampleStride) +
              ((size_t)y * Wp + x) * (CPG * 8) + c8 * 8]) = z;
}

// ---------------------------------------------------------------------------
// 3) Encode, banded HWC with LDS room cache + hot bitmap.
// ---------------------------------------------------------------------------
__global__ __launch_bounds__(320) void encode_k(
    const int* __restrict__ X, const unsigned long long* __restrict__ masks,
    const float* __restrict__ emb, unsigned short* __restrict__ G,
    int n0, int sampleStride)
{
    __shared__ float tile[4][72][33];
    __shared__ unsigned s_pos[RR];
    __shared__ unsigned long long s_mask[RR];
    __shared__ unsigned long long s_hot[5];

    const int nl = blockIdx.x, band = blockIdx.y;
    const int by = band * 4;
    const int n  = n0 + nl;
    const int tid = threadIdx.x;

    float* tf = &tile[0][0][0];
    for (int i = tid; i < 4 * 72 * 33; i += 320) tf[i] = 0.0f;

    const int2* Xp = reinterpret_cast<const int2*>(X);
    bool hot = false;
    if (tid < RR) {
        int2 pos = Xp[n * RR + tid];
        s_pos[tid]  = (unsigned)pos.x | ((unsigned)pos.y << 16);
        s_mask[tid] = masks[tid];
        hot = (pos.y <= by + 3) && (pos.y + 7 >= by);
    }
    unsigned long long bal = __ballot(hot);
    if ((tid & 63) == 0) s_hot[tid >> 6] = bal;
    __syncthreads();

    const int dx = tid / 33;
    const int c  = tid - dx * 33;
    for (int w = 0; w < 5; ++w) {
        unsigned long long hm = s_hot[w];
        while (hm) {
            int b = __builtin_ctzll(hm);
            hm &= (hm - 1);
            int r = w * 64 + b;
            unsigned pxy = s_pos[r];
            int px = pxy & 0xffff, py = pxy >> 16;
            if (tid < 264) {
                float s = (c == 0) ? 1.0f : emb[r * EMB + (c - 1)];
                unsigned long long mm = s_mask[r] >> (dx * 8);
                int x = px + dx;
                #pragma unroll
                for (int dyb = 0; dyb < 4; ++dyb) {
                    int dyr = by + dyb - py;
                    if ((unsigned)dyr < 8u && ((mm >> dyr) & 1ull))
                        atomicAdd(&tile[dyb][x][c], s);
                }
            }
        }
    }
    __syncthreads();

    unsigned short* Gn = G + (size_t)nl * sampleStride;
    for (int i = tid; i < 4 * 72 * 10; i += 320) {
        int cc = i % 10;
        int t  = i / 10;
        int x  = t % 72;
        int dyb = t / 10 / 72;
        dyb = t / 72;
        int c0 = cc * 4;
        unsigned short r[4];
        #pragma unroll
        for (int j = 0; j < 4; ++j)
            r[j] = (c0 + j < 33) ? f2bf(tile[dyb][x][c0 + j]) : 0;
        uint2 pk;
        pk.x = (unsigned)r[0] | ((unsigned)r[1] << 16);
        pk.y = (unsigned)r[2] | ((unsigned)r[3] << 16);
        *reinterpret_cast<uint2*>(
            &Gn[((size_t)(by + dyb + 2) * 76 + (x + 2)) * 40 + c0]) = pk;
    }
}

// ---------------------------------------------------------------------------
// 4) Weight pack: w[oc][ci][K][K] fp32 -> bf16 wPT[kb][oc][32]
// ---------------------------------------------------------------------------
__global__ __launch_bounds__(256) void wpack_k(
    const float* __restrict__ w, unsigned short* __restrict__ wPT,
    int COUT, int CIN, int KK, int gpc, int total)
{
    int idx = blockIdx.x * 256 + threadIdx.x;
    if (idx >= total) return;
    int kk = idx & 31;
    int t  = idx >> 5;
    int oc = t % COUT;
    int kb = t / COUT;
    int g  = kb * 4 + (kk >> 3);
    int j  = kk & 7;
    int shift = g / gpc;
    int ci    = (g % gpc) * 8 + j;
    float v = (shift < KK && ci < CIN)
        ? w[(size_t)oc * CIN * KK + (size_t)ci * KK + shift] : 0.0f;
    wPT[idx] = f2bf(v);
}

// ---------------------------------------------------------------------------
// 5) ktab: LDS-space group offsets (elem units)
// ---------------------------------------------------------------------------
__global__ __launch_bounds__(256) void ktab_all_k(
    int* __restrict__ kt0, int* __restrict__ kt1, int* __restrict__ kt2)
{
    int t = threadIdx.x;
    int which = blockIdx.y;
    int ngr, gpc, K, Wp, CL;
    int* dst;
    if (which == 0)      { ngr = 128; gpc = 5;  K = 5; Wp = 20; CL = 40;  dst = kt0; }
    else if (which == 1) { ngr = 72;  gpc = 8;  K = 3; Wp = 37; CL = 72;  dst = kt1; }
    else                 { ngr = 144; gpc = 16; K = 3; Wp = 19; CL = 136; dst = kt2; }
    if (t >= ngr) return;
    int shift = t / gpc;
    int off = 0;
    if (shift < K * K) {
        int ky = shift / K, kx = shift % K;
        off = (ky * Wp + kx) * CL + (t % gpc) * 8;
    }
    dst[t] = off;
}

// ---------------------------------------------------------------------------
// 6a) conv0: 24x16-spatial-tile implicit-GEMM, bf16 MFMA 16x16x32.
//     M=384 (MFRAG=6), NOC=64, slab 28x20x40 = 44.8KB staged once.
//     Per k-step: 6 A ds_reads + 4 B loads + 24 MFMA. No K-loop barriers.
// ---------------------------------------------------------------------------
template<int KSTEPS>
__global__ __launch_bounds__(256) void conv0_tile_k(
    const unsigned short* __restrict__ inP,   // [B][76][76][40] bf16
    const unsigned short* __restrict__ wPT,   // [KSTEPS][64][32] bf16
    const int* __restrict__ ktab,             // [KSTEPS*4] LDS offsets
    const float* __restrict__ bias,
    unsigned short* __restrict__ out,         // [B][5184][64] bf16
    int inSS, int outSS)
{
    constexpr int CL = 40;
    constexpr int LP = 72;
    __shared__ __align__(16) unsigned short slab[28 * 20 * CL];  // 44800 B
    unsigned short* s_c = slab;

    const int tid = threadIdx.x;
    const int tl  = blockIdx.x;           // 0..14
    const int nl  = blockIdx.y;
    const int tyi = tl / 5, txi = tl % 5;
    const int y0 = tyi * 24;
    const int x0 = txi < 4 ? txi * 16 : 56;

    const int lane = tid & 63, wv = tid >> 6, frow = lane & 15, fq = lane >> 4;

    const unsigned short* in_n = inP + (size_t)nl * inSS;
    {
        const uint4* src = reinterpret_cast<const uint4*>(in_n);
        uint4* dst = reinterpret_cast<uint4*>(slab);
        #pragma unroll
        for (int it = 0; it < 11; ++it) {
            int q = tid + it * 256;
            if (q < 2800) {
                int r = q / 100, c = q - r * 100;   // slab row, 16B chunk
                dst[q] = src[((y0 + r) * 76 + x0) * 5 + c];
            }
        }
    }

    int ldsb[6];
    #pragma unroll
    for (int mf = 0; mf < 6; ++mf)
        ldsb[mf] = ((mf * 4 + wv) * 20 + frow) * CL;   // pixel (ty, tx=frow)

    const unsigned short* wbase = wPT + (size_t)frow * 32 + fq * 8;

    f32x4 acc[6][4];
    #pragma unroll
    for (int a = 0; a < 6; ++a)
        #pragma unroll
        for (int b = 0; b < 4; ++b) acc[a][b] = (f32x4){0.f, 0.f, 0.f, 0.f};

    __syncthreads();

    #pragma unroll 2
    for (int kb = 0; kb < KSTEPS; ++kb) {
        int go = ktab[kb * 4 + fq];
        bf16x8 af[6];
        #pragma unroll
        for (int mf = 0; mf < 6; ++mf)
            af[mf] = *reinterpret_cast<const bf16x8*>(&slab[ldsb[mf] + go]);
        const unsigned short* wk = wbase + (size_t)kb * 64 * 32;
        #pragma unroll
        for (int ng = 0; ng < 4; ++ng) {
            bf16x8 bf = *reinterpret_cast<const bf16x8*>(wk + ng * 16 * 32);
            #pragma unroll
            for (int mf = 0; mf < 6; ++mf)
                acc[mf][ng] = __builtin_amdgcn_mfma_f32_16x16x32_bf16(
                    af[mf], bf, acc[mf][ng], 0, 0, 0);
        }
    }

    unsigned short* out_n = out + (size_t)nl * outSS;
    const int erow = tid >> 2, eseg = tid & 3;        // 64 rows x 4 segs
    #pragma unroll
    for (int mf = 0; mf < 6; ++mf) {
        __syncthreads();
        #pragma unroll
        for (int ng = 0; ng < 4; ++ng) {
            float bv = bias[ng * 16 + frow];
            #pragma unroll
            for (int j = 0; j < 4; ++j)
                s_c[(wv * 16 + fq * 4 + j) * LP + ng * 16 + frow] =
                    f2bf(fmaxf(acc[mf][ng][j] + bv, 0.0f));
        }
        __syncthreads();
        {
            int ty = mf * 4 + (erow >> 4);
            int tx = erow & 15;
            int pos = (y0 + ty) * 72 + (x0 + tx);
            ushort8 v0 = *reinterpret_cast<const ushort8*>(
                &s_c[erow * LP + eseg * 16]);
            ushort8 v1 = *reinterpret_cast<const ushort8*>(
                &s_c[erow * LP + eseg * 16 + 8]);
            unsigned short* op = out_n + (size_t)pos * 64 + eseg * 16;
            *reinterpret_cast<ushort8*>(op) = v0;
            *reinterpret_cast<ushort8*>(op + 8) = v1;
        }
    }
}

// ---------------------------------------------------------------------------
// 6b) Generic row-slab implicit-GEMM conv (conv1/conv2), bf16 MFMA 16x16x32.
// ---------------------------------------------------------------------------
template<int MFRAG, int NG, int KH, int CPG, int CL, int SLAB, int KSTEPS>
__global__ __launch_bounds__(256) void conv_mfma_k(
    const unsigned short* __restrict__ inP,   // [B][Hp][Wp][Cp] bf16
    const unsigned short* __restrict__ wPT,   // [KSTEPS][COUT][32] bf16
    const int* __restrict__ ktab,             // [KSTEPS*4] LDS group offsets
    const float* __restrict__ bias,
    unsigned short* __restrict__ out,         // [B][Mtot][COUT] bf16
    int W, int Wp, int Mtot, int inSS, int outSS, int COUT)
{
    constexpr int Mblk = MFRAG * 64;
    constexpr int NOC  = NG * 16;
    constexpr int SEGS = NOC / 16;
    constexpr int LP   = NOC + 8;
    constexpr int CP   = CPG * 8;
    constexpr int SMEM = (SLAB * 2 > 64 * LP * 2) ? SLAB * 2 : 64 * LP * 2;
    __shared__ __align__(16) char smem[SMEM];
    unsigned short* slab = reinterpret_cast<unsigned short*>(smem);
    unsigned short* s_c  = reinterpret_cast<unsigned short*>(smem);

    const int tid  = threadIdx.x;
    const int mb   = blockIdx.x;
    const int ocb  = blockIdx.y;
    const int nl   = blockIdx.z;
    const int lane = tid & 63;
    const int wv   = tid >> 6;
    const int frow = lane & 15;
    const int fq   = lane >> 4;

    const int p0    = mb * Mblk;
    const int y0    = p0 / W;
    const int plast = (p0 + Mblk < Mtot ? p0 + Mblk : Mtot) - 1;
    const int rows  = plast / W - y0 + KH;

    const unsigned short* in_n =
        inP + (size_t)nl * inSS + (size_t)y0 * Wp * CP;
    const int nchunks = rows * Wp * CPG;
    for (int q = tid; q < nchunks; q += 256) {
        int pix = q / CPG, c8 = q - pix * CPG;
        uint4 v = reinterpret_cast<const uint4*>(in_n)[q];
        *reinterpret_cast<uint4*>(&slab[pix * CL + c8 * 8]) = v;
    }

    int ldsb[MFRAG];
    #pragma unroll
    for (int mf = 0; mf < MFRAG; ++mf) {
        int p  = p0 + mf * 64 + wv * 16 + frow;
        int pc = p < Mtot ? p : (Mtot - 1);
        int y  = pc / W;
        int x  = pc - y * W;
        ldsb[mf] = ((y - y0) * Wp + x) * CL;
    }
    const unsigned short* wbase =
        wPT + ((size_t)(ocb * NOC + frow)) * 32 + fq * 8;

    f32x4 acc[MFRAG][NG];
    #pragma unroll
    for (int mf = 0; mf < MFRAG; ++mf)
        #pragma unroll
        for (int ng = 0; ng < NG; ++ng)
            acc[mf][ng] = (f32x4){0.f, 0.f, 0.f, 0.f};

    __syncthreads();

    for (int kb = 0; kb < KSTEPS; ++kb) {
        int go = ktab[kb * 4 + fq];
        bf16x8 af[MFRAG];
        #pragma unroll
        for (int mf = 0; mf < MFRAG; ++mf)
            af[mf] = *reinterpret_cast<const bf16x8*>(&slab[ldsb[mf] + go]);
        const unsigned short* wk = wbase + (size_t)kb * COUT * 32;
        #pragma unroll
        for (int ng = 0; ng < NG; ++ng) {
            bf16x8 bf = *reinterpret_cast<const bf16x8*>(wk + ng * 16 * 32);
            #pragma unroll
            for (int mf = 0; mf < MFRAG; ++mf)
                acc[mf][ng] = __builtin_amdgcn_mfma_f32_16x16x32_bf16(
                    af[mf], bf, acc[mf][ng], 0, 0, 0);
        }
    }

    unsigned short* out_n = out + (size_t)nl * outSS;
    #pragma unroll
    for (int mf = 0; mf < MFRAG; ++mf) {
        __syncthreads();
        #pragma unroll
        for (int ng = 0; ng < NG; ++ng) {
            float bv = bias[ocb * NOC + ng * 16 + frow];
            #pragma unroll
            for (int j = 0; j < 4; ++j)
                s_c[(wv * 16 + fq * 4 + j) * LP + ng * 16 + frow] =
                    f2bf(fmaxf(acc[mf][ng][j] + bv, 0.0f));
        }
        __syncthreads();
        for (int t = tid; t < 64 * SEGS; t += 256) {
            int row = t / SEGS, seg = t % SEGS;
            int p = p0 + mf * 64 + row;
            if (p < Mtot) {
                ushort8 v0 = *reinterpret_cast<const ushort8*>(
                    &s_c[row * LP + seg * 16]);
                ushort8 v1 = *reinterpret_cast<const ushort8*>(
                    &s_c[row * LP + seg * 16 + 8]);
                unsigned short* op =
                    out_n + (size_t)p * COUT + ocb * NOC + seg * 16;
                *reinterpret_cast<ushort8*>(op) = v0;
                *reinterpret_cast<ushort8*>(op + 8) = v1;
            }
        }
    }
}

// ---------------------------------------------------------------------------
// 7) MaxPool 3x3 s2 VALID, HWC, ushort8 (post-ReLU: u16 max).
// ---------------------------------------------------------------------------
__global__ __launch_bounds__(256) void pool_k(
    const unsigned short* __restrict__ in, unsigned short* __restrict__ out,
    int CG, int C, int W, int inSS,
    int HO, int WO, int Wpo, int outSS, int total)
{
    int idx = blockIdx.x * 256 + threadIdx.x;
    if (idx >= total) return;
    int cg = idx % CG;
    int t  = idx / CG;
    int x  = t % WO;
    t /= WO;
    int y  = t % HO;
    int nl = t / HO;

    const unsigned short* pin = in + (size_t)nl * inSS + cg * 8;
    ushort8 mx = {0,0,0,0,0,0,0,0};
    #pragma unroll
    for (int dy = 0; dy < 3; ++dy)
        #pragma unroll
        for (int dx = 0; dx < 3; ++dx) {
            ushort8 v = *reinterpret_cast<const ushort8*>(
                pin + ((size_t)(2 * y + dy) * W + (2 * x + dx)) * C);
            #pragma unroll
            for (int j = 0; j < 8; ++j) mx[j] = v[j] > mx[j] ? v[j] : mx[j];
        }
    *reinterpret_cast<ushort8*>(
        out + (size_t)nl * outSS +
        ((size_t)(y + 1) * Wpo + (x + 1)) * C + cg * 8) = mx;
}

// ---------------------------------------------------------------------------
// 8) Fused pool2 (3x3 s2 on [17][17][256]) + global average pool -> fp32
// ---------------------------------------------------------------------------
__global__ __launch_bounds__(512) void pool2gap_k(
    const unsigned short* __restrict__ in, float* __restrict__ out,
    int inSS, int n0)
{
    __shared__ float part[256];
    const int nl = blockIdx.x;
    const int c    = threadIdx.x & 255;
    const int half = threadIdx.x >> 8;
    const unsigned short* p = in + (size_t)nl * inSS + c;
    float s = 0.0f;
    for (int w = half * 32; w < half * 32 + 32; ++w) {
        int y = w >> 3, x = w & 7;
        unsigned short mx = 0;
        #pragma unroll
        for (int dy = 0; dy < 3; ++dy)
            #pragma unroll
            for (int dx = 0; dx < 3; ++dx) {
                unsigned short v = p[((size_t)(2*y+dy) * 17 + (2*x+dx)) * 256];
                mx = v > mx ? v : mx;
            }
        s += bf2f(mx);
    }
    if (half) part[c] = s;
    __syncthreads();
    if (!half) out[(size_t)(n0 + nl) * 256 + c] = (s + part[c]) * (1.0f / 64.0f);
}

// ---------------------------------------------------------------------------
// 9) FC weight transpose: w[o][i] -> wT[i][o]
// ---------------------------------------------------------------------------
__global__ __launch_bounds__(256) void fcT_k(
    const float* __restrict__ w, float* __restrict__ wT, int O, int I, int total)
{
    int idx = blockIdx.x * 256 + threadIdx.x;
    if (idx >= total) return;
    int i = idx % I, o = idx / I;
    wT[(size_t)i * O + o] = w[idx];
}

// ---------------------------------------------------------------------------
// 10) Fused 3-layer FC head (256->512->256->512), one block per sample
// ---------------------------------------------------------------------------
__global__ __launch_bounds__(256) void fc_fused_k(
    const float* __restrict__ in,
    const float* __restrict__ w0T, const float* __restrict__ b0,
    const float* __restrict__ w1T, const float* __restrict__ b1,
    const float* __restrict__ w2T, const float* __restrict__ b2,
    float* __restrict__ out)
{
    __shared__ float s_in[256], s_h0[512], s_h1[256];
    const int n = blockIdx.x, t = threadIdx.x;
    s_in[t] = in[(size_t)n * 256 + t];
    __syncthreads();
    float a0 = 0.f, a1 = 0.f;
    for (int i = 0; i < 256; ++i) {
        float v = s_in[i];
        a0 += v * w0T[i * 512 + t];
        a1 += v * w0T[i * 512 + t + 256];
    }
    s_h0[t]       = fmaxf(a0 + b0[t], 0.0f);
    s_h0[t + 256] = fmaxf(a1 + b0[t + 256], 0.0f);
    __syncthreads();
    float h = 0.f;
    for (int i = 0; i < 512; ++i) h += s_h0[i] * w1T[i * 256 + t];
    s_h1[t] = fmaxf(h + b1[t], 0.0f);
    __syncthreads();
    a0 = 0.f; a1 = 0.f;
    for (int i = 0; i < 256; ++i) {
        float v = s_h1[i];
        a0 += v * w2T[i * 512 + t];
        a1 += v * w2T[i * 512 + t + 256];
    }
    out[(size_t)n * 512 + t]       = a0 + b2[t];
    out[(size_t)n * 512 + t + 256] = a1 + b2[t + 256];
}

// ---------------------------------------------------------------------------
// Launch. Per-sample u16 sizes (HWC):
//   A: G [76][76][40] = 231,040   (overlay: C1 [1225][128]=156,800)
//   B: C0 [5184][64]  = 331,776   (overlay: C2 [289][256]=73,984)
//   C: P0p [37][37][64]=87,616 + P1p [19][19][128]=46,208 = 133,824
// ---------------------------------------------------------------------------
extern "C" void kernel_launch(void* const* d_in, const int* in_sizes, int n_in,
                              void* d_out, int out_size, void* d_ws, size_t ws_size,
                              hipStream_t stream)
{
    const int*   X   = (const int*)d_in[0];
    const int*   rm  = (const int*)d_in[1];
    const float* emb = (const float*)d_in[2];
    const float* cw0 = (const float*)d_in[3];
    const float* cb0 = (const float*)d_in[4];
    const float* cw1 = (const float*)d_in[5];
    const float* cb1 = (const float*)d_in[6];
    const float* cw2 = (const float*)d_in[7];
    const float* cb2 = (const float*)d_in[8];
    const float* fw0 = (const float*)d_in[9];
    const float* fb0 = (const float*)d_in[10];
    const float* fw1 = (const float*)d_in[11];
    const float* fb1 = (const float*)d_in[12];
    const float* fw2 = (const float*)d_in[13];
    const float* fb2 = (const float*)d_in[14];
    float* out = (float*)d_out;

    char* p = (char*)d_ws;
    auto alloc = [&](size_t bytes) -> char* {
        char* r = p; p += (bytes + 255) & ~(size_t)255; return r;
    };
    unsigned short* WP0 = (unsigned short*)alloc((size_t)32 * 64 * 32 * 2);
    unsigned short* WP1 = (unsigned short*)alloc((size_t)18 * 128 * 32 * 2);
    unsigned short* WP2 = (unsigned short*)alloc((size_t)36 * 256 * 32 * 2);
    int* KT0 = (int*)alloc(128 * 4);
    int* KT1 = (int*)alloc(72 * 4);
    int* KT2 = (int*)alloc(144 * 4);
    unsigned long long* MASKS = (unsigned long long*)alloc(RR * 8);
    float* W0T  = (float*)alloc((size_t)256 * 512 * 4);
    float* W1T  = (float*)alloc((size_t)512 * 256 * 4);
    float* W2T  = (float*)alloc((size_t)256 * 512 * 4);
    float* GAPB = (float*)alloc((size_t)NB * 256 * 4);
    size_t fixed_bytes = (size_t)(p - (char*)d_ws);

    const size_t A_FL = 231040, B_FL = 331776, C_FL = 133824;   // u16
    const size_t per_sample = (A_FL + B_FL + C_FL) * 2 + 768;
    int Bc = 128;
    while (Bc > 1 && fixed_bytes + (size_t)Bc * per_sample > ws_size) Bc >>= 1;

    unsigned short* bufA = (unsigned short*)alloc((size_t)Bc * A_FL * 2);
    unsigned short* bufC = (unsigned short*)alloc((size_t)Bc * C_FL * 2);
    unsigned short* bufB = (unsigned short*)alloc((size_t)Bc * B_FL * 2);

    // ---- one-time prep (runs every call; graph-safe) ----
    build_masks_k<<<2, 256, 0, stream>>>(rm, MASKS);
    wpack_k<<<(32 * 64 * 32 + 255) / 256, 256, 0, stream>>>(
        cw0, WP0, 64, 33, 25, 5, 32 * 64 * 32);
    wpack_k<<<(18 * 128 * 32 + 255) / 256, 256, 0, stream>>>(
        cw1, WP1, 128, 64, 9, 8, 18 * 128 * 32);
    wpack_k<<<(36 * 256 * 32 + 255) / 256, 256, 0, stream>>>(
        cw2, WP2, 256, 128, 9, 16, 36 * 256 * 32);
    ktab_all_k<<<dim3(1, 3), 256, 0, stream>>>(KT0, KT1, KT2);
    fcT_k<<<(512 * 256 + 255) / 256, 256, 0, stream>>>(fw0, W0T, 512, 256, 512 * 256);
    fcT_k<<<(256 * 512 + 255) / 256, 256, 0, stream>>>(fw1, W1T, 256, 512, 256 * 512);
    fcT_k<<<(512 * 256 + 255) / 256, 256, 0, stream>>>(fw2, W2T, 512, 256, 512 * 256);

    // ---- chunked pipeline ----
    for (int n0 = 0; n0 < NB; n0 += Bc) {
        // zero only the halo borders (interiors fully overwritten each call)
        border_k<<<(Bc * 592 * 5 + 255) / 256, 256, 0, stream>>>(
            bufA, 76, 76, 5, 2, (int)A_FL, 592, Bc * 592 * 5);
        border_k<<<(Bc * 144 * 8 + 255) / 256, 256, 0, stream>>>(
            bufC, 37, 37, 8, 1, (int)C_FL, 144, Bc * 144 * 8);
        border_k<<<(Bc * 72 * 16 + 255) / 256, 256, 0, stream>>>(
            bufC + 87616, 19, 19, 16, 1, (int)C_FL, 72, Bc * 72 * 16);

        // encode -> A (HWC G [76][76][40], interior +2)
        encode_k<<<dim3(Bc, 18), 320, 0, stream>>>(X, MASKS, emb, bufA, n0, (int)A_FL);

        // conv0: A -> B  (15 24x16 tiles/sample, COUT=64, 32 ksteps)
        conv0_tile_k<32><<<dim3(15, Bc), 256, 0, stream>>>(
            bufA, WP0, KT0, cb0, bufB, (int)A_FL, (int)B_FL);
        // pool0: B [72][72][64] -> C P0p [37][37][64] interior +1
        pool_k<<<(Bc * 35 * 35 * 8 + 255) / 256, 256, 0, stream>>>(
            bufB, bufC, 8, 64, 72, (int)B_FL,
            35, 35, 37, (int)C_FL, Bc * 35 * 35 * 8);

        // conv1: C -> A  (M=1225, Mblk=256 -> 5 mblocks, COUT=128)
        conv_mfma_k<4, 8, 3, 8, 72, 29304, 18><<<dim3(5, 1, Bc), 256, 0, stream>>>(
            bufC, WP1, KT1, cb1, bufA, 35, 37,
            1225, (int)C_FL, (int)A_FL, 128);
        // pool1: A [35][35][128] -> C+87616 P1p [19][19][128] interior +1
        pool_k<<<(Bc * 17 * 17 * 16 + 255) / 256, 256, 0, stream>>>(
            bufA, bufC + 87616, 16, 128, 35, (int)A_FL,
            17, 17, 19, (int)C_FL, Bc * 17 * 17 * 16);

        // conv2: C+87616 -> B  (M=289, Mblk=128 -> 3 mblocks, 2 oc-blocks)
        conv_mfma_k<2, 8, 3, 16, 136, 28424, 36><<<dim3(3, 2, Bc), 256, 0, stream>>>(
            bufC + 87616, WP2, KT2, cb2, bufB, 17, 19,
            289, (int)C_FL, (int)B_FL, 256);

        // fused pool2 + GAP: B [17][17][256] -> GAPB fp32
        pool2gap_k<<<Bc, 512, 0, stream>>>(bufB, GAPB, (int)B_FL, n0);
    }

    // fused FC head
    fc_fused_k<<<NB, 256, 0, stream>>>(GAPB, W0T, fb0, W1T, fb1, W2T, fb2, out);
}

// Round 10
// 596.801 us; speedup vs baseline: 1.6656x; 1.0062x over previous
//
#include <hip/hip_runtime.h>
#include <hip/hip_bf16.h>
#include <cstdint>
#include <cstddef>

#define NB      128
#define RR      300
#define EMB     32

typedef __bf16 bf16x8 __attribute__((ext_vector_type(8)));
typedef float  f32x4  __attribute__((ext_vector_type(4)));
typedef unsigned short ushort8 __attribute__((ext_vector_type(8)));

__device__ __forceinline__ unsigned short f2bf(float f) {
    union { __hip_bfloat16 h; unsigned short u; } c;
    c.h = __float2bfloat16(f);
    return c.u;
}
__device__ __forceinline__ float bf2f(unsigned short u) {
    union { __hip_bfloat16 h; unsigned short u; } c;
    c.u = u;
    return __bfloat162float(c.h);
}

// ---------------------------------------------------------------------------
// 1) Room occupancy -> uint64 bitmask (bit b = dx*8+dy)
// ---------------------------------------------------------------------------
__global__ __launch_bounds__(256) void build_masks_k(
    const int* __restrict__ rm, unsigned long long* __restrict__ masks)
{
    int r = blockIdx.x * 256 + threadIdx.x;
    if (r >= RR) return;
    unsigned long long m = 0ull;
    #pragma unroll
    for (int b = 0; b < 64; ++b)
        if (rm[r * 64 + b]) m |= (1ull << b);
    masks[r] = m;
}

// ---------------------------------------------------------------------------
// 2) Border zero: zeroes only the halo pixels of a padded HWC buffer.
// ---------------------------------------------------------------------------
__global__ __launch_bounds__(256) void border_k(
    unsigned short* __restrict__ base, int Hp, int Wp, int CPG, int pad,
    int sampleStride, int nborder, int total)
{
    int idx = blockIdx.x * 256 + threadIdx.x;
    if (idx >= total) return;
    int c8 = idx % CPG;
    int t  = idx / CPG;
    int bi = t % nborder;
    int nl = t / nborder;

    int topN = pad * Wp;
    int y, x;
    if (bi < topN) {
        y = bi / Wp; x = bi - y * Wp;
    } else if (bi < 2 * topN) {
        int b2 = bi - topN;
        y = Hp - pad + b2 / Wp; x = b2 % Wp;
    } else {
        int mid = bi - 2 * topN;
        int rowlen = 2 * pad;
        y = pad + mid / rowlen;
        int r = mid % rowlen;
        x = r < pad ? r : Wp - pad + (r - pad);
    }
    uint4 z = make_uint4(0, 0, 0, 0);
    *reinterpret_cast<uint4*>(
        &base[((size_t)nl * sampleStride) +
              ((size_t)y * Wp + x) * (CPG * 8) + c8 * 8]) = z;
}

// ---------------------------------------------------------------------------
// 3) Encode, banded HWC. v3: hot-room COMPACTION + LDS emb cache so the
//    serial walk loop touches LDS only (no global loads on the chain).
// ---------------------------------------------------------------------------
__global__ __launch_bounds__(320) void encode_k(
    const int* __restrict__ X, const unsigned long long* __restrict__ masks,
    const float* __restrict__ emb, unsigned short* __restrict__ G,
    int n0, int sampleStride)
{
    __shared__ float tile[4][72][33];                  // 38016 B
    __shared__ unsigned s_pos[RR];                     // 1200 B
    __shared__ unsigned long long s_mask[RR];          // 2400 B
    __shared__ unsigned short s_list[320];             // 640 B
    __shared__ float s_emb[64 * 33];                   // 8448 B
    __shared__ int s_woff[8];
    __shared__ int s_cnt;

    const int nl = blockIdx.x, band = blockIdx.y;
    const int by = band * 4;
    const int n  = n0 + nl;
    const int tid = threadIdx.x;

    float* tf = &tile[0][0][0];
    for (int i = tid; i < 4 * 72 * 33; i += 320) tf[i] = 0.0f;

    // phase 1: preload rooms, ballot hot predicate, per-word counts
    const int2* Xp = reinterpret_cast<const int2*>(X);
    bool hot = false;
    if (tid < RR) {
        int2 pos = Xp[n * RR + tid];
        s_pos[tid]  = (unsigned)pos.x | ((unsigned)pos.y << 16);
        s_mask[tid] = masks[tid];
        hot = (pos.y <= by + 3) && (pos.y + 7 >= by);
    }
    unsigned long long bal = __ballot(hot);
    if ((tid & 63) == 0) s_woff[tid >> 6] = (int)__popcll(bal);
    __syncthreads();
    if (tid == 0) {
        int acc = 0;
        #pragma unroll
        for (int w = 0; w < 5; ++w) { int c = s_woff[w]; s_woff[w] = acc; acc += c; }
        s_cnt = acc;
    }
    __syncthreads();
    if (hot) {
        int w = tid >> 6, b = tid & 63;
        unsigned long long before = (b == 0) ? 0ull : (bal & ((1ull << b) - 1ull));
        s_list[s_woff[w] + (int)__popcll(before)] = (unsigned short)tid;
    }
    __syncthreads();

    // phase 2: chunked walk — emb rows staged to LDS first, then LDS-only loop
    const int dx = tid / 33;
    const int c  = tid - dx * 33;
    const int cnt = s_cnt;
    for (int base = 0; base < cnt; base += 64) {
        int cn = cnt - base; if (cn > 64) cn = 64;
        for (int i = tid; i < cn * 33; i += 320) {
            int hi = i / 33, cc = i - hi * 33;
            int r = s_list[base + hi];
            s_emb[i] = (cc == 0) ? 1.0f : emb[r * EMB + cc - 1];
        }
        __syncthreads();
        if (tid < 264) {
            for (int j = 0; j < cn; ++j) {
                int r = s_list[base + j];
                unsigned pxy = s_pos[r];
                int px = pxy & 0xffff, py = pxy >> 16;
                float s = s_emb[j * 33 + c];
                unsigned long long mm = s_mask[r] >> (dx * 8);
                int x = px + dx;
                #pragma unroll
                for (int dyb = 0; dyb < 4; ++dyb) {
                    int dyr = by + dyb - py;
                    if ((unsigned)dyr < 8u && ((mm >> dyr) & 1ull))
                        atomicAdd(&tile[dyb][x][c], s);
                }
            }
        }
        __syncthreads();
    }
    __syncthreads();

    // write-out: 4 rows x 72 px x 40ch as uint2 (4ch) chunks
    unsigned short* Gn = G + (size_t)nl * sampleStride;
    for (int i = tid; i < 4 * 72 * 10; i += 320) {
        int cc = i % 10;
        int t  = i / 10;
        int x  = t % 72;
        int dyb = t / 72;
        int c0 = cc * 4;
        unsigned short r[4];
        #pragma unroll
        for (int j = 0; j < 4; ++j)
            r[j] = (c0 + j < 33) ? f2bf(tile[dyb][x][c0 + j]) : 0;
        uint2 pk;
        pk.x = (unsigned)r[0] | ((unsigned)r[1] << 16);
        pk.y = (unsigned)r[2] | ((unsigned)r[3] << 16);
        *reinterpret_cast<uint2*>(
            &Gn[((size_t)(by + dyb + 2) * 76 + (x + 2)) * 40 + c0]) = pk;
    }
}

// ---------------------------------------------------------------------------
// 4) Weight pack: w[oc][ci][K][K] fp32 -> bf16 wPT[kb][oc][32]
// ---------------------------------------------------------------------------
__global__ __launch_bounds__(256) void wpack_k(
    const float* __restrict__ w, unsigned short* __restrict__ wPT,
    int COUT, int CIN, int KK, int gpc, int total)
{
    int idx = blockIdx.x * 256 + threadIdx.x;
    if (idx >= total) return;
    int kk = idx & 31;
    int t  = idx >> 5;
    int oc = t % COUT;
    int kb = t / COUT;
    int g  = kb * 4 + (kk >> 3);
    int j  = kk & 7;
    int shift = g / gpc;
    int ci    = (g % gpc) * 8 + j;
    float v = (shift < KK && ci < CIN)
        ? w[(size_t)oc * CIN * KK + (size_t)ci * KK + shift] : 0.0f;
    wPT[idx] = f2bf(v);
}

// ---------------------------------------------------------------------------
// 5) ktab: LDS-space group offsets (elem units)
// ---------------------------------------------------------------------------
__global__ __launch_bounds__(256) void ktab_all_k(
    int* __restrict__ kt0, int* __restrict__ kt1, int* __restrict__ kt2)
{
    int t = threadIdx.x;
    int which = blockIdx.y;
    int ngr, gpc, K, Wp, CL;
    int* dst;
    if (which == 0)      { ngr = 128; gpc = 5;  K = 5; Wp = 20; CL = 40;  dst = kt0; }
    else if (which == 1) { ngr = 72;  gpc = 8;  K = 3; Wp = 37; CL = 72;  dst = kt1; }
    else                 { ngr = 144; gpc = 16; K = 3; Wp = 19; CL = 136; dst = kt2; }
    if (t >= ngr) return;
    int shift = t / gpc;
    int off = 0;
    if (shift < K * K) {
        int ky = shift / K, kx = shift % K;
        off = (ky * Wp + kx) * CL + (t % gpc) * 8;
    }
    dst[t] = off;
}

// ---------------------------------------------------------------------------
// 6a) conv0: 24x16-spatial-tile implicit-GEMM, bf16 MFMA 16x16x32.
//     M=384 (MFRAG=6), NOC=64, slab 28x20x40 = 44.8KB staged once.
// ---------------------------------------------------------------------------
template<int KSTEPS>
__global__ __launch_bounds__(256) void conv0_tile_k(
    const unsigned short* __restrict__ inP,   // [B][76][76][40] bf16
    const unsigned short* __restrict__ wPT,   // [KSTEPS][64][32] bf16
    const int* __restrict__ ktab,             // [KSTEPS*4] LDS offsets
    const float* __restrict__ bias,
    unsigned short* __restrict__ out,         // [B][5184][64] bf16
    int inSS, int outSS)
{
    constexpr int CL = 40;
    constexpr int LP = 72;
    __shared__ __align__(16) unsigned short slab[28 * 20 * CL];  // 44800 B
    unsigned short* s_c = slab;

    const int tid = threadIdx.x;
    const int tl  = blockIdx.x;           // 0..14
    const int nl  = blockIdx.y;
    const int tyi = tl / 5, txi = tl % 5;
    const int y0 = tyi * 24;
    const int x0 = txi < 4 ? txi * 16 : 56;

    const int lane = tid & 63, wv = tid >> 6, frow = lane & 15, fq = lane >> 4;

    const unsigned short* in_n = inP + (size_t)nl * inSS;
    {
        const uint4* src = reinterpret_cast<const uint4*>(in_n);
        uint4* dst = reinterpret_cast<uint4*>(slab);
        #pragma unroll
        for (int it = 0; it < 11; ++it) {
            int q = tid + it * 256;
            if (q < 2800) {
                int r = q / 100, c = q - r * 100;
                dst[q] = src[((y0 + r) * 76 + x0) * 5 + c];
            }
        }
    }

    int ldsb[6];
    #pragma unroll
    for (int mf = 0; mf < 6; ++mf)
        ldsb[mf] = ((mf * 4 + wv) * 20 + frow) * CL;

    const unsigned short* wbase = wPT + (size_t)frow * 32 + fq * 8;

    f32x4 acc[6][4];
    #pragma unroll
    for (int a = 0; a < 6; ++a)
        #pragma unroll
        for (int b = 0; b < 4; ++b) acc[a][b] = (f32x4){0.f, 0.f, 0.f, 0.f};

    __syncthreads();

    #pragma unroll 2
    for (int kb = 0; kb < KSTEPS; ++kb) {
        int go = ktab[kb * 4 + fq];
        bf16x8 af[6];
        #pragma unroll
        for (int mf = 0; mf < 6; ++mf)
            af[mf] = *reinterpret_cast<const bf16x8*>(&slab[ldsb[mf] + go]);
        const unsigned short* wk = wbase + (size_t)kb * 64 * 32;
        #pragma unroll
        for (int ng = 0; ng < 4; ++ng) {
            bf16x8 bf = *reinterpret_cast<const bf16x8*>(wk + ng * 16 * 32);
            #pragma unroll
            for (int mf = 0; mf < 6; ++mf)
                acc[mf][ng] = __builtin_amdgcn_mfma_f32_16x16x32_bf16(
                    af[mf], bf, acc[mf][ng], 0, 0, 0);
        }
    }

    unsigned short* out_n = out + (size_t)nl * outSS;
    const int erow = tid >> 2, eseg = tid & 3;
    #pragma unroll
    for (int mf = 0; mf < 6; ++mf) {
        __syncthreads();
        #pragma unroll
        for (int ng = 0; ng < 4; ++ng) {
            float bv = bias[ng * 16 + frow];
            #pragma unroll
            for (int j = 0; j < 4; ++j)
                s_c[(wv * 16 + fq * 4 + j) * LP + ng * 16 + frow] =
                    f2bf(fmaxf(acc[mf][ng][j] + bv, 0.0f));
        }
        __syncthreads();
        {
            int ty = mf * 4 + (erow >> 4);
            int tx = erow & 15;
            int pos = (y0 + ty) * 72 + (x0 + tx);
            ushort8 v0 = *reinterpret_cast<const ushort8*>(
                &s_c[erow * LP + eseg * 16]);
            ushort8 v1 = *reinterpret_cast<const ushort8*>(
                &s_c[erow * LP + eseg * 16 + 8]);
            unsigned short* op = out_n + (size_t)pos * 64 + eseg * 16;
            *reinterpret_cast<ushort8*>(op) = v0;
            *reinterpret_cast<ushort8*>(op + 8) = v1;
        }
    }
}

// ---------------------------------------------------------------------------
// 6b) Generic row-slab implicit-GEMM conv (conv1/conv2), bf16 MFMA 16x16x32.
// ---------------------------------------------------------------------------
template<int MFRAG, int NG, int KH, int CPG, int CL, int SLAB, int KSTEPS>
__global__ __launch_bounds__(256) void conv_mfma_k(
    const unsigned short* __restrict__ inP,
    const unsigned short* __restrict__ wPT,
    const int* __restrict__ ktab,
    const float* __restrict__ bias,
    unsigned short* __restrict__ out,
    int W, int Wp, int Mtot, int inSS, int outSS, int COUT)
{
    constexpr int Mblk = MFRAG * 64;
    constexpr int NOC  = NG * 16;
    constexpr int SEGS = NOC / 16;
    constexpr int LP   = NOC + 8;
    constexpr int CP   = CPG * 8;
    constexpr int SMEM = (SLAB * 2 > 64 * LP * 2) ? SLAB * 2 : 64 * LP * 2;
    __shared__ __align__(16) char smem[SMEM];
    unsigned short* slab = reinterpret_cast<unsigned short*>(smem);
    unsigned short* s_c  = reinterpret_cast<unsigned short*>(smem);

    const int tid  = threadIdx.x;
    const int mb   = blockIdx.x;
    const int ocb  = blockIdx.y;
    const int nl   = blockIdx.z;
    const int lane = tid & 63;
    const int wv   = tid >> 6;
    const int frow = lane & 15;
    const int fq   = lane >> 4;

    const int p0    = mb * Mblk;
    const int y0    = p0 / W;
    const int plast = (p0 + Mblk < Mtot ? p0 + Mblk : Mtot) - 1;
    const int rows  = plast / W - y0 + KH;

    const unsigned short* in_n =
        inP + (size_t)nl * inSS + (size_t)y0 * Wp * CP;
    const int nchunks = rows * Wp * CPG;
    for (int q = tid; q < nchunks; q += 256) {
        int pix = q / CPG, c8 = q - pix * CPG;
        uint4 v = reinterpret_cast<const uint4*>(in_n)[q];
        *reinterpret_cast<uint4*>(&slab[pix * CL + c8 * 8]) = v;
    }

    int ldsb[MFRAG];
    #pragma unroll
    for (int mf = 0; mf < MFRAG; ++mf) {
        int p  = p0 + mf * 64 + wv * 16 + frow;
        int pc = p < Mtot ? p : (Mtot - 1);
        int y  = pc / W;
        int x  = pc - y * W;
        ldsb[mf] = ((y - y0) * Wp + x) * CL;
    }
    const unsigned short* wbase =
        wPT + ((size_t)(ocb * NOC + frow)) * 32 + fq * 8;

    f32x4 acc[MFRAG][NG];
    #pragma unroll
    for (int mf = 0; mf < MFRAG; ++mf)
        #pragma unroll
        for (int ng = 0; ng < NG; ++ng)
            acc[mf][ng] = (f32x4){0.f, 0.f, 0.f, 0.f};

    __syncthreads();

    for (int kb = 0; kb < KSTEPS; ++kb) {
        int go = ktab[kb * 4 + fq];
        bf16x8 af[MFRAG];
        #pragma unroll
        for (int mf = 0; mf < MFRAG; ++mf)
            af[mf] = *reinterpret_cast<const bf16x8*>(&slab[ldsb[mf] + go]);
        const unsigned short* wk = wbase + (size_t)kb * COUT * 32;
        #pragma unroll
        for (int ng = 0; ng < NG; ++ng) {
            bf16x8 bf = *reinterpret_cast<const bf16x8*>(wk + ng * 16 * 32);
            #pragma unroll
            for (int mf = 0; mf < MFRAG; ++mf)
                acc[mf][ng] = __builtin_amdgcn_mfma_f32_16x16x32_bf16(
                    af[mf], bf, acc[mf][ng], 0, 0, 0);
        }
    }

    unsigned short* out_n = out + (size_t)nl * outSS;
    #pragma unroll
    for (int mf = 0; mf < MFRAG; ++mf) {
        __syncthreads();
        #pragma unroll
        for (int ng = 0; ng < NG; ++ng) {
            float bv = bias[ocb * NOC + ng * 16 + frow];
            #pragma unroll
            for (int j = 0; j < 4; ++j)
                s_c[(wv * 16 + fq * 4 + j) * LP + ng * 16 + frow] =
                    f2bf(fmaxf(acc[mf][ng][j] + bv, 0.0f));
        }
        __syncthreads();
        for (int t = tid; t < 64 * SEGS; t += 256) {
            int row = t / SEGS, seg = t % SEGS;
            int p = p0 + mf * 64 + row;
            if (p < Mtot) {
                ushort8 v0 = *reinterpret_cast<const ushort8*>(
                    &s_c[row * LP + seg * 16]);
                ushort8 v1 = *reinterpret_cast<const ushort8*>(
                    &s_c[row * LP + seg * 16 + 8]);
                unsigned short* op =
                    out_n + (size_t)p * COUT + ocb * NOC + seg * 16;
                *reinterpret_cast<ushort8*>(op) = v0;
                *reinterpret_cast<ushort8*>(op + 8) = v1;
            }
        }
    }
}

// ---------------------------------------------------------------------------
// 7) MaxPool 3x3 s2 VALID, HWC, ushort8 (post-ReLU: u16 max).
// ---------------------------------------------------------------------------
__global__ __launch_bounds__(256) void pool_k(
    const unsigned short* __restrict__ in, unsigned short* __restrict__ out,
    int CG, int C, int W, int inSS,
    int HO, int WO, int Wpo, int outSS, int total)
{
    int idx = blockIdx.x * 256 + threadIdx.x;
    if (idx >= total) return;
    int cg = idx % CG;
    int t  = idx / CG;
    int x  = t % WO;
    t /= WO;
    int y  = t % HO;
    int nl = t / HO;

    const unsigned short* pin = in + (size_t)nl * inSS + cg * 8;
    ushort8 mx = {0,0,0,0,0,0,0,0};
    #pragma unroll
    for (int dy = 0; dy < 3; ++dy)
        #pragma unroll
        for (int dx = 0; dx < 3; ++dx) {
            ushort8 v = *reinterpret_cast<const ushort8*>(
                pin + ((size_t)(2 * y + dy) * W + (2 * x + dx)) * C);
            #pragma unroll
            for (int j = 0; j < 8; ++j) mx[j] = v[j] > mx[j] ? v[j] : mx[j];
        }
    *reinterpret_cast<ushort8*>(
        out + (size_t)nl * outSS +
        ((size_t)(y + 1) * Wpo + (x + 1)) * C + cg * 8) = mx;
}

// ---------------------------------------------------------------------------
// 8) Fused pool2 (3x3 s2 on [17][17][256]) + global average pool -> fp32
// ---------------------------------------------------------------------------
__global__ __launch_bounds__(512) void pool2gap_k(
    const unsigned short* __restrict__ in, float* __restrict__ out,
    int inSS, int n0)
{
    __shared__ float part[256];
    const int nl = blockIdx.x;
    const int c    = threadIdx.x & 255;
    const int half = threadIdx.x >> 8;
    const unsigned short* p = in + (size_t)nl * inSS + c;
    float s = 0.0f;
    for (int w = half * 32; w < half * 32 + 32; ++w) {
        int y = w >> 3, x = w & 7;
        unsigned short mx = 0;
        #pragma unroll
        for (int dy = 0; dy < 3; ++dy)
            #pragma unroll
            for (int dx = 0; dx < 3; ++dx) {
                unsigned short v = p[((size_t)(2*y+dy) * 17 + (2*x+dx)) * 256];
                mx = v > mx ? v : mx;
            }
        s += bf2f(mx);
    }
    if (half) part[c] = s;
    __syncthreads();
    if (!half) out[(size_t)(n0 + nl) * 256 + c] = (s + part[c]) * (1.0f / 64.0f);
}

// ---------------------------------------------------------------------------
// 9) FC weight transpose: w[o][i] -> wT[i][o]
// ---------------------------------------------------------------------------
__global__ __launch_bounds__(256) void fcT_k(
    const float* __restrict__ w, float* __restrict__ wT, int O, int I, int total)
{
    int idx = blockIdx.x * 256 + threadIdx.x;
    if (idx >= total) return;
    int i = idx % I, o = idx / I;
    wT[(size_t)i * O + o] = w[idx];
}

// ---------------------------------------------------------------------------
// 10) Fused 3-layer FC head (256->512->256->512), one block per sample
// ---------------------------------------------------------------------------
__global__ __launch_bounds__(256) void fc_fused_k(
    const float* __restrict__ in,
    const float* __restrict__ w0T, const float* __restrict__ b0,
    const float* __restrict__ w1T, const float* __restrict__ b1,
    const float* __restrict__ w2T, const float* __restrict__ b2,
    float* __restrict__ out)
{
    __shared__ float s_in[256], s_h0[512], s_h1[256];
    const int n = blockIdx.x, t = threadIdx.x;
    s_in[t] = in[(size_t)n * 256 + t];
    __syncthreads();
    float a0 = 0.f, a1 = 0.f;
    for (int i = 0; i < 256; ++i) {
        float v = s_in[i];
        a0 += v * w0T[i * 512 + t];
        a1 += v * w0T[i * 512 + t + 256];
    }
    s_h0[t]       = fmaxf(a0 + b0[t], 0.0f);
    s_h0[t + 256] = fmaxf(a1 + b0[t + 256], 0.0f);
    __syncthreads();
    float h = 0.f;
    for (int i = 0; i < 512; ++i) h += s_h0[i] * w1T[i * 256 + t];
    s_h1[t] = fmaxf(h + b1[t], 0.0f);
    __syncthreads();
    a0 = 0.f; a1 = 0.f;
    for (int i = 0; i < 256; ++i) {
        float v = s_h1[i];
        a0 += v * w2T[i * 512 + t];
        a1 += v * w2T[i * 512 + t + 256];
    }
    out[(size_t)n * 512 + t]       = a0 + b2[t];
    out[(size_t)n * 512 + t + 256] = a1 + b2[t + 256];
}

// ---------------------------------------------------------------------------
// Launch. Per-sample u16 sizes (HWC):
//   A: G [76][76][40] = 231,040   (overlay: C1 [1225][128]=156,800)
//   B: C0 [5184][64]  = 331,776   (overlay: C2 [289][256]=73,984)
//   C: P0p [37][37][64]=87,616 + P1p [19][19][128]=46,208 = 133,824
// ---------------------------------------------------------------------------
extern "C" void kernel_launch(void* const* d_in, const int* in_sizes, int n_in,
                              void* d_out, int out_size, void* d_ws, size_t ws_size,
                              hipStream_t stream)
{
    const int*   X   = (const int*)d_in[0];
    const int*   rm  = (const int*)d_in[1];
    const float* emb = (const float*)d_in[2];
    const float* cw0 = (const float*)d_in[3];
    const float* cb0 = (const float*)d_in[4];
    const float* cw1 = (const float*)d_in[5];
    const float* cb1 = (const float*)d_in[6];
    const float* cw2 = (const float*)d_in[7];
    const float* cb2 = (const float*)d_in[8];
    const float* fw0 = (const float*)d_in[9];
    const float* fb0 = (const float*)d_in[10];
    const float* fw1 = (const float*)d_in[11];
    const float* fb1 = (const float*)d_in[12];
    const float* fw2 = (const float*)d_in[13];
    const float* fb2 = (const float*)d_in[14];
    float* out = (float*)d_out;

    char* p = (char*)d_ws;
    auto alloc = [&](size_t bytes) -> char* {
        char* r = p; p += (bytes + 255) & ~(size_t)255; return r;
    };
    unsigned short* WP0 = (unsigned short*)alloc((size_t)32 * 64 * 32 * 2);
    unsigned short* WP1 = (unsigned short*)alloc((size_t)18 * 128 * 32 * 2);
    unsigned short* WP2 = (unsigned short*)alloc((size_t)36 * 256 * 32 * 2);
    int* KT0 = (int*)alloc(128 * 4);
    int* KT1 = (int*)alloc(72 * 4);
    int* KT2 = (int*)alloc(144 * 4);
    unsigned long long* MASKS = (unsigned long long*)alloc(RR * 8);
    float* W0T  = (float*)alloc((size_t)256 * 512 * 4);
    float* W1T  = (float*)alloc((size_t)512 * 256 * 4);
    float* W2T  = (float*)alloc((size_t)256 * 512 * 4);
    float* GAPB = (float*)alloc((size_t)NB * 256 * 4);
    size_t fixed_bytes = (size_t)(p - (char*)d_ws);

    const size_t A_FL = 231040, B_FL = 331776, C_FL = 133824;   // u16
    const size_t per_sample = (A_FL + B_FL + C_FL) * 2 + 768;
    int Bc = 128;
    while (Bc > 1 && fixed_bytes + (size_t)Bc * per_sample > ws_size) Bc >>= 1;

    unsigned short* bufA = (unsigned short*)alloc((size_t)Bc * A_FL * 2);
    unsigned short* bufC = (unsigned short*)alloc((size_t)Bc * C_FL * 2);
    unsigned short* bufB = (unsigned short*)alloc((size_t)Bc * B_FL * 2);

    // ---- one-time prep (runs every call; graph-safe) ----
    build_masks_k<<<2, 256, 0, stream>>>(rm, MASKS);
    wpack_k<<<(32 * 64 * 32 + 255) / 256, 256, 0, stream>>>(
        cw0, WP0, 64, 33, 25, 5, 32 * 64 * 32);
    wpack_k<<<(18 * 128 * 32 + 255) / 256, 256, 0, stream>>>(
        cw1, WP1, 128, 64, 9, 8, 18 * 128 * 32);
    wpack_k<<<(36 * 256 * 32 + 255) / 256, 256, 0, stream>>>(
        cw2, WP2, 256, 128, 9, 16, 36 * 256 * 32);
    ktab_all_k<<<dim3(1, 3), 256, 0, stream>>>(KT0, KT1, KT2);
    fcT_k<<<(512 * 256 + 255) / 256, 256, 0, stream>>>(fw0, W0T, 512, 256, 512 * 256);
    fcT_k<<<(256 * 512 + 255) / 256, 256, 0, stream>>>(fw1, W1T, 256, 512, 256 * 512);
    fcT_k<<<(512 * 256 + 255) / 256, 256, 0, stream>>>(fw2, W2T, 512, 256, 512 * 256);

    // ---- chunked pipeline ----
    for (int n0 = 0; n0 < NB; n0 += Bc) {
        // zero only the halo borders (interiors fully overwritten each call)
        border_k<<<(Bc * 592 * 5 + 255) / 256, 256, 0, stream>>>(
            bufA, 76, 76, 5, 2, (int)A_FL, 592, Bc * 592 * 5);
        border_k<<<(Bc * 144 * 8 + 255) / 256, 256, 0, stream>>>(
            bufC, 37, 37, 8, 1, (int)C_FL, 144, Bc * 144 * 8);
        border_k<<<(Bc * 72 * 16 + 255) / 256, 256, 0, stream>>>(
            bufC + 87616, 19, 19, 16, 1, (int)C_FL, 72, Bc * 72 * 16);

        // encode -> A (HWC G [76][76][40], interior +2)
        encode_k<<<dim3(Bc, 18), 320, 0, stream>>>(X, MASKS, emb, bufA, n0, (int)A_FL);

        // conv0: A -> B  (15 24x16 tiles/sample, COUT=64, 32 ksteps)
        conv0_tile_k<32><<<dim3(15, Bc), 256, 0, stream>>>(
            bufA, WP0, KT0, cb0, bufB, (int)A_FL, (int)B_FL);
        // pool0: B [72][72][64] -> C P0p [37][37][64] interior +1
        pool_k<<<(Bc * 35 * 35 * 8 + 255) / 256, 256, 0, stream>>>(
            bufB, bufC, 8, 64, 72, (int)B_FL,
            35, 35, 37, (int)C_FL, Bc * 35 * 35 * 8);

        // conv1: C -> A  (M=1225, Mblk=256 -> 5 mblocks, COUT=128)
        conv_mfma_k<4, 8, 3, 8, 72, 29304, 18><<<dim3(5, 1, Bc), 256, 0, stream>>>(
            bufC, WP1, KT1, cb1, bufA, 35, 37,
            1225, (int)C_FL, (int)A_FL, 128);
        // pool1: A [35][35][128] -> C+87616 P1p [19][19][128] interior +1
        pool_k<<<(Bc * 17 * 17 * 16 + 255) / 256, 256, 0, stream>>>(
            bufA, bufC + 87616, 16, 128, 35, (int)A_FL,
            17, 17, 19, (int)C_FL, Bc * 17 * 17 * 16);

        // conv2: C+87616 -> B  (M=289, Mblk=128 -> 3 mblocks, 2 oc-blocks)
        conv_mfma_k<2, 8, 3, 16, 136, 28424, 36><<<dim3(3, 2, Bc), 256, 0, stream>>>(
            bufC + 87616, WP2, KT2, cb2, bufB, 17, 19,
            289, (int)C_FL, (int)B_FL, 256);

        // fused pool2 + GAP: B [17][17][256] -> GAPB fp32
        pool2gap_k<<<Bc, 512, 0, stream>>>(bufB, GAPB, (int)B_FL, n0);
    }

    // fused FC head
    fc_fused_k<<<NB, 256, 0, stream>>>(GAPB, W0T, fb0, W1T, fb1, W2T, fb2, out);
}

// Round 11
// 573.710 us; speedup vs baseline: 1.7326x; 1.0402x over previous
//
#include <hip/hip_runtime.h>
#include <hip/hip_bf16.h>
#include <cstdint>
#include <cstddef>

#define NB      128
#define RR      300
#define EMB     32

typedef __bf16 bf16x8 __attribute__((ext_vector_type(8)));
typedef float  f32x4  __attribute__((ext_vector_type(4)));
typedef unsigned short ushort8 __attribute__((ext_vector_type(8)));

__device__ __forceinline__ unsigned short f2bf(float f) {
    union { __hip_bfloat16 h; unsigned short u; } c;
    c.h = __float2bfloat16(f);
    return c.u;
}
__device__ __forceinline__ float bf2f(unsigned short u) {
    union { __hip_bfloat16 h; unsigned short u; } c;
    c.u = u;
    return __bfloat162float(c.h);
}

// ---------------------------------------------------------------------------
// 1) Room occupancy -> uint64 bitmask (bit b = dx*8+dy)
// ---------------------------------------------------------------------------
__global__ __launch_bounds__(256) void build_masks_k(
    const int* __restrict__ rm, unsigned long long* __restrict__ masks)
{
    int r = blockIdx.x * 256 + threadIdx.x;
    if (r >= RR) return;
    unsigned long long m = 0ull;
    #pragma unroll
    for (int b = 0; b < 64; ++b)
        if (rm[r * 64 + b]) m |= (1ull << b);
    masks[r] = m;
}

// ---------------------------------------------------------------------------
// 2) Border zero: zeroes only the halo pixels of a padded HWC buffer.
// ---------------------------------------------------------------------------
__global__ __launch_bounds__(256) void border_k(
    unsigned short* __restrict__ base, int Hp, int Wp, int CPG, int pad,
    int sampleStride, int nborder, int total)
{
    int idx = blockIdx.x * 256 + threadIdx.x;
    if (idx >= total) return;
    int c8 = idx % CPG;
    int t  = idx / CPG;
    int bi = t % nborder;
    int nl = t / nborder;

    int topN = pad * Wp;
    int y, x;
    if (bi < topN) {
        y = bi / Wp; x = bi - y * Wp;
    } else if (bi < 2 * topN) {
        int b2 = bi - topN;
        y = Hp - pad + b2 / Wp; x = b2 % Wp;
    } else {
        int mid = bi - 2 * topN;
        int rowlen = 2 * pad;
        y = pad + mid / rowlen;
        int r = mid % rowlen;
        x = r < pad ? r : Wp - pad + (r - pad);
    }
    uint4 z = make_uint4(0, 0, 0, 0);
    *reinterpret_cast<uint4*>(
        &base[((size_t)nl * sampleStride) +
              ((size_t)y * Wp + x) * (CPG * 8) + c8 * 8]) = z;
}

// ---------------------------------------------------------------------------
// 3) Encode, banded HWC. v4: wave-parallel hot-room walk — wave wv handles
//    rooms j = wv, wv+5, ...; lanes cover 8 dx x 8 channel-slots (5 ch).
//    5x shorter serial path than the all-threads-all-rooms walk.
// ---------------------------------------------------------------------------
__global__ __launch_bounds__(320) void encode_k(
    const int* __restrict__ X, const unsigned long long* __restrict__ masks,
    const float* __restrict__ emb, unsigned short* __restrict__ G,
    int n0, int sampleStride)
{
    __shared__ float tile[4][72][33];                  // 38016 B
    __shared__ unsigned s_pos[RR];                     // 1200 B
    __shared__ unsigned long long s_mask[RR];          // 2400 B
    __shared__ unsigned short s_list[320];             // 640 B
    __shared__ float s_emb[64 * 33];                   // 8448 B
    __shared__ int s_woff[8];
    __shared__ int s_cnt;

    const int nl = blockIdx.x, band = blockIdx.y;
    const int by = band * 4;
    const int n  = n0 + nl;
    const int tid = threadIdx.x;

    float* tf = &tile[0][0][0];
    for (int i = tid; i < 4 * 72 * 33; i += 320) tf[i] = 0.0f;

    // phase 1: preload rooms, ballot hot predicate, compact to dense list
    const int2* Xp = reinterpret_cast<const int2*>(X);
    bool hot = false;
    if (tid < RR) {
        int2 pos = Xp[n * RR + tid];
        s_pos[tid]  = (unsigned)pos.x | ((unsigned)pos.y << 16);
        s_mask[tid] = masks[tid];
        hot = (pos.y <= by + 3) && (pos.y + 7 >= by);
    }
    unsigned long long bal = __ballot(hot);
    if ((tid & 63) == 0) s_woff[tid >> 6] = (int)__popcll(bal);
    __syncthreads();
    if (tid == 0) {
        int acc = 0;
        #pragma unroll
        for (int w = 0; w < 5; ++w) { int c = s_woff[w]; s_woff[w] = acc; acc += c; }
        s_cnt = acc;
    }
    __syncthreads();
    if (hot) {
        int w = tid >> 6, b = tid & 63;
        unsigned long long before = (b == 0) ? 0ull : (bal & ((1ull << b) - 1ull));
        s_list[s_woff[w] + (int)__popcll(before)] = (unsigned short)tid;
    }
    __syncthreads();

    // phase 2: chunked, wave-parallel walk (operands all in LDS)
    const int lane = tid & 63;
    const int wvi  = tid >> 6;          // 0..4
    const int dx   = lane >> 3;         // 0..7
    const int c0   = (lane & 7) * 5;    // channels [c0, c0+5) ∩ [0,33)
    const int cnt  = s_cnt;
    for (int base = 0; base < cnt; base += 64) {
        int cn = cnt - base; if (cn > 64) cn = 64;
        for (int i = tid; i < cn * 33; i += 320) {
            int hi = i / 33, cc = i - hi * 33;
            int r = s_list[base + hi];
            s_emb[i] = (cc == 0) ? 1.0f : emb[r * EMB + cc - 1];
        }
        __syncthreads();
        for (int j = wvi; j < cn; j += 5) {
            int r = s_list[base + j];
            unsigned pxy = s_pos[r];
            int px = pxy & 0xffff, py = pxy >> 16;
            unsigned long long mm = s_mask[r] >> (dx * 8);
            int x = px + dx;
            float ev[5];
            #pragma unroll
            for (int q = 0; q < 5; ++q)
                ev[q] = (c0 + q < 33) ? s_emb[j * 33 + c0 + q] : 0.0f;
            #pragma unroll
            for (int dyb = 0; dyb < 4; ++dyb) {
                int dyr = by + dyb - py;
                if ((unsigned)dyr < 8u && ((mm >> dyr) & 1ull)) {
                    #pragma unroll
                    for (int q = 0; q < 5; ++q)
                        if (c0 + q < 33)
                            atomicAdd(&tile[dyb][x][c0 + q], ev[q]);
                }
            }
        }
        __syncthreads();
    }
    __syncthreads();

    // write-out: 4 rows x 72 px x 40ch as uint2 (4ch) chunks
    unsigned short* Gn = G + (size_t)nl * sampleStride;
    for (int i = tid; i < 4 * 72 * 10; i += 320) {
        int cc = i % 10;
        int t  = i / 10;
        int x  = t % 72;
        int dyb = t / 72;
        int c0w = cc * 4;
        unsigned short r[4];
        #pragma unroll
        for (int j = 0; j < 4; ++j)
            r[j] = (c0w + j < 33) ? f2bf(tile[dyb][x][c0w + j]) : 0;
        uint2 pk;
        pk.x = (unsigned)r[0] | ((unsigned)r[1] << 16);
        pk.y = (unsigned)r[2] | ((unsigned)r[3] << 16);
        *reinterpret_cast<uint2*>(
            &Gn[((size_t)(by + dyb + 2) * 76 + (x + 2)) * 40 + c0w]) = pk;
    }
}

// ---------------------------------------------------------------------------
// 4) Weight pack: w[oc][ci][K][K] fp32 -> bf16 wPT[kb][oc][32]
// ---------------------------------------------------------------------------
__global__ __launch_bounds__(256) void wpack_k(
    const float* __restrict__ w, unsigned short* __restrict__ wPT,
    int COUT, int CIN, int KK, int gpc, int total)
{
    int idx = blockIdx.x * 256 + threadIdx.x;
    if (idx >= total) return;
    int kk = idx & 31;
    int t  = idx >> 5;
    int oc = t % COUT;
    int kb = t / COUT;
    int g  = kb * 4 + (kk >> 3);
    int j  = kk & 7;
    int shift = g / gpc;
    int ci    = (g % gpc) * 8 + j;
    float v = (shift < KK && ci < CIN)
        ? w[(size_t)oc * CIN * KK + (size_t)ci * KK + shift] : 0.0f;
    wPT[idx] = f2bf(v);
}

// ---------------------------------------------------------------------------
// 5) ktab: LDS-space group offsets (elem units)
// ---------------------------------------------------------------------------
__global__ __launch_bounds__(256) void ktab_all_k(
    int* __restrict__ kt0, int* __restrict__ kt1, int* __restrict__ kt2)
{
    int t = threadIdx.x;
    int which = blockIdx.y;
    int ngr, gpc, K, Wp, CL;
    int* dst;
    if (which == 0)      { ngr = 128; gpc = 5;  K = 5; Wp = 20; CL = 40;  dst = kt0; }
    else if (which == 1) { ngr = 72;  gpc = 8;  K = 3; Wp = 37; CL = 72;  dst = kt1; }
    else                 { ngr = 144; gpc = 16; K = 3; Wp = 19; CL = 136; dst = kt2; }
    if (t >= ngr) return;
    int shift = t / gpc;
    int off = 0;
    if (shift < K * K) {
        int ky = shift / K, kx = shift % K;
        off = (ky * Wp + kx) * CL + (t % gpc) * 8;
    }
    dst[t] = off;
}

// ---------------------------------------------------------------------------
// 6a) conv0: 24x16-spatial-tile implicit-GEMM, bf16 MFMA 16x16x32.
// ---------------------------------------------------------------------------
template<int KSTEPS>
__global__ __launch_bounds__(256) void conv0_tile_k(
    const unsigned short* __restrict__ inP,   // [B][76][76][40] bf16
    const unsigned short* __restrict__ wPT,   // [KSTEPS][64][32] bf16
    const int* __restrict__ ktab,             // [KSTEPS*4] LDS offsets
    const float* __restrict__ bias,
    unsigned short* __restrict__ out,         // [B][5184][64] bf16
    int inSS, int outSS)
{
    constexpr int CL = 40;
    constexpr int LP = 72;
    __shared__ __align__(16) unsigned short slab[28 * 20 * CL];  // 44800 B
    unsigned short* s_c = slab;

    const int tid = threadIdx.x;
    const int tl  = blockIdx.x;           // 0..14
    const int nl  = blockIdx.y;
    const int tyi = tl / 5, txi = tl % 5;
    const int y0 = tyi * 24;
    const int x0 = txi < 4 ? txi * 16 : 56;

    const int lane = tid & 63, wv = tid >> 6, frow = lane & 15, fq = lane >> 4;

    const unsigned short* in_n = inP + (size_t)nl * inSS;
    {
        const uint4* src = reinterpret_cast<const uint4*>(in_n);
        uint4* dst = reinterpret_cast<uint4*>(slab);
        #pragma unroll
        for (int it = 0; it < 11; ++it) {
            int q = tid + it * 256;
            if (q < 2800) {
                int r = q / 100, c = q - r * 100;
                dst[q] = src[((y0 + r) * 76 + x0) * 5 + c];
            }
        }
    }

    int ldsb[6];
    #pragma unroll
    for (int mf = 0; mf < 6; ++mf)
        ldsb[mf] = ((mf * 4 + wv) * 20 + frow) * CL;

    const unsigned short* wbase = wPT + (size_t)frow * 32 + fq * 8;

    f32x4 acc[6][4];
    #pragma unroll
    for (int a = 0; a < 6; ++a)
        #pragma unroll
        for (int b = 0; b < 4; ++b) acc[a][b] = (f32x4){0.f, 0.f, 0.f, 0.f};

    __syncthreads();

    #pragma unroll 2
    for (int kb = 0; kb < KSTEPS; ++kb) {
        int go = ktab[kb * 4 + fq];
        bf16x8 af[6];
        #pragma unroll
        for (int mf = 0; mf < 6; ++mf)
            af[mf] = *reinterpret_cast<const bf16x8*>(&slab[ldsb[mf] + go]);
        const unsigned short* wk = wbase + (size_t)kb * 64 * 32;
        #pragma unroll
        for (int ng = 0; ng < 4; ++ng) {
            bf16x8 bf = *reinterpret_cast<const bf16x8*>(wk + ng * 16 * 32);
            #pragma unroll
            for (int mf = 0; mf < 6; ++mf)
                acc[mf][ng] = __builtin_amdgcn_mfma_f32_16x16x32_bf16(
                    af[mf], bf, acc[mf][ng], 0, 0, 0);
        }
    }

    unsigned short* out_n = out + (size_t)nl * outSS;
    const int erow = tid >> 2, eseg = tid & 3;
    #pragma unroll
    for (int mf = 0; mf < 6; ++mf) {
        __syncthreads();
        #pragma unroll
        for (int ng = 0; ng < 4; ++ng) {
            float bv = bias[ng * 16 + frow];
            #pragma unroll
            for (int j = 0; j < 4; ++j)
                s_c[(wv * 16 + fq * 4 + j) * LP + ng * 16 + frow] =
                    f2bf(fmaxf(acc[mf][ng][j] + bv, 0.0f));
        }
        __syncthreads();
        {
            int ty = mf * 4 + (erow >> 4);
            int tx = erow & 15;
            int pos = (y0 + ty) * 72 + (x0 + tx);
            ushort8 v0 = *reinterpret_cast<const ushort8*>(
                &s_c[erow * LP + eseg * 16]);
            ushort8 v1 = *reinterpret_cast<const ushort8*>(
                &s_c[erow * LP + eseg * 16 + 8]);
            unsigned short* op = out_n + (size_t)pos * 64 + eseg * 16;
            *reinterpret_cast<ushort8*>(op) = v0;
            *reinterpret_cast<ushort8*>(op + 8) = v1;
        }
    }
}

// ---------------------------------------------------------------------------
// 6b) Generic row-slab implicit-GEMM conv (conv1/conv2), bf16 MFMA 16x16x32.
// ---------------------------------------------------------------------------
template<int MFRAG, int NG, int KH, int CPG, int CL, int SLAB, int KSTEPS>
__global__ __launch_bounds__(256) void conv_mfma_k(
    const unsigned short* __restrict__ inP,
    const unsigned short* __restrict__ wPT,
    const int* __restrict__ ktab,
    const float* __restrict__ bias,
    unsigned short* __restrict__ out,
    int W, int Wp, int Mtot, int inSS, int outSS, int COUT)
{
    constexpr int Mblk = MFRAG * 64;
    constexpr int NOC  = NG * 16;
    constexpr int SEGS = NOC / 16;
    constexpr int LP   = NOC + 8;
    constexpr int CP   = CPG * 8;
    constexpr int SMEM = (SLAB * 2 > 64 * LP * 2) ? SLAB * 2 : 64 * LP * 2;
    __shared__ __align__(16) char smem[SMEM];
    unsigned short* slab = reinterpret_cast<unsigned short*>(smem);
    unsigned short* s_c  = reinterpret_cast<unsigned short*>(smem);

    const int tid  = threadIdx.x;
    const int mb   = blockIdx.x;
    const int ocb  = blockIdx.y;
    const int nl   = blockIdx.z;
    const int lane = tid & 63;
    const int wv   = tid >> 6;
    const int frow = lane & 15;
    const int fq   = lane >> 4;

    const int p0    = mb * Mblk;
    const int y0    = p0 / W;
    const int plast = (p0 + Mblk < Mtot ? p0 + Mblk : Mtot) - 1;
    const int rows  = plast / W - y0 + KH;

    const unsigned short* in_n =
        inP + (size_t)nl * inSS + (size_t)y0 * Wp * CP;
    const int nchunks = rows * Wp * CPG;
    for (int q = tid; q < nchunks; q += 256) {
        int pix = q / CPG, c8 = q - pix * CPG;
        uint4 v = reinterpret_cast<const uint4*>(in_n)[q];
        *reinterpret_cast<uint4*>(&slab[pix * CL + c8 * 8]) = v;
    }

    int ldsb[MFRAG];
    #pragma unroll
    for (int mf = 0; mf < MFRAG; ++mf) {
        int p  = p0 + mf * 64 + wv * 16 + frow;
        int pc = p < Mtot ? p : (Mtot - 1);
        int y  = pc / W;
        int x  = pc - y * W;
        ldsb[mf] = ((y - y0) * Wp + x) * CL;
    }
    const unsigned short* wbase =
        wPT + ((size_t)(ocb * NOC + frow)) * 32 + fq * 8;

    f32x4 acc[MFRAG][NG];
    #pragma unroll
    for (int mf = 0; mf < MFRAG; ++mf)
        #pragma unroll
        for (int ng = 0; ng < NG; ++ng)
            acc[mf][ng] = (f32x4){0.f, 0.f, 0.f, 0.f};

    __syncthreads();

    for (int kb = 0; kb < KSTEPS; ++kb) {
        int go = ktab[kb * 4 + fq];
        bf16x8 af[MFRAG];
        #pragma unroll
        for (int mf = 0; mf < MFRAG; ++mf)
            af[mf] = *reinterpret_cast<const bf16x8*>(&slab[ldsb[mf] + go]);
        const unsigned short* wk = wbase + (size_t)kb * COUT * 32;
        #pragma unroll
        for (int ng = 0; ng < NG; ++ng) {
            bf16x8 bf = *reinterpret_cast<const bf16x8*>(wk + ng * 16 * 32);
            #pragma unroll
            for (int mf = 0; mf < MFRAG; ++mf)
                acc[mf][ng] = __builtin_amdgcn_mfma_f32_16x16x32_bf16(
                    af[mf], bf, acc[mf][ng], 0, 0, 0);
        }
    }

    unsigned short* out_n = out + (size_t)nl * outSS;
    #pragma unroll
    for (int mf = 0; mf < MFRAG; ++mf) {
        __syncthreads();
        #pragma unroll
        for (int ng = 0; ng < NG; ++ng) {
            float bv = bias[ocb * NOC + ng * 16 + frow];
            #pragma unroll
            for (int j = 0; j < 4; ++j)
                s_c[(wv * 16 + fq * 4 + j) * LP + ng * 16 + frow] =
                    f2bf(fmaxf(acc[mf][ng][j] + bv, 0.0f));
        }
        __syncthreads();
        for (int t = tid; t < 64 * SEGS; t += 256) {
            int row = t / SEGS, seg = t % SEGS;
            int p = p0 + mf * 64 + row;
            if (p < Mtot) {
                ushort8 v0 = *reinterpret_cast<const ushort8*>(
                    &s_c[row * LP + seg * 16]);
                ushort8 v1 = *reinterpret_cast<const ushort8*>(
                    &s_c[row * LP + seg * 16 + 8]);
                unsigned short* op =
                    out_n + (size_t)p * COUT + ocb * NOC + seg * 16;
                *reinterpret_cast<ushort8*>(op) = v0;
                *reinterpret_cast<ushort8*>(op + 8) = v1;
            }
        }
    }
}

// ---------------------------------------------------------------------------
// 7) MaxPool 3x3 s2 VALID, HWC, ushort8 (post-ReLU: u16 max).
// ---------------------------------------------------------------------------
__global__ __launch_bounds__(256) void pool_k(
    const unsigned short* __restrict__ in, unsigned short* __restrict__ out,
    int CG, int C, int W, int inSS,
    int HO, int WO, int Wpo, int outSS, int total)
{
    int idx = blockIdx.x * 256 + threadIdx.x;
    if (idx >= total) return;
    int cg = idx % CG;
    int t  = idx / CG;
    int x  = t % WO;
    t /= WO;
    int y  = t % HO;
    int nl = t / HO;

    const unsigned short* pin = in + (size_t)nl * inSS + cg * 8;
    ushort8 mx = {0,0,0,0,0,0,0,0};
    #pragma unroll
    for (int dy = 0; dy < 3; ++dy)
        #pragma unroll
        for (int dx = 0; dx < 3; ++dx) {
            ushort8 v = *reinterpret_cast<const ushort8*>(
                pin + ((size_t)(2 * y + dy) * W + (2 * x + dx)) * C);
            #pragma unroll
            for (int j = 0; j < 8; ++j) mx[j] = v[j] > mx[j] ? v[j] : mx[j];
        }
    *reinterpret_cast<ushort8*>(
        out + (size_t)nl * outSS +
        ((size_t)(y + 1) * Wpo + (x + 1)) * C + cg * 8) = mx;
}

// ---------------------------------------------------------------------------
// 8) Fused pool2 (3x3 s2 on [17][17][256]) + global average pool -> fp32
// ---------------------------------------------------------------------------
__global__ __launch_bounds__(512) void pool2gap_k(
    const unsigned short* __restrict__ in, float* __restrict__ out,
    int inSS, int n0)
{
    __shared__ float part[256];
    const int nl = blockIdx.x;
    const int c    = threadIdx.x & 255;
    const int half = threadIdx.x >> 8;
    const unsigned short* p = in + (size_t)nl * inSS + c;
    float s = 0.0f;
    for (int w = half * 32; w < half * 32 + 32; ++w) {
        int y = w >> 3, x = w & 7;
        unsigned short mx = 0;
        #pragma unroll
        for (int dy = 0; dy < 3; ++dy)
            #pragma unroll
            for (int dx = 0; dx < 3; ++dx) {
                unsigned short v = p[((size_t)(2*y+dy) * 17 + (2*x+dx)) * 256];
                mx = v > mx ? v : mx;
            }
        s += bf2f(mx);
    }
    if (half) part[c] = s;
    __syncthreads();
    if (!half) out[(size_t)(n0 + nl) * 256 + c] = (s + part[c]) * (1.0f / 64.0f);
}

// ---------------------------------------------------------------------------
// 9) FC weight transpose: w[o][i] -> wT[i][o]
// ---------------------------------------------------------------------------
__global__ __launch_bounds__(256) void fcT_k(
    const float* __restrict__ w, float* __restrict__ wT, int O, int I, int total)
{
    int idx = blockIdx.x * 256 + threadIdx.x;
    if (idx >= total) return;
    int i = idx % I, o = idx / I;
    wT[(size_t)i * O + o] = w[idx];
}

// ---------------------------------------------------------------------------
// 10) Fused 3-layer FC head (256->512->256->512), one block per sample
// ---------------------------------------------------------------------------
__global__ __launch_bounds__(256) void fc_fused_k(
    const float* __restrict__ in,
    const float* __restrict__ w0T, const float* __restrict__ b0,
    const float* __restrict__ w1T, const float* __restrict__ b1,
    const float* __restrict__ w2T, const float* __restrict__ b2,
    float* __restrict__ out)
{
    __shared__ float s_in[256], s_h0[512], s_h1[256];
    const int n = blockIdx.x, t = threadIdx.x;
    s_in[t] = in[(size_t)n * 256 + t];
    __syncthreads();
    float a0 = 0.f, a1 = 0.f;
    for (int i = 0; i < 256; ++i) {
        float v = s_in[i];
        a0 += v * w0T[i * 512 + t];
        a1 += v * w0T[i * 512 + t + 256];
    }
    s_h0[t]       = fmaxf(a0 + b0[t], 0.0f);
    s_h0[t + 256] = fmaxf(a1 + b0[t + 256], 0.0f);
    __syncthreads();
    float h = 0.f;
    for (int i = 0; i < 512; ++i) h += s_h0[i] * w1T[i * 256 + t];
    s_h1[t] = fmaxf(h + b1[t], 0.0f);
    __syncthreads();
    a0 = 0.f; a1 = 0.f;
    for (int i = 0; i < 256; ++i) {
        float v = s_h1[i];
        a0 += v * w2T[i * 512 + t];
        a1 += v * w2T[i * 512 + t + 256];
    }
    out[(size_t)n * 512 + t]       = a0 + b2[t];
    out[(size_t)n * 512 + t + 256] = a1 + b2[t + 256];
}

// ---------------------------------------------------------------------------
// Launch. Per-sample u16 sizes (HWC):
//   A: G [76][76][40] = 231,040   (overlay: C1 [1225][128]=156,800)
//   B: C0 [5184][64]  = 331,776   (overlay: C2 [289][256]=73,984)
//   C: P0p [37][37][64]=87,616 + P1p [19][19][128]=46,208 = 133,824
// ---------------------------------------------------------------------------
extern "C" void kernel_launch(void* const* d_in, const int* in_sizes, int n_in,
                              void* d_out, int out_size, void* d_ws, size_t ws_size,
                              hipStream_t stream)
{
    const int*   X   = (const int*)d_in[0];
    const int*   rm  = (const int*)d_in[1];
    const float* emb = (const float*)d_in[2];
    const float* cw0 = (const float*)d_in[3];
    const float* cb0 = (const float*)d_in[4];
    const float* cw1 = (const float*)d_in[5];
    const float* cb1 = (const float*)d_in[6];
    const float* cw2 = (const float*)d_in[7];
    const float* cb2 = (const float*)d_in[8];
    const float* fw0 = (const float*)d_in[9];
    const float* fb0 = (const float*)d_in[10];
    const float* fw1 = (const float*)d_in[11];
    const float* fb1 = (const float*)d_in[12];
    const float* fw2 = (const float*)d_in[13];
    const float* fb2 = (const float*)d_in[14];
    float* out = (float*)d_out;

    char* p = (char*)d_ws;
    auto alloc = [&](size_t bytes) -> char* {
        char* r = p; p += (bytes + 255) & ~(size_t)255; return r;
    };
    unsigned short* WP0 = (unsigned short*)alloc((size_t)32 * 64 * 32 * 2);
    unsigned short* WP1 = (unsigned short*)alloc((size_t)18 * 128 * 32 * 2);
    unsigned short* WP2 = (unsigned short*)alloc((size_t)36 * 256 * 32 * 2);
    int* KT0 = (int*)alloc(128 * 4);
    int* KT1 = (int*)alloc(72 * 4);
    int* KT2 = (int*)alloc(144 * 4);
    unsigned long long* MASKS = (unsigned long long*)alloc(RR * 8);
    float* W0T  = (float*)alloc((size_t)256 * 512 * 4);
    float* W1T  = (float*)alloc((size_t)512 * 256 * 4);
    float* W2T  = (float*)alloc((size_t)256 * 512 * 4);
    float* GAPB = (float*)alloc((size_t)NB * 256 * 4);
    size_t fixed_bytes = (size_t)(p - (char*)d_ws);

    const size_t A_FL = 231040, B_FL = 331776, C_FL = 133824;   // u16
    const size_t per_sample = (A_FL + B_FL + C_FL) * 2 + 768;
    int Bc = 128;
    while (Bc > 1 && fixed_bytes + (size_t)Bc * per_sample > ws_size) Bc >>= 1;

    unsigned short* bufA = (unsigned short*)alloc((size_t)Bc * A_FL * 2);
    unsigned short* bufC = (unsigned short*)alloc((size_t)Bc * C_FL * 2);
    unsigned short* bufB = (unsigned short*)alloc((size_t)Bc * B_FL * 2);

    // ---- one-time prep (runs every call; graph-safe) ----
    build_masks_k<<<2, 256, 0, stream>>>(rm, MASKS);
    wpack_k<<<(32 * 64 * 32 + 255) / 256, 256, 0, stream>>>(
        cw0, WP0, 64, 33, 25, 5, 32 * 64 * 32);
    wpack_k<<<(18 * 128 * 32 + 255) / 256, 256, 0, stream>>>(
        cw1, WP1, 128, 64, 9, 8, 18 * 128 * 32);
    wpack_k<<<(36 * 256 * 32 + 255) / 256, 256, 0, stream>>>(
        cw2, WP2, 256, 128, 9, 16, 36 * 256 * 32);
    ktab_all_k<<<dim3(1, 3), 256, 0, stream>>>(KT0, KT1, KT2);
    fcT_k<<<(512 * 256 + 255) / 256, 256, 0, stream>>>(fw0, W0T, 512, 256, 512 * 256);
    fcT_k<<<(256 * 512 + 255) / 256, 256, 0, stream>>>(fw1, W1T, 256, 512, 256 * 512);
    fcT_k<<<(512 * 256 + 255) / 256, 256, 0, stream>>>(fw2, W2T, 512, 256, 512 * 256);

    // ---- chunked pipeline ----
    for (int n0 = 0; n0 < NB; n0 += Bc) {
        // zero only the halo borders (interiors fully overwritten each call)
        border_k<<<(Bc * 592 * 5 + 255) / 256, 256, 0, stream>>>(
            bufA, 76, 76, 5, 2, (int)A_FL, 592, Bc * 592 * 5);
        border_k<<<(Bc * 144 * 8 + 255) / 256, 256, 0, stream>>>(
            bufC, 37, 37, 8, 1, (int)C_FL, 144, Bc * 144 * 8);
        border_k<<<(Bc * 72 * 16 + 255) / 256, 256, 0, stream>>>(
            bufC + 87616, 19, 19, 16, 1, (int)C_FL, 72, Bc * 72 * 16);

        // encode -> A (HWC G [76][76][40], interior +2)
        encode_k<<<dim3(Bc, 18), 320, 0, stream>>>(X, MASKS, emb, bufA, n0, (int)A_FL);

        // conv0: A -> B  (15 24x16 tiles/sample, COUT=64, 32 ksteps)
        conv0_tile_k<32><<<dim3(15, Bc), 256, 0, stream>>>(
            bufA, WP0, KT0, cb0, bufB, (int)A_FL, (int)B_FL);
        // pool0: B [72][72][64] -> C P0p [37][37][64] interior +1
        pool_k<<<(Bc * 35 * 35 * 8 + 255) / 256, 256, 0, stream>>>(
            bufB, bufC, 8, 64, 72, (int)B_FL,
            35, 35, 37, (int)C_FL, Bc * 35 * 35 * 8);

        // conv1: C -> A  (M=1225, Mblk=256 -> 5 mblocks, COUT=128)
        conv_mfma_k<4, 8, 3, 8, 72, 29304, 18><<<dim3(5, 1, Bc), 256, 0, stream>>>(
            bufC, WP1, KT1, cb1, bufA, 35, 37,
            1225, (int)C_FL, (int)A_FL, 128);
        // pool1: A [35][35][128] -> C+87616 P1p [19][19][128] interior +1
        pool_k<<<(Bc * 17 * 17 * 16 + 255) / 256, 256, 0, stream>>>(
            bufA, bufC + 87616, 16, 128, 35, (int)A_FL,
            17, 17, 19, (int)C_FL, Bc * 17 * 17 * 16);

        // conv2: C+87616 -> B  (M=289, Mblk=128 -> 3 mblocks, 2 oc-blocks)
        conv_mfma_k<2, 8, 3, 16, 136, 28424, 36><<<dim3(3, 2, Bc), 256, 0, stream>>>(
            bufC + 87616, WP2, KT2, cb2, bufB, 17, 19,
            289, (int)C_FL, (int)B_FL, 256);

        // fused pool2 + GAP: B [17][17][256] -> GAPB fp32
        pool2gap_k<<<Bc, 512, 0, stream>>>(bufB, GAPB, (int)B_FL, n0);
    }

    // fused FC head
    fc_fused_k<<<NB, 256, 0, stream>>>(GAPB, W0T, fb0, W1T, fb1, W2T, fb2, out);
}

// Round 12
// 537.023 us; speedup vs baseline: 1.8510x; 1.0683x over previous
//
#include <hip/hip_runtime.h>
#include <hip/hip_bf16.h>
#include <cstdint>
#include <cstddef>

#define NB      128
#define RR      300
#define EMB     32

typedef __bf16 bf16x8 __attribute__((ext_vector_type(8)));
typedef float  f32x4  __attribute__((ext_vector_type(4)));
typedef unsigned short ushort8 __attribute__((ext_vector_type(8)));

__device__ __forceinline__ unsigned short f2bf(float f) {
    union { __hip_bfloat16 h; unsigned short u; } c;
    c.h = __float2bfloat16(f);
    return c.u;
}
__device__ __forceinline__ float bf2f(unsigned short u) {
    union { __hip_bfloat16 h; unsigned short u; } c;
    c.u = u;
    return __bfloat162float(c.h);
}

// ---------------------------------------------------------------------------
// 1) Room occupancy -> uint64 bitmask (bit b = dx*8+dy)
// ---------------------------------------------------------------------------
__global__ __launch_bounds__(256) void build_masks_k(
    const int* __restrict__ rm, unsigned long long* __restrict__ masks)
{
    int r = blockIdx.x * 256 + threadIdx.x;
    if (r >= RR) return;
    unsigned long long m = 0ull;
    #pragma unroll
    for (int b = 0; b < 64; ++b)
        if (rm[r * 64 + b]) m |= (1ull << b);
    masks[r] = m;
}

// ---------------------------------------------------------------------------
// 2) Border zero: zeroes only the halo pixels of a padded HWC buffer.
// ---------------------------------------------------------------------------
__global__ __launch_bounds__(256) void border_k(
    unsigned short* __restrict__ base, int Hp, int Wp, int CPG, int pad,
    int sampleStride, int nborder, int total)
{
    int idx = blockIdx.x * 256 + threadIdx.x;
    if (idx >= total) return;
    int c8 = idx % CPG;
    int t  = idx / CPG;
    int bi = t % nborder;
    int nl = t / nborder;

    int topN = pad * Wp;
    int y, x;
    if (bi < topN) {
        y = bi / Wp; x = bi - y * Wp;
    } else if (bi < 2 * topN) {
        int b2 = bi - topN;
        y = Hp - pad + b2 / Wp; x = b2 % Wp;
    } else {
        int mid = bi - 2 * topN;
        int rowlen = 2 * pad;
        y = pad + mid / rowlen;
        int r = mid % rowlen;
        x = r < pad ? r : Wp - pad + (r - pad);
    }
    uint4 z = make_uint4(0, 0, 0, 0);
    *reinterpret_cast<uint4*>(
        &base[((size_t)nl * sampleStride) +
              ((size_t)y * Wp + x) * (CPG * 8) + c8 * 8]) = z;
}

// ---------------------------------------------------------------------------
// 3) Encode, banded HWC. v4: wave-parallel hot-room walk.
// ---------------------------------------------------------------------------
__global__ __launch_bounds__(320) void encode_k(
    const int* __restrict__ X, const unsigned long long* __restrict__ masks,
    const float* __restrict__ emb, unsigned short* __restrict__ G,
    int n0, int sampleStride)
{
    __shared__ float tile[4][72][33];
    __shared__ unsigned s_pos[RR];
    __shared__ unsigned long long s_mask[RR];
    __shared__ unsigned short s_list[320];
    __shared__ float s_emb[64 * 33];
    __shared__ int s_woff[8];
    __shared__ int s_cnt;

    const int nl = blockIdx.x, band = blockIdx.y;
    const int by = band * 4;
    const int n  = n0 + nl;
    const int tid = threadIdx.x;

    float* tf = &tile[0][0][0];
    for (int i = tid; i < 4 * 72 * 33; i += 320) tf[i] = 0.0f;

    const int2* Xp = reinterpret_cast<const int2*>(X);
    bool hot = false;
    if (tid < RR) {
        int2 pos = Xp[n * RR + tid];
        s_pos[tid]  = (unsigned)pos.x | ((unsigned)pos.y << 16);
        s_mask[tid] = masks[tid];
        hot = (pos.y <= by + 3) && (pos.y + 7 >= by);
    }
    unsigned long long bal = __ballot(hot);
    if ((tid & 63) == 0) s_woff[tid >> 6] = (int)__popcll(bal);
    __syncthreads();
    if (tid == 0) {
        int acc = 0;
        #pragma unroll
        for (int w = 0; w < 5; ++w) { int c = s_woff[w]; s_woff[w] = acc; acc += c; }
        s_cnt = acc;
    }
    __syncthreads();
    if (hot) {
        int w = tid >> 6, b = tid & 63;
        unsigned long long before = (b == 0) ? 0ull : (bal & ((1ull << b) - 1ull));
        s_list[s_woff[w] + (int)__popcll(before)] = (unsigned short)tid;
    }
    __syncthreads();

    const int lane = tid & 63;
    const int wvi  = tid >> 6;
    const int dx   = lane >> 3;
    const int c0   = (lane & 7) * 5;
    const int cnt  = s_cnt;
    for (int base = 0; base < cnt; base += 64) {
        int cn = cnt - base; if (cn > 64) cn = 64;
        for (int i = tid; i < cn * 33; i += 320) {
            int hi = i / 33, cc = i - hi * 33;
            int r = s_list[base + hi];
            s_emb[i] = (cc == 0) ? 1.0f : emb[r * EMB + cc - 1];
        }
        __syncthreads();
        for (int j = wvi; j < cn; j += 5) {
            int r = s_list[base + j];
            unsigned pxy = s_pos[r];
            int px = pxy & 0xffff, py = pxy >> 16;
            unsigned long long mm = s_mask[r] >> (dx * 8);
            int x = px + dx;
            float ev[5];
            #pragma unroll
            for (int q = 0; q < 5; ++q)
                ev[q] = (c0 + q < 33) ? s_emb[j * 33 + c0 + q] : 0.0f;
            #pragma unroll
            for (int dyb = 0; dyb < 4; ++dyb) {
                int dyr = by + dyb - py;
                if ((unsigned)dyr < 8u && ((mm >> dyr) & 1ull)) {
                    #pragma unroll
                    for (int q = 0; q < 5; ++q)
                        if (c0 + q < 33)
                            atomicAdd(&tile[dyb][x][c0 + q], ev[q]);
                }
            }
        }
        __syncthreads();
    }
    __syncthreads();

    unsigned short* Gn = G + (size_t)nl * sampleStride;
    for (int i = tid; i < 4 * 72 * 10; i += 320) {
        int cc = i % 10;
        int t  = i / 10;
        int x  = t % 72;
        int dyb = t / 72;
        int c0w = cc * 4;
        unsigned short r[4];
        #pragma unroll
        for (int j = 0; j < 4; ++j)
            r[j] = (c0w + j < 33) ? f2bf(tile[dyb][x][c0w + j]) : 0;
        uint2 pk;
        pk.x = (unsigned)r[0] | ((unsigned)r[1] << 16);
        pk.y = (unsigned)r[2] | ((unsigned)r[3] << 16);
        *reinterpret_cast<uint2*>(
            &Gn[((size_t)(by + dyb + 2) * 76 + (x + 2)) * 40 + c0w]) = pk;
    }
}

// ---------------------------------------------------------------------------
// 4) Weight pack: w[oc][ci][K][K] fp32 -> bf16 wPT[kb][oc][32]
// ---------------------------------------------------------------------------
__global__ __launch_bounds__(256) void wpack_k(
    const float* __restrict__ w, unsigned short* __restrict__ wPT,
    int COUT, int CIN, int KK, int gpc, int total)
{
    int idx = blockIdx.x * 256 + threadIdx.x;
    if (idx >= total) return;
    int kk = idx & 31;
    int t  = idx >> 5;
    int oc = t % COUT;
    int kb = t / COUT;
    int g  = kb * 4 + (kk >> 3);
    int j  = kk & 7;
    int shift = g / gpc;
    int ci    = (g % gpc) * 8 + j;
    float v = (shift < KK && ci < CIN)
        ? w[(size_t)oc * CIN * KK + (size_t)ci * KK + shift] : 0.0f;
    wPT[idx] = f2bf(v);
}

// ---------------------------------------------------------------------------
// 5) ktab: LDS-space group offsets (elem units)
// ---------------------------------------------------------------------------
__global__ __launch_bounds__(256) void ktab_all_k(
    int* __restrict__ kt0, int* __restrict__ kt1, int* __restrict__ kt2)
{
    int t = threadIdx.x;
    int which = blockIdx.y;
    int ngr, gpc, K, Wp, CL;
    int* dst;
    if (which == 0)      { ngr = 128; gpc = 5;  K = 5; Wp = 20; CL = 40;  dst = kt0; }
    else if (which == 1) { ngr = 72;  gpc = 8;  K = 3; Wp = 37; CL = 72;  dst = kt1; }
    else                 { ngr = 144; gpc = 16; K = 3; Wp = 19; CL = 136; dst = kt2; }
    if (t >= ngr) return;
    int shift = t / gpc;
    int off = 0;
    if (shift < K * K) {
        int ky = shift / K, kx = shift % K;
        off = (ky * Wp + kx) * CL + (t % gpc) * 8;
    }
    dst[t] = off;
}

// ---------------------------------------------------------------------------
// 6a) conv0: 24x16-spatial-tile implicit-GEMM, bf16 MFMA 16x16x32.
//     __launch_bounds__(256,3): LDS caps occupancy at 3 blocks/CU anyway, so
//     allow ~170 VGPR — keeps addressing resident (kills VALU recompute).
//     ktab cached in LDS.
// ---------------------------------------------------------------------------
template<int KSTEPS>
__global__ __launch_bounds__(256, 3) void conv0_tile_k(
    const unsigned short* __restrict__ inP,   // [B][76][76][40] bf16
    const unsigned short* __restrict__ wPT,   // [KSTEPS][64][32] bf16
    const int* __restrict__ ktab,             // [KSTEPS*4] LDS offsets
    const float* __restrict__ bias,
    unsigned short* __restrict__ out,         // [B][5184][64] bf16
    int inSS, int outSS)
{
    constexpr int CL = 40;
    constexpr int LP = 72;
    __shared__ __align__(16) unsigned short slab[28 * 20 * CL];  // 44800 B
    __shared__ int s_kt[KSTEPS * 4];
    unsigned short* s_c = slab;

    const int tid = threadIdx.x;
    const int tl  = blockIdx.x;           // 0..14
    const int nl  = blockIdx.y;
    const int tyi = tl / 5, txi = tl % 5;
    const int y0 = tyi * 24;
    const int x0 = txi < 4 ? txi * 16 : 56;

    const int lane = tid & 63, wv = tid >> 6, frow = lane & 15, fq = lane >> 4;

    if (tid < KSTEPS * 4) s_kt[tid] = ktab[tid];

    const unsigned short* in_n = inP + (size_t)nl * inSS;
    {
        const uint4* src = reinterpret_cast<const uint4*>(in_n);
        uint4* dst = reinterpret_cast<uint4*>(slab);
        #pragma unroll
        for (int it = 0; it < 11; ++it) {
            int q = tid + it * 256;
            if (q < 2800) {
                int r = q / 100, c = q - r * 100;
                dst[q] = src[((y0 + r) * 76 + x0) * 5 + c];
            }
        }
    }

    int ldsb[6];
    #pragma unroll
    for (int mf = 0; mf < 6; ++mf)
        ldsb[mf] = ((mf * 4 + wv) * 20 + frow) * CL;

    const unsigned short* wbase = wPT + (size_t)frow * 32 + fq * 8;

    f32x4 acc[6][4];
    #pragma unroll
    for (int a = 0; a < 6; ++a)
        #pragma unroll
        for (int b = 0; b < 4; ++b) acc[a][b] = (f32x4){0.f, 0.f, 0.f, 0.f};

    __syncthreads();

    #pragma unroll 2
    for (int kb = 0; kb < KSTEPS; ++kb) {
        int go = s_kt[kb * 4 + fq];
        bf16x8 af[6];
        #pragma unroll
        for (int mf = 0; mf < 6; ++mf)
            af[mf] = *reinterpret_cast<const bf16x8*>(&slab[ldsb[mf] + go]);
        const unsigned short* wk = wbase + (size_t)kb * 64 * 32;
        #pragma unroll
        for (int ng = 0; ng < 4; ++ng) {
            bf16x8 bf = *reinterpret_cast<const bf16x8*>(wk + ng * 16 * 32);
            #pragma unroll
            for (int mf = 0; mf < 6; ++mf)
                acc[mf][ng] = __builtin_amdgcn_mfma_f32_16x16x32_bf16(
                    af[mf], bf, acc[mf][ng], 0, 0, 0);
        }
    }

    unsigned short* out_n = out + (size_t)nl * outSS;
    const int erow = tid >> 2, eseg = tid & 3;
    #pragma unroll
    for (int mf = 0; mf < 6; ++mf) {
        __syncthreads();
        #pragma unroll
        for (int ng = 0; ng < 4; ++ng) {
            float bv = bias[ng * 16 + frow];
            #pragma unroll
            for (int j = 0; j < 4; ++j)
                s_c[(wv * 16 + fq * 4 + j) * LP + ng * 16 + frow] =
                    f2bf(fmaxf(acc[mf][ng][j] + bv, 0.0f));
        }
        __syncthreads();
        {
            int ty = mf * 4 + (erow >> 4);
            int tx = erow & 15;
            int pos = (y0 + ty) * 72 + (x0 + tx);
            ushort8 v0 = *reinterpret_cast<const ushort8*>(
                &s_c[erow * LP + eseg * 16]);
            ushort8 v1 = *reinterpret_cast<const ushort8*>(
                &s_c[erow * LP + eseg * 16 + 8]);
            unsigned short* op = out_n + (size_t)pos * 64 + eseg * 16;
            *reinterpret_cast<ushort8*>(op) = v0;
            *reinterpret_cast<ushort8*>(op + 8) = v1;
        }
    }
}

// ---------------------------------------------------------------------------
// 6b) Generic row-slab implicit-GEMM conv (conv1/conv2), bf16 MFMA 16x16x32.
//     __launch_bounds__(256,2): LDS caps at 2 blocks/CU -> allow ~256 VGPR.
// ---------------------------------------------------------------------------
template<int MFRAG, int NG, int KH, int CPG, int CL, int SLAB, int KSTEPS>
__global__ __launch_bounds__(256, 2) void conv_mfma_k(
    const unsigned short* __restrict__ inP,
    const unsigned short* __restrict__ wPT,
    const int* __restrict__ ktab,
    const float* __restrict__ bias,
    unsigned short* __restrict__ out,
    int W, int Wp, int Mtot, int inSS, int outSS, int COUT)
{
    constexpr int Mblk = MFRAG * 64;
    constexpr int NOC  = NG * 16;
    constexpr int SEGS = NOC / 16;
    constexpr int LP   = NOC + 8;
    constexpr int CP   = CPG * 8;
    constexpr int SMEM = (SLAB * 2 > 64 * LP * 2) ? SLAB * 2 : 64 * LP * 2;
    __shared__ __align__(16) char smem[SMEM];
    __shared__ int s_kt[KSTEPS * 4];
    unsigned short* slab = reinterpret_cast<unsigned short*>(smem);
    unsigned short* s_c  = reinterpret_cast<unsigned short*>(smem);

    const int tid  = threadIdx.x;
    const int mb   = blockIdx.x;
    const int ocb  = blockIdx.y;
    const int nl   = blockIdx.z;
    const int lane = tid & 63;
    const int wv   = tid >> 6;
    const int frow = lane & 15;
    const int fq   = lane >> 4;

    if (tid < KSTEPS * 4) s_kt[tid] = ktab[tid];

    const int p0    = mb * Mblk;
    const int y0    = p0 / W;
    const int plast = (p0 + Mblk < Mtot ? p0 + Mblk : Mtot) - 1;
    const int rows  = plast / W - y0 + KH;

    const unsigned short* in_n =
        inP + (size_t)nl * inSS + (size_t)y0 * Wp * CP;
    const int nchunks = rows * Wp * CPG;
    for (int q = tid; q < nchunks; q += 256) {
        int pix = q / CPG, c8 = q - pix * CPG;
        uint4 v = reinterpret_cast<const uint4*>(in_n)[q];
        *reinterpret_cast<uint4*>(&slab[pix * CL + c8 * 8]) = v;
    }

    int ldsb[MFRAG];
    #pragma unroll
    for (int mf = 0; mf < MFRAG; ++mf) {
        int p  = p0 + mf * 64 + wv * 16 + frow;
        int pc = p < Mtot ? p : (Mtot - 1);
        int y  = pc / W;
        int x  = pc - y * W;
        ldsb[mf] = ((y - y0) * Wp + x) * CL;
    }
    const unsigned short* wbase =
        wPT + ((size_t)(ocb * NOC + frow)) * 32 + fq * 8;

    f32x4 acc[MFRAG][NG];
    #pragma unroll
    for (int mf = 0; mf < MFRAG; ++mf)
        #pragma unroll
        for (int ng = 0; ng < NG; ++ng)
            acc[mf][ng] = (f32x4){0.f, 0.f, 0.f, 0.f};

    __syncthreads();

    for (int kb = 0; kb < KSTEPS; ++kb) {
        int go = s_kt[kb * 4 + fq];
        bf16x8 af[MFRAG];
        #pragma unroll
        for (int mf = 0; mf < MFRAG; ++mf)
            af[mf] = *reinterpret_cast<const bf16x8*>(&slab[ldsb[mf] + go]);
        const unsigned short* wk = wbase + (size_t)kb * COUT * 32;
        #pragma unroll
        for (int ng = 0; ng < NG; ++ng) {
            bf16x8 bf = *reinterpret_cast<const bf16x8*>(wk + ng * 16 * 32);
            #pragma unroll
            for (int mf = 0; mf < MFRAG; ++mf)
                acc[mf][ng] = __builtin_amdgcn_mfma_f32_16x16x32_bf16(
                    af[mf], bf, acc[mf][ng], 0, 0, 0);
        }
    }

    unsigned short* out_n = out + (size_t)nl * outSS;
    #pragma unroll
    for (int mf = 0; mf < MFRAG; ++mf) {
        __syncthreads();
        #pragma unroll
        for (int ng = 0; ng < NG; ++ng) {
            float bv = bias[ocb * NOC + ng * 16 + frow];
            #pragma unroll
            for (int j = 0; j < 4; ++j)
                s_c[(wv * 16 + fq * 4 + j) * LP + ng * 16 + frow] =
                    f2bf(fmaxf(acc[mf][ng][j] + bv, 0.0f));
        }
        __syncthreads();
        for (int t = tid; t < 64 * SEGS; t += 256) {
            int row = t / SEGS, seg = t % SEGS;
            int p = p0 + mf * 64 + row;
            if (p < Mtot) {
                ushort8 v0 = *reinterpret_cast<const ushort8*>(
                    &s_c[row * LP + seg * 16]);
                ushort8 v1 = *reinterpret_cast<const ushort8*>(
                    &s_c[row * LP + seg * 16 + 8]);
                unsigned short* op =
                    out_n + (size_t)p * COUT + ocb * NOC + seg * 16;
                *reinterpret_cast<ushort8*>(op) = v0;
                *reinterpret_cast<ushort8*>(op + 8) = v1;
            }
        }
    }
}

// ---------------------------------------------------------------------------
// 7) MaxPool 3x3 s2 VALID, HWC, ushort8 (post-ReLU: u16 max).
// ---------------------------------------------------------------------------
__global__ __launch_bounds__(256) void pool_k(
    const unsigned short* __restrict__ in, unsigned short* __restrict__ out,
    int CG, int C, int W, int inSS,
    int HO, int WO, int Wpo, int outSS, int total)
{
    int idx = blockIdx.x * 256 + threadIdx.x;
    if (idx >= total) return;
    int cg = idx % CG;
    int t  = idx / CG;
    int x  = t % WO;
    t /= WO;
    int y  = t % HO;
    int nl = t / HO;

    const unsigned short* pin = in + (size_t)nl * inSS + cg * 8;
    ushort8 mx = {0,0,0,0,0,0,0,0};
    #pragma unroll
    for (int dy = 0; dy < 3; ++dy)
        #pragma unroll
        for (int dx = 0; dx < 3; ++dx) {
            ushort8 v = *reinterpret_cast<const ushort8*>(
                pin + ((size_t)(2 * y + dy) * W + (2 * x + dx)) * C);
            #pragma unroll
            for (int j = 0; j < 8; ++j) mx[j] = v[j] > mx[j] ? v[j] : mx[j];
        }
    *reinterpret_cast<ushort8*>(
        out + (size_t)nl * outSS +
        ((size_t)(y + 1) * Wpo + (x + 1)) * C + cg * 8) = mx;
}

// ---------------------------------------------------------------------------
// 8) Fused pool2 (3x3 s2 on [17][17][256]) + global average pool -> fp32
// ---------------------------------------------------------------------------
__global__ __launch_bounds__(512) void pool2gap_k(
    const unsigned short* __restrict__ in, float* __restrict__ out,
    int inSS, int n0)
{
    __shared__ float part[256];
    const int nl = blockIdx.x;
    const int c    = threadIdx.x & 255;
    const int half = threadIdx.x >> 8;
    const unsigned short* p = in + (size_t)nl * inSS + c;
    float s = 0.0f;
    for (int w = half * 32; w < half * 32 + 32; ++w) {
        int y = w >> 3, x = w & 7;
        unsigned short mx = 0;
        #pragma unroll
        for (int dy = 0; dy < 3; ++dy)
            #pragma unroll
            for (int dx = 0; dx < 3; ++dx) {
                unsigned short v = p[((size_t)(2*y+dy) * 17 + (2*x+dx)) * 256];
                mx = v > mx ? v : mx;
            }
        s += bf2f(mx);
    }
    if (half) part[c] = s;
    __syncthreads();
    if (!half) out[(size_t)(n0 + nl) * 256 + c] = (s + part[c]) * (1.0f / 64.0f);
}

// ---------------------------------------------------------------------------
// 9) FC weight transpose: w[o][i] -> wT[i][o]
// ---------------------------------------------------------------------------
__global__ __launch_bounds__(256) void fcT_k(
    const float* __restrict__ w, float* __restrict__ wT, int O, int I, int total)
{
    int idx = blockIdx.x * 256 + threadIdx.x;
    if (idx >= total) return;
    int i = idx % I, o = idx / I;
    wT[(size_t)i * O + o] = w[idx];
}

// ---------------------------------------------------------------------------
// 10) Fused 3-layer FC head (256->512->256->512), one block per sample
// ---------------------------------------------------------------------------
__global__ __launch_bounds__(256) void fc_fused_k(
    const float* __restrict__ in,
    const float* __restrict__ w0T, const float* __restrict__ b0,
    const float* __restrict__ w1T, const float* __restrict__ b1,
    const float* __restrict__ w2T, const float* __restrict__ b2,
    float* __restrict__ out)
{
    __shared__ float s_in[256], s_h0[512], s_h1[256];
    const int n = blockIdx.x, t = threadIdx.x;
    s_in[t] = in[(size_t)n * 256 + t];
    __syncthreads();
    float a0 = 0.f, a1 = 0.f;
    for (int i = 0; i < 256; ++i) {
        float v = s_in[i];
        a0 += v * w0T[i * 512 + t];
        a1 += v * w0T[i * 512 + t + 256];
    }
    s_h0[t]       = fmaxf(a0 + b0[t], 0.0f);
    s_h0[t + 256] = fmaxf(a1 + b0[t + 256], 0.0f);
    __syncthreads();
    float h = 0.f;
    for (int i = 0; i < 512; ++i) h += s_h0[i] * w1T[i * 256 + t];
    s_h1[t] = fmaxf(h + b1[t], 0.0f);
    __syncthreads();
    a0 = 0.f; a1 = 0.f;
    for (int i = 0; i < 256; ++i) {
        float v = s_h1[i];
        a0 += v * w2T[i * 512 + t];
        a1 += v * w2T[i * 512 + t + 256];
    }
    out[(size_t)n * 512 + t]       = a0 + b2[t];
    out[(size_t)n * 512 + t + 256] = a1 + b2[t + 256];
}

// ---------------------------------------------------------------------------
// Launch.
// ---------------------------------------------------------------------------
extern "C" void kernel_launch(void* const* d_in, const int* in_sizes, int n_in,
                              void* d_out, int out_size, void* d_ws, size_t ws_size,
                              hipStream_t stream)
{
    const int*   X   = (const int*)d_in[0];
    const int*   rm  = (const int*)d_in[1];
    const float* emb = (const float*)d_in[2];
    const float* cw0 = (const float*)d_in[3];
    const float* cb0 = (const float*)d_in[4];
    const float* cw1 = (const float*)d_in[5];
    const float* cb1 = (const float*)d_in[6];
    const float* cw2 = (const float*)d_in[7];
    const float* cb2 = (const float*)d_in[8];
    const float* fw0 = (const float*)d_in[9];
    const float* fb0 = (const float*)d_in[10];
    const float* fw1 = (const float*)d_in[11];
    const float* fb1 = (const float*)d_in[12];
    const float* fw2 = (const float*)d_in[13];
    const float* fb2 = (const float*)d_in[14];
    float* out = (float*)d_out;

    char* p = (char*)d_ws;
    auto alloc = [&](size_t bytes) -> char* {
        char* r = p; p += (bytes + 255) & ~(size_t)255; return r;
    };
    unsigned short* WP0 = (unsigned short*)alloc((size_t)32 * 64 * 32 * 2);
    unsigned short* WP1 = (unsigned short*)alloc((size_t)18 * 128 * 32 * 2);
    unsigned short* WP2 = (unsigned short*)alloc((size_t)36 * 256 * 32 * 2);
    int* KT0 = (int*)alloc(128 * 4);
    int* KT1 = (int*)alloc(72 * 4);
    int* KT2 = (int*)alloc(144 * 4);
    unsigned long long* MASKS = (unsigned long long*)alloc(RR * 8);
    float* W0T  = (float*)alloc((size_t)256 * 512 * 4);
    float* W1T  = (float*)alloc((size_t)512 * 256 * 4);
    float* W2T  = (float*)alloc((size_t)256 * 512 * 4);
    float* GAPB = (float*)alloc((size_t)NB * 256 * 4);
    size_t fixed_bytes = (size_t)(p - (char*)d_ws);

    const size_t A_FL = 231040, B_FL = 331776, C_FL = 133824;   // u16
    const size_t per_sample = (A_FL + B_FL + C_FL) * 2 + 768;
    int Bc = 128;
    while (Bc > 1 && fixed_bytes + (size_t)Bc * per_sample > ws_size) Bc >>= 1;

    unsigned short* bufA = (unsigned short*)alloc((size_t)Bc * A_FL * 2);
    unsigned short* bufC = (unsigned short*)alloc((size_t)Bc * C_FL * 2);
    unsigned short* bufB = (unsigned short*)alloc((size_t)Bc * B_FL * 2);

    // ---- one-time prep (runs every call; graph-safe) ----
    build_masks_k<<<2, 256, 0, stream>>>(rm, MASKS);
    wpack_k<<<(32 * 64 * 32 + 255) / 256, 256, 0, stream>>>(
        cw0, WP0, 64, 33, 25, 5, 32 * 64 * 32);
    wpack_k<<<(18 * 128 * 32 + 255) / 256, 256, 0, stream>>>(
        cw1, WP1, 128, 64, 9, 8, 18 * 128 * 32);
    wpack_k<<<(36 * 256 * 32 + 255) / 256, 256, 0, stream>>>(
        cw2, WP2, 256, 128, 9, 16, 36 * 256 * 32);
    ktab_all_k<<<dim3(1, 3), 256, 0, stream>>>(KT0, KT1, KT2);
    fcT_k<<<(512 * 256 + 255) / 256, 256, 0, stream>>>(fw0, W0T, 512, 256, 512 * 256);
    fcT_k<<<(256 * 512 + 255) / 256, 256, 0, stream>>>(fw1, W1T, 256, 512, 256 * 512);
    fcT_k<<<(512 * 256 + 255) / 256, 256, 0, stream>>>(fw2, W2T, 512, 256, 512 * 256);

    // ---- chunked pipeline ----
    for (int n0 = 0; n0 < NB; n0 += Bc) {
        border_k<<<(Bc * 592 * 5 + 255) / 256, 256, 0, stream>>>(
            bufA, 76, 76, 5, 2, (int)A_FL, 592, Bc * 592 * 5);
        border_k<<<(Bc * 144 * 8 + 255) / 256, 256, 0, stream>>>(
            bufC, 37, 37, 8, 1, (int)C_FL, 144, Bc * 144 * 8);
        border_k<<<(Bc * 72 * 16 + 255) / 256, 256, 0, stream>>>(
            bufC + 87616, 19, 19, 16, 1, (int)C_FL, 72, Bc * 72 * 16);

        // encode -> A (HWC G [76][76][40], interior +2)
        encode_k<<<dim3(Bc, 18), 320, 0, stream>>>(X, MASKS, emb, bufA, n0, (int)A_FL);

        // conv0: A -> B  (15 24x16 tiles/sample, COUT=64, 32 ksteps)
        conv0_tile_k<32><<<dim3(15, Bc), 256, 0, stream>>>(
            bufA, WP0, KT0, cb0, bufB, (int)A_FL, (int)B_FL);
        // pool0: B [72][72][64] -> C P0p [37][37][64] interior +1
        pool_k<<<(Bc * 35 * 35 * 8 + 255) / 256, 256, 0, stream>>>(
            bufB, bufC, 8, 64, 72, (int)B_FL,
            35, 35, 37, (int)C_FL, Bc * 35 * 35 * 8);

        // conv1: C -> A  (M=1225, Mblk=256 -> 5 mblocks, COUT=128)
        conv_mfma_k<4, 8, 3, 8, 72, 29304, 18><<<dim3(5, 1, Bc), 256, 0, stream>>>(
            bufC, WP1, KT1, cb1, bufA, 35, 37,
            1225, (int)C_FL, (int)A_FL, 128);
        // pool1: A [35][35][128] -> C+87616 P1p [19][19][128] interior +1
        pool_k<<<(Bc * 17 * 17 * 16 + 255) / 256, 256, 0, stream>>>(
            bufA, bufC + 87616, 16, 128, 35, (int)A_FL,
            17, 17, 19, (int)C_FL, Bc * 17 * 17 * 16);

        // conv2: C+87616 -> B  (M=289, Mblk=128 -> 3 mblocks, 2 oc-blocks)
        conv_mfma_k<2, 8, 3, 16, 136, 28424, 36><<<dim3(3, 2, Bc), 256, 0, stream>>>(
            bufC + 87616, WP2, KT2, cb2, bufB, 17, 19,
            289, (int)C_FL, (int)B_FL, 256);

        // fused pool2 + GAP: B [17][17][256] -> GAPB fp32
        pool2gap_k<<<Bc, 512, 0, stream>>>(bufB, GAPB, (int)B_FL, n0);
    }

    // fused FC head
    fc_fused_k<<<NB, 256, 0, stream>>>(GAPB, W0T, fb0, W1T, fb1, W2T, fb2, out);
}

// Round 13
// 516.580 us; speedup vs baseline: 1.9242x; 1.0396x over previous
//
#include <hip/hip_runtime.h>
#include <hip/hip_bf16.h>
#include <cstdint>
#include <cstddef>

#define NB      128
#define RR      300
#define EMB     32

typedef __bf16 bf16x8 __attribute__((ext_vector_type(8)));
typedef float  f32x4  __attribute__((ext_vector_type(4)));
typedef unsigned short ushort8 __attribute__((ext_vector_type(8)));

__device__ __forceinline__ unsigned short f2bf(float f) {
    union { __hip_bfloat16 h; unsigned short u; } c;
    c.h = __float2bfloat16(f);
    return c.u;
}
__device__ __forceinline__ float bf2f(unsigned short u) {
    union { __hip_bfloat16 h; unsigned short u; } c;
    c.u = u;
    return __bfloat162float(c.h);
}

// ---------------------------------------------------------------------------
// 1) Room occupancy -> uint64 bitmask (bit b = dx*8+dy)
// ---------------------------------------------------------------------------
__global__ __launch_bounds__(256) void build_masks_k(
    const int* __restrict__ rm, unsigned long long* __restrict__ masks)
{
    int r = blockIdx.x * 256 + threadIdx.x;
    if (r >= RR) return;
    unsigned long long m = 0ull;
    #pragma unroll
    for (int b = 0; b < 64; ++b)
        if (rm[r * 64 + b]) m |= (1ull << b);
    masks[r] = m;
}

// ---------------------------------------------------------------------------
// 2) Border zero: zeroes only the halo pixels of a padded HWC buffer.
// ---------------------------------------------------------------------------
__global__ __launch_bounds__(256) void border_k(
    unsigned short* __restrict__ base, int Hp, int Wp, int CPG, int pad,
    int sampleStride, int nborder, int total)
{
    int idx = blockIdx.x * 256 + threadIdx.x;
    if (idx >= total) return;
    int c8 = idx % CPG;
    int t  = idx / CPG;
    int bi = t % nborder;
    int nl = t / nborder;

    int topN = pad * Wp;
    int y, x;
    if (bi < topN) {
        y = bi / Wp; x = bi - y * Wp;
    } else if (bi < 2 * topN) {
        int b2 = bi - topN;
        y = Hp - pad + b2 / Wp; x = b2 % Wp;
    } else {
        int mid = bi - 2 * topN;
        int rowlen = 2 * pad;
        y = pad + mid / rowlen;
        int r = mid % rowlen;
        x = r < pad ? r : Wp - pad + (r - pad);
    }
    uint4 z = make_uint4(0, 0, 0, 0);
    *reinterpret_cast<uint4*>(
        &base[((size_t)nl * sampleStride) +
              ((size_t)y * Wp + x) * (CPG * 8) + c8 * 8]) = z;
}

// ---------------------------------------------------------------------------
// 3) Encode, banded HWC. v5: 512 threads (8 waves) + unroll-2 room walk:
//    shorter serial chains AND more waves to hide them.
// ---------------------------------------------------------------------------
__global__ __launch_bounds__(512) void encode_k(
    const int* __restrict__ X, const unsigned long long* __restrict__ masks,
    const float* __restrict__ emb, unsigned short* __restrict__ G,
    int n0, int sampleStride)
{
    __shared__ float tile[4][72][33];
    __shared__ unsigned s_pos[RR];
    __shared__ unsigned long long s_mask[RR];
    __shared__ unsigned short s_list[320];
    __shared__ float s_emb[64 * 33];
    __shared__ int s_woff[8];
    __shared__ int s_cnt;

    const int nl = blockIdx.x, band = blockIdx.y;
    const int by = band * 4;
    const int n  = n0 + nl;
    const int tid = threadIdx.x;

    float* tf = &tile[0][0][0];
    for (int i = tid; i < 4 * 72 * 33; i += 512) tf[i] = 0.0f;

    // phase 1: preload rooms, ballot hot predicate, compact to dense list
    const int2* Xp = reinterpret_cast<const int2*>(X);
    bool hot = false;
    if (tid < RR) {
        int2 pos = Xp[n * RR + tid];
        s_pos[tid]  = (unsigned)pos.x | ((unsigned)pos.y << 16);
        s_mask[tid] = masks[tid];
        hot = (pos.y <= by + 3) && (pos.y + 7 >= by);
    }
    unsigned long long bal = __ballot(hot);
    if ((tid & 63) == 0) s_woff[tid >> 6] = (int)__popcll(bal);
    __syncthreads();
    if (tid == 0) {
        int acc = 0;
        #pragma unroll
        for (int w = 0; w < 8; ++w) { int c = s_woff[w]; s_woff[w] = acc; acc += c; }
        s_cnt = acc;
    }
    __syncthreads();
    if (hot) {
        int w = tid >> 6, b = tid & 63;
        unsigned long long before = (b == 0) ? 0ull : (bal & ((1ull << b) - 1ull));
        s_list[s_woff[w] + (int)__popcll(before)] = (unsigned short)tid;
    }
    __syncthreads();

    // phase 2: chunked, 8-wave-parallel walk, unrolled by 2
    const int lane = tid & 63;
    const int wvi  = tid >> 6;          // 0..7
    const int dx   = lane >> 3;         // 0..7
    const int c0   = (lane & 7) * 5;    // channels [c0, c0+5) ∩ [0,33)
    const int cnt  = s_cnt;

    for (int base = 0; base < cnt; base += 64) {
        int cn = cnt - base; if (cn > 64) cn = 64;
        for (int i = tid; i < cn * 33; i += 512) {
            int hi = i / 33, cc = i - hi * 33;
            int r = s_list[base + hi];
            s_emb[i] = (cc == 0) ? 1.0f : emb[r * EMB + cc - 1];
        }
        __syncthreads();

        int j = wvi;
        for (; j + 8 < cn; j += 16) {
            // two independent rooms: load params up-front, then atomics
            int rA = s_list[base + j];
            int rB = s_list[base + j + 8];
            unsigned pA = s_pos[rA], pB = s_pos[rB];
            unsigned long long mA = s_mask[rA] >> (dx * 8);
            unsigned long long mB = s_mask[rB] >> (dx * 8);
            int xA = (pA & 0xffff) + dx, yA = pA >> 16;
            int xB = (pB & 0xffff) + dx, yB = pB >> 16;
            float eA[5], eB[5];
            #pragma unroll
            for (int q = 0; q < 5; ++q) {
                eA[q] = (c0 + q < 33) ? s_emb[j * 33 + c0 + q] : 0.0f;
                eB[q] = (c0 + q < 33) ? s_emb[(j + 8) * 33 + c0 + q] : 0.0f;
            }
            #pragma unroll
            for (int dyb = 0; dyb < 4; ++dyb) {
                int dA = by + dyb - yA;
                if ((unsigned)dA < 8u && ((mA >> dA) & 1ull)) {
                    #pragma unroll
                    for (int q = 0; q < 5; ++q)
                        if (c0 + q < 33)
                            atomicAdd(&tile[dyb][xA][c0 + q], eA[q]);
                }
                int dB = by + dyb - yB;
                if ((unsigned)dB < 8u && ((mB >> dB) & 1ull)) {
                    #pragma unroll
                    for (int q = 0; q < 5; ++q)
                        if (c0 + q < 33)
                            atomicAdd(&tile[dyb][xB][c0 + q], eB[q]);
                }
            }
        }
        for (; j < cn; j += 8) {
            int r = s_list[base + j];
            unsigned pxy = s_pos[r];
            int px = pxy & 0xffff, py = pxy >> 16;
            unsigned long long mm = s_mask[r] >> (dx * 8);
            int x = px + dx;
            float ev[5];
            #pragma unroll
            for (int q = 0; q < 5; ++q)
                ev[q] = (c0 + q < 33) ? s_emb[j * 33 + c0 + q] : 0.0f;
            #pragma unroll
            for (int dyb = 0; dyb < 4; ++dyb) {
                int dyr = by + dyb - py;
                if ((unsigned)dyr < 8u && ((mm >> dyr) & 1ull)) {
                    #pragma unroll
                    for (int q = 0; q < 5; ++q)
                        if (c0 + q < 33)
                            atomicAdd(&tile[dyb][x][c0 + q], ev[q]);
                }
            }
        }
        __syncthreads();
    }
    __syncthreads();

    // write-out: 4 rows x 72 px x 40ch as uint2 (4ch) chunks
    unsigned short* Gn = G + (size_t)nl * sampleStride;
    for (int i = tid; i < 4 * 72 * 10; i += 512) {
        int cc = i % 10;
        int t  = i / 10;
        int x  = t % 72;
        int dyb = t / 72;
        int c0w = cc * 4;
        unsigned short r[4];
        #pragma unroll
        for (int j = 0; j < 4; ++j)
            r[j] = (c0w + j < 33) ? f2bf(tile[dyb][x][c0w + j]) : 0;
        uint2 pk;
        pk.x = (unsigned)r[0] | ((unsigned)r[1] << 16);
        pk.y = (unsigned)r[2] | ((unsigned)r[3] << 16);
        *reinterpret_cast<uint2*>(
            &Gn[((size_t)(by + dyb + 2) * 76 + (x + 2)) * 40 + c0w]) = pk;
    }
}

// ---------------------------------------------------------------------------
// 4) Weight pack: w[oc][ci][K][K] fp32 -> bf16 wPT[kb][oc][32]
// ---------------------------------------------------------------------------
__global__ __launch_bounds__(256) void wpack_k(
    const float* __restrict__ w, unsigned short* __restrict__ wPT,
    int COUT, int CIN, int KK, int gpc, int total)
{
    int idx = blockIdx.x * 256 + threadIdx.x;
    if (idx >= total) return;
    int kk = idx & 31;
    int t  = idx >> 5;
    int oc = t % COUT;
    int kb = t / COUT;
    int g  = kb * 4 + (kk >> 3);
    int j  = kk & 7;
    int shift = g / gpc;
    int ci    = (g % gpc) * 8 + j;
    float v = (shift < KK && ci < CIN)
        ? w[(size_t)oc * CIN * KK + (size_t)ci * KK + shift] : 0.0f;
    wPT[idx] = f2bf(v);
}

// ---------------------------------------------------------------------------
// 5) ktab: LDS-space group offsets (elem units)
// ---------------------------------------------------------------------------
__global__ __launch_bounds__(256) void ktab_all_k(
    int* __restrict__ kt0, int* __restrict__ kt1, int* __restrict__ kt2)
{
    int t = threadIdx.x;
    int which = blockIdx.y;
    int ngr, gpc, K, Wp, CL;
    int* dst;
    if (which == 0)      { ngr = 128; gpc = 5;  K = 5; Wp = 20; CL = 40;  dst = kt0; }
    else if (which == 1) { ngr = 72;  gpc = 8;  K = 3; Wp = 37; CL = 72;  dst = kt1; }
    else                 { ngr = 144; gpc = 16; K = 3; Wp = 19; CL = 136; dst = kt2; }
    if (t >= ngr) return;
    int shift = t / gpc;
    int off = 0;
    if (shift < K * K) {
        int ky = shift / K, kx = shift % K;
        off = (ky * Wp + kx) * CL + (t % gpc) * 8;
    }
    dst[t] = off;
}

// ---------------------------------------------------------------------------
// 6a) conv0: 24x16-spatial-tile implicit-GEMM, bf16 MFMA 16x16x32.
//     __launch_bounds__(256,3): LDS caps occupancy at 3 blocks/CU anyway.
// ---------------------------------------------------------------------------
template<int KSTEPS>
__global__ __launch_bounds__(256, 3) void conv0_tile_k(
    const unsigned short* __restrict__ inP,   // [B][76][76][40] bf16
    const unsigned short* __restrict__ wPT,   // [KSTEPS][64][32] bf16
    const int* __restrict__ ktab,             // [KSTEPS*4] LDS offsets
    const float* __restrict__ bias,
    unsigned short* __restrict__ out,         // [B][5184][64] bf16
    int inSS, int outSS)
{
    constexpr int CL = 40;
    constexpr int LP = 72;
    __shared__ __align__(16) unsigned short slab[28 * 20 * CL];  // 44800 B
    __shared__ int s_kt[KSTEPS * 4];
    unsigned short* s_c = slab;

    const int tid = threadIdx.x;
    const int tl  = blockIdx.x;           // 0..14
    const int nl  = blockIdx.y;
    const int tyi = tl / 5, txi = tl % 5;
    const int y0 = tyi * 24;
    const int x0 = txi < 4 ? txi * 16 : 56;

    const int lane = tid & 63, wv = tid >> 6, frow = lane & 15, fq = lane >> 4;

    if (tid < KSTEPS * 4) s_kt[tid] = ktab[tid];

    const unsigned short* in_n = inP + (size_t)nl * inSS;
    {
        const uint4* src = reinterpret_cast<const uint4*>(in_n);
        uint4* dst = reinterpret_cast<uint4*>(slab);
        #pragma unroll
        for (int it = 0; it < 11; ++it) {
            int q = tid + it * 256;
            if (q < 2800) {
                int r = q / 100, c = q - r * 100;
                dst[q] = src[((y0 + r) * 76 + x0) * 5 + c];
            }
        }
    }

    int ldsb[6];
    #pragma unroll
    for (int mf = 0; mf < 6; ++mf)
        ldsb[mf] = ((mf * 4 + wv) * 20 + frow) * CL;

    const unsigned short* wbase = wPT + (size_t)frow * 32 + fq * 8;

    f32x4 acc[6][4];
    #pragma unroll
    for (int a = 0; a < 6; ++a)
        #pragma unroll
        for (int b = 0; b < 4; ++b) acc[a][b] = (f32x4){0.f, 0.f, 0.f, 0.f};

    __syncthreads();

    #pragma unroll 2
    for (int kb = 0; kb < KSTEPS; ++kb) {
        int go = s_kt[kb * 4 + fq];
        bf16x8 af[6];
        #pragma unroll
        for (int mf = 0; mf < 6; ++mf)
            af[mf] = *reinterpret_cast<const bf16x8*>(&slab[ldsb[mf] + go]);
        const unsigned short* wk = wbase + (size_t)kb * 64 * 32;
        #pragma unroll
        for (int ng = 0; ng < 4; ++ng) {
            bf16x8 bf = *reinterpret_cast<const bf16x8*>(wk + ng * 16 * 32);
            #pragma unroll
            for (int mf = 0; mf < 6; ++mf)
                acc[mf][ng] = __builtin_amdgcn_mfma_f32_16x16x32_bf16(
                    af[mf], bf, acc[mf][ng], 0, 0, 0);
        }
    }

    unsigned short* out_n = out + (size_t)nl * outSS;
    const int erow = tid >> 2, eseg = tid & 3;
    #pragma unroll
    for (int mf = 0; mf < 6; ++mf) {
        __syncthreads();
        #pragma unroll
        for (int ng = 0; ng < 4; ++ng) {
            float bv = bias[ng * 16 + frow];
            #pragma unroll
            for (int j = 0; j < 4; ++j)
                s_c[(wv * 16 + fq * 4 + j) * LP + ng * 16 + frow] =
                    f2bf(fmaxf(acc[mf][ng][j] + bv, 0.0f));
        }
        __syncthreads();
        {
            int ty = mf * 4 + (erow >> 4);
            int tx = erow & 15;
            int pos = (y0 + ty) * 72 + (x0 + tx);
            ushort8 v0 = *reinterpret_cast<const ushort8*>(
                &s_c[erow * LP + eseg * 16]);
            ushort8 v1 = *reinterpret_cast<const ushort8*>(
                &s_c[erow * LP + eseg * 16 + 8]);
            unsigned short* op = out_n + (size_t)pos * 64 + eseg * 16;
            *reinterpret_cast<ushort8*>(op) = v0;
            *reinterpret_cast<ushort8*>(op + 8) = v1;
        }
    }
}

// ---------------------------------------------------------------------------
// 6b) Generic row-slab implicit-GEMM conv (conv1/conv2), bf16 MFMA 16x16x32.
// ---------------------------------------------------------------------------
template<int MFRAG, int NG, int KH, int CPG, int CL, int SLAB, int KSTEPS>
__global__ __launch_bounds__(256, 2) void conv_mfma_k(
    const unsigned short* __restrict__ inP,
    const unsigned short* __restrict__ wPT,
    const int* __restrict__ ktab,
    const float* __restrict__ bias,
    unsigned short* __restrict__ out,
    int W, int Wp, int Mtot, int inSS, int outSS, int COUT)
{
    constexpr int Mblk = MFRAG * 64;
    constexpr int NOC  = NG * 16;
    constexpr int SEGS = NOC / 16;
    constexpr int LP   = NOC + 8;
    constexpr int CP   = CPG * 8;
    constexpr int SMEM = (SLAB * 2 > 64 * LP * 2) ? SLAB * 2 : 64 * LP * 2;
    __shared__ __align__(16) char smem[SMEM];
    __shared__ int s_kt[KSTEPS * 4];
    unsigned short* slab = reinterpret_cast<unsigned short*>(smem);
    unsigned short* s_c  = reinterpret_cast<unsigned short*>(smem);

    const int tid  = threadIdx.x;
    const int mb   = blockIdx.x;
    const int ocb  = blockIdx.y;
    const int nl   = blockIdx.z;
    const int lane = tid & 63;
    const int wv   = tid >> 6;
    const int frow = lane & 15;
    const int fq   = lane >> 4;

    if (tid < KSTEPS * 4) s_kt[tid] = ktab[tid];

    const int p0    = mb * Mblk;
    const int y0    = p0 / W;
    const int plast = (p0 + Mblk < Mtot ? p0 + Mblk : Mtot) - 1;
    const int rows  = plast / W - y0 + KH;

    const unsigned short* in_n =
        inP + (size_t)nl * inSS + (size_t)y0 * Wp * CP;
    const int nchunks = rows * Wp * CPG;
    for (int q = tid; q < nchunks; q += 256) {
        int pix = q / CPG, c8 = q - pix * CPG;
        uint4 v = reinterpret_cast<const uint4*>(in_n)[q];
        *reinterpret_cast<uint4*>(&slab[pix * CL + c8 * 8]) = v;
    }

    int ldsb[MFRAG];
    #pragma unroll
    for (int mf = 0; mf < MFRAG; ++mf) {
        int p  = p0 + mf * 64 + wv * 16 + frow;
        int pc = p < Mtot ? p : (Mtot - 1);
        int y  = pc / W;
        int x  = pc - y * W;
        ldsb[mf] = ((y - y0) * Wp + x) * CL;
    }
    const unsigned short* wbase =
        wPT + ((size_t)(ocb * NOC + frow)) * 32 + fq * 8;

    f32x4 acc[MFRAG][NG];
    #pragma unroll
    for (int mf = 0; mf < MFRAG; ++mf)
        #pragma unroll
        for (int ng = 0; ng < NG; ++ng)
            acc[mf][ng] = (f32x4){0.f, 0.f, 0.f, 0.f};

    __syncthreads();

    for (int kb = 0; kb < KSTEPS; ++kb) {
        int go = s_kt[kb * 4 + fq];
        bf16x8 af[MFRAG];
        #pragma unroll
        for (int mf = 0; mf < MFRAG; ++mf)
            af[mf] = *reinterpret_cast<const bf16x8*>(&slab[ldsb[mf] + go]);
        const unsigned short* wk = wbase + (size_t)kb * COUT * 32;
        #pragma unroll
        for (int ng = 0; ng < NG; ++ng) {
            bf16x8 bf = *reinterpret_cast<const bf16x8*>(wk + ng * 16 * 32);
            #pragma unroll
            for (int mf = 0; mf < MFRAG; ++mf)
                acc[mf][ng] = __builtin_amdgcn_mfma_f32_16x16x32_bf16(
                    af[mf], bf, acc[mf][ng], 0, 0, 0);
        }
    }

    unsigned short* out_n = out + (size_t)nl * outSS;
    #pragma unroll
    for (int mf = 0; mf < MFRAG; ++mf) {
        __syncthreads();
        #pragma unroll
        for (int ng = 0; ng < NG; ++ng) {
            float bv = bias[ocb * NOC + ng * 16 + frow];
            #pragma unroll
            for (int j = 0; j < 4; ++j)
                s_c[(wv * 16 + fq * 4 + j) * LP + ng * 16 + frow] =
                    f2bf(fmaxf(acc[mf][ng][j] + bv, 0.0f));
        }
        __syncthreads();
        for (int t = tid; t < 64 * SEGS; t += 256) {
            int row = t / SEGS, seg = t % SEGS;
            int p = p0 + mf * 64 + row;
            if (p < Mtot) {
                ushort8 v0 = *reinterpret_cast<const ushort8*>(
                    &s_c[row * LP + seg * 16]);
                ushort8 v1 = *reinterpret_cast<const ushort8*>(
                    &s_c[row * LP + seg * 16 + 8]);
                unsigned short* op =
                    out_n + (size_t)p * COUT + ocb * NOC + seg * 16;
                *reinterpret_cast<ushort8*>(op) = v0;
                *reinterpret_cast<ushort8*>(op + 8) = v1;
            }
        }
    }
}

// ---------------------------------------------------------------------------
// 7) MaxPool 3x3 s2 VALID, HWC, ushort8 (post-ReLU: u16 max).
// ---------------------------------------------------------------------------
__global__ __launch_bounds__(256) void pool_k(
    const unsigned short* __restrict__ in, unsigned short* __restrict__ out,
    int CG, int C, int W, int inSS,
    int HO, int WO, int Wpo, int outSS, int total)
{
    int idx = blockIdx.x * 256 + threadIdx.x;
    if (idx >= total) return;
    int cg = idx % CG;
    int t  = idx / CG;
    int x  = t % WO;
    t /= WO;
    int y  = t % HO;
    int nl = t / HO;

    const unsigned short* pin = in + (size_t)nl * inSS + cg * 8;
    ushort8 mx = {0,0,0,0,0,0,0,0};
    #pragma unroll
    for (int dy = 0; dy < 3; ++dy)
        #pragma unroll
        for (int dx = 0; dx < 3; ++dx) {
            ushort8 v = *reinterpret_cast<const ushort8*>(
                pin + ((size_t)(2 * y + dy) * W + (2 * x + dx)) * C);
            #pragma unroll
            for (int j = 0; j < 8; ++j) mx[j] = v[j] > mx[j] ? v[j] : mx[j];
        }
    *reinterpret_cast<ushort8*>(
        out + (size_t)nl * outSS +
        ((size_t)(y + 1) * Wpo + (x + 1)) * C + cg * 8) = mx;
}

// ---------------------------------------------------------------------------
// 8) Fused pool2 (3x3 s2 on [17][17][256]) + global average pool -> fp32
// ---------------------------------------------------------------------------
__global__ __launch_bounds__(512) void pool2gap_k(
    const unsigned short* __restrict__ in, float* __restrict__ out,
    int inSS, int n0)
{
    __shared__ float part[256];
    const int nl = blockIdx.x;
    const int c    = threadIdx.x & 255;
    const int half = threadIdx.x >> 8;
    const unsigned short* p = in + (size_t)nl * inSS + c;
    float s = 0.0f;
    for (int w = half * 32; w < half * 32 + 32; ++w) {
        int y = w >> 3, x = w & 7;
        unsigned short mx = 0;
        #pragma unroll
        for (int dy = 0; dy < 3; ++dy)
            #pragma unroll
            for (int dx = 0; dx < 3; ++dx) {
                unsigned short v = p[((size_t)(2*y+dy) * 17 + (2*x+dx)) * 256];
                mx = v > mx ? v : mx;
            }
        s += bf2f(mx);
    }
    if (half) part[c] = s;
    __syncthreads();
    if (!half) out[(size_t)(n0 + nl) * 256 + c] = (s + part[c]) * (1.0f / 64.0f);
}

// ---------------------------------------------------------------------------
// 9) FC weight transpose: w[o][i] -> wT[i][o]
// ---------------------------------------------------------------------------
__global__ __launch_bounds__(256) void fcT_k(
    const float* __restrict__ w, float* __restrict__ wT, int O, int I, int total)
{
    int idx = blockIdx.x * 256 + threadIdx.x;
    if (idx >= total) return;
    int i = idx % I, o = idx / I;
    wT[(size_t)i * O + o] = w[idx];
}

// ---------------------------------------------------------------------------
// 10) Fused 3-layer FC head (256->512->256->512), one block per sample
// ---------------------------------------------------------------------------
__global__ __launch_bounds__(256) void fc_fused_k(
    const float* __restrict__ in,
    const float* __restrict__ w0T, const float* __restrict__ b0,
    const float* __restrict__ w1T, const float* __restrict__ b1,
    const float* __restrict__ w2T, const float* __restrict__ b2,
    float* __restrict__ out)
{
    __shared__ float s_in[256], s_h0[512], s_h1[256];
    const int n = blockIdx.x, t = threadIdx.x;
    s_in[t] = in[(size_t)n * 256 + t];
    __syncthreads();
    float a0 = 0.f, a1 = 0.f;
    for (int i = 0; i < 256; ++i) {
        float v = s_in[i];
        a0 += v * w0T[i * 512 + t];
        a1 += v * w0T[i * 512 + t + 256];
    }
    s_h0[t]       = fmaxf(a0 + b0[t], 0.0f);
    s_h0[t + 256] = fmaxf(a1 + b0[t + 256], 0.0f);
    __syncthreads();
    float h = 0.f;
    for (int i = 0; i < 512; ++i) h += s_h0[i] * w1T[i * 256 + t];
    s_h1[t] = fmaxf(h + b1[t], 0.0f);
    __syncthreads();
    a0 = 0.f; a1 = 0.f;
    for (int i = 0; i < 256; ++i) {
        float v = s_h1[i];
        a0 += v * w2T[i * 512 + t];
        a1 += v * w2T[i * 512 + t + 256];
    }
    out[(size_t)n * 512 + t]       = a0 + b2[t];
    out[(size_t)n * 512 + t + 256] = a1 + b2[t + 256];
}

// ---------------------------------------------------------------------------
// Launch.
// ---------------------------------------------------------------------------
extern "C" void kernel_launch(void* const* d_in, const int* in_sizes, int n_in,
                              void* d_out, int out_size, void* d_ws, size_t ws_size,
                              hipStream_t stream)
{
    const int*   X   = (const int*)d_in[0];
    const int*   rm  = (const int*)d_in[1];
    const float* emb = (const float*)d_in[2];
    const float* cw0 = (const float*)d_in[3];
    const float* cb0 = (const float*)d_in[4];
    const float* cw1 = (const float*)d_in[5];
    const float* cb1 = (const float*)d_in[6];
    const float* cw2 = (const float*)d_in[7];
    const float* cb2 = (const float*)d_in[8];
    const float* fw0 = (const float*)d_in[9];
    const float* fb0 = (const float*)d_in[10];
    const float* fw1 = (const float*)d_in[11];
    const float* fb1 = (const float*)d_in[12];
    const float* fw2 = (const float*)d_in[13];
    const float* fb2 = (const float*)d_in[14];
    float* out = (float*)d_out;

    char* p = (char*)d_ws;
    auto alloc = [&](size_t bytes) -> char* {
        char* r = p; p += (bytes + 255) & ~(size_t)255; return r;
    };
    unsigned short* WP0 = (unsigned short*)alloc((size_t)32 * 64 * 32 * 2);
    unsigned short* WP1 = (unsigned short*)alloc((size_t)18 * 128 * 32 * 2);
    unsigned short* WP2 = (unsigned short*)alloc((size_t)36 * 256 * 32 * 2);
    int* KT0 = (int*)alloc(128 * 4);
    int* KT1 = (int*)alloc(72 * 4);
    int* KT2 = (int*)alloc(144 * 4);
    unsigned long long* MASKS = (unsigned long long*)alloc(RR * 8);
    float* W0T  = (float*)alloc((size_t)256 * 512 * 4);
    float* W1T  = (float*)alloc((size_t)512 * 256 * 4);
    float* W2T  = (float*)alloc((size_t)256 * 512 * 4);
    float* GAPB = (float*)alloc((size_t)NB * 256 * 4);
    size_t fixed_bytes = (size_t)(p - (char*)d_ws);

    const size_t A_FL = 231040, B_FL = 331776, C_FL = 133824;   // u16
    const size_t per_sample = (A_FL + B_FL + C_FL) * 2 + 768;
    int Bc = 128;
    while (Bc > 1 && fixed_bytes + (size_t)Bc * per_sample > ws_size) Bc >>= 1;

    unsigned short* bufA = (unsigned short*)alloc((size_t)Bc * A_FL * 2);
    unsigned short* bufC = (unsigned short*)alloc((size_t)Bc * C_FL * 2);
    unsigned short* bufB = (unsigned short*)alloc((size_t)Bc * B_FL * 2);

    // ---- one-time prep (runs every call; graph-safe) ----
    build_masks_k<<<2, 256, 0, stream>>>(rm, MASKS);
    wpack_k<<<(32 * 64 * 32 + 255) / 256, 256, 0, stream>>>(
        cw0, WP0, 64, 33, 25, 5, 32 * 64 * 32);
    wpack_k<<<(18 * 128 * 32 + 255) / 256, 256, 0, stream>>>(
        cw1, WP1, 128, 64, 9, 8, 18 * 128 * 32);
    wpack_k<<<(36 * 256 * 32 + 255) / 256, 256, 0, stream>>>(
        cw2, WP2, 256, 128, 9, 16, 36 * 256 * 32);
    ktab_all_k<<<dim3(1, 3), 256, 0, stream>>>(KT0, KT1, KT2);
    fcT_k<<<(512 * 256 + 255) / 256, 256, 0, stream>>>(fw0, W0T, 512, 256, 512 * 256);
    fcT_k<<<(256 * 512 + 255) / 256, 256, 0, stream>>>(fw1, W1T, 256, 512, 256 * 512);
    fcT_k<<<(512 * 256 + 255) / 256, 256, 0, stream>>>(fw2, W2T, 512, 256, 512 * 256);

    // ---- chunked pipeline ----
    for (int n0 = 0; n0 < NB; n0 += Bc) {
        border_k<<<(Bc * 592 * 5 + 255) / 256, 256, 0, stream>>>(
            bufA, 76, 76, 5, 2, (int)A_FL, 592, Bc * 592 * 5);
        border_k<<<(Bc * 144 * 8 + 255) / 256, 256, 0, stream>>>(
            bufC, 37, 37, 8, 1, (int)C_FL, 144, Bc * 144 * 8);
        border_k<<<(Bc * 72 * 16 + 255) / 256, 256, 0, stream>>>(
            bufC + 87616, 19, 19, 16, 1, (int)C_FL, 72, Bc * 72 * 16);

        // encode -> A (HWC G [76][76][40], interior +2)
        encode_k<<<dim3(Bc, 18), 512, 0, stream>>>(X, MASKS, emb, bufA, n0, (int)A_FL);

        // conv0: A -> B  (15 24x16 tiles/sample, COUT=64, 32 ksteps)
        conv0_tile_k<32><<<dim3(15, Bc), 256, 0, stream>>>(
            bufA, WP0, KT0, cb0, bufB, (int)A_FL, (int)B_FL);
        // pool0: B [72][72][64] -> C P0p [37][37][64] interior +1
        pool_k<<<(Bc * 35 * 35 * 8 + 255) / 256, 256, 0, stream>>>(
            bufB, bufC, 8, 64, 72, (int)B_FL,
            35, 35, 37, (int)C_FL, Bc * 35 * 35 * 8);

        // conv1: C -> A  (M=1225, Mblk=256 -> 5 mblocks, COUT=128)
        conv_mfma_k<4, 8, 3, 8, 72, 29304, 18><<<dim3(5, 1, Bc), 256, 0, stream>>>(
            bufC, WP1, KT1, cb1, bufA, 35, 37,
            1225, (int)C_FL, (int)A_FL, 128);
        // pool1: A [35][35][128] -> C+87616 P1p [19][19][128] interior +1
        pool_k<<<(Bc * 17 * 17 * 16 + 255) / 256, 256, 0, stream>>>(
            bufA, bufC + 87616, 16, 128, 35, (int)A_FL,
            17, 17, 19, (int)C_FL, Bc * 17 * 17 * 16);

        // conv2: C+87616 -> B  (M=289, Mblk=128 -> 3 mblocks, 2 oc-blocks)
        conv_mfma_k<2, 8, 3, 16, 136, 28424, 36><<<dim3(3, 2, Bc), 256, 0, stream>>>(
            bufC + 87616, WP2, KT2, cb2, bufB, 17, 19,
            289, (int)C_FL, (int)B_FL, 256);

        // fused pool2 + GAP: B [17][17][256] -> GAPB fp32
        pool2gap_k<<<Bc, 512, 0, stream>>>(bufB, GAPB, (int)B_FL, n0);
    }

    // fused FC head
    fc_fused_k<<<NB, 256, 0, stream>>>(GAPB, W0T, fb0, W1T, fb1, W2T, fb2, out);
}

// Round 14
// 500.439 us; speedup vs baseline: 1.9863x; 1.0323x over previous
//
#include <hip/hip_runtime.h>
#include <hip/hip_bf16.h>
#include <cstdint>
#include <cstddef>

#define NB      128
#define RR      300
#define EMB     32

typedef __bf16 bf16x8 __attribute__((ext_vector_type(8)));
typedef float  f32x4  __attribute__((ext_vector_type(4)));
typedef unsigned short ushort8 __attribute__((ext_vector_type(8)));

__device__ __forceinline__ unsigned short f2bf(float f) {
    union { __hip_bfloat16 h; unsigned short u; } c;
    c.h = __float2bfloat16(f);
    return c.u;
}
__device__ __forceinline__ float bf2f(unsigned short u) {
    union { __hip_bfloat16 h; unsigned short u; } c;
    c.u = u;
    return __bfloat162float(c.h);
}

// ---------------------------------------------------------------------------
// helpers for the consolidated prep kernel
// ---------------------------------------------------------------------------
__device__ __forceinline__ void wpack_body(
    const float* __restrict__ w, unsigned short* __restrict__ wPT,
    int COUT, int CIN, int KK, int gpc, int idx, int total)
{
    if (idx >= total) return;
    int kk = idx & 31;
    int t  = idx >> 5;
    int oc = t % COUT;
    int kb = t / COUT;
    int g  = kb * 4 + (kk >> 3);
    int j  = kk & 7;
    int shift = g / gpc;
    int ci    = (g % gpc) * 8 + j;
    float v = (shift < KK && ci < CIN)
        ? w[(size_t)oc * CIN * KK + (size_t)ci * KK + shift] : 0.0f;
    wPT[idx] = f2bf(v);
}

__device__ __forceinline__ void fcT_body(
    const float* __restrict__ w, float* __restrict__ wT, int O, int I, int idx)
{
    if (idx >= O * I) return;
    int i = idx % I, o = idx / I;
    wT[(size_t)i * O + o] = w[idx];
}

// ---------------------------------------------------------------------------
// 1) Consolidated prep: masks + wpack x3 + ktab x3 + fcT x3 in ONE launch.
//    Block ranges: [0,2) masks | [2,258) wpack0 | [258,546) wpack1 |
//    [546,1698) wpack2 | [1698,1699) ktab | [1699,2211) fcT0 |
//    [2211,2723) fcT1 | [2723,3235) fcT2
// ---------------------------------------------------------------------------
__global__ __launch_bounds__(256) void prep_k(
    const int* __restrict__ rm, unsigned long long* __restrict__ masks,
    const float* __restrict__ cw0, unsigned short* __restrict__ WP0,
    const float* __restrict__ cw1, unsigned short* __restrict__ WP1,
    const float* __restrict__ cw2, unsigned short* __restrict__ WP2,
    int* __restrict__ kt0, int* __restrict__ kt1, int* __restrict__ kt2,
    const float* __restrict__ fw0, float* __restrict__ W0T,
    const float* __restrict__ fw1, float* __restrict__ W1T,
    const float* __restrict__ fw2, float* __restrict__ W2T)
{
    const int b = blockIdx.x;
    const int t = threadIdx.x;
    if (b < 2) {
        int r = b * 256 + t;
        if (r < RR) {
            unsigned long long m = 0ull;
            #pragma unroll
            for (int k = 0; k < 64; ++k)
                if (rm[r * 64 + k]) m |= (1ull << k);
            masks[r] = m;
        }
    } else if (b < 258) {
        wpack_body(cw0, WP0, 64, 33, 25, 5, (b - 2) * 256 + t, 32 * 64 * 32);
    } else if (b < 546) {
        wpack_body(cw1, WP1, 128, 64, 9, 8, (b - 258) * 256 + t, 18 * 128 * 32);
    } else if (b < 1698) {
        wpack_body(cw2, WP2, 256, 128, 9, 16, (b - 546) * 256 + t, 36 * 256 * 32);
    } else if (b < 1699) {
        #pragma unroll
        for (int which = 0; which < 3; ++which) {
            int ngr, gpc, K, Wp, CL;
            int* dst;
            if (which == 0)      { ngr = 128; gpc = 5;  K = 5; Wp = 20; CL = 40;  dst = kt0; }
            else if (which == 1) { ngr = 72;  gpc = 8;  K = 3; Wp = 37; CL = 72;  dst = kt1; }
            else                 { ngr = 144; gpc = 16; K = 3; Wp = 19; CL = 136; dst = kt2; }
            if (t < ngr) {
                int shift = t / gpc;
                int off = 0;
                if (shift < K * K) {
                    int ky = shift / K, kx = shift % K;
                    off = (ky * Wp + kx) * CL + (t % gpc) * 8;
                }
                dst[t] = off;
            }
        }
    } else if (b < 2211) {
        fcT_body(fw0, W0T, 512, 256, (b - 1699) * 256 + t);
    } else if (b < 2723) {
        fcT_body(fw1, W1T, 256, 512, (b - 2211) * 256 + t);
    } else {
        fcT_body(fw2, W2T, 512, 256, (b - 2723) * 256 + t);
    }
}

// ---------------------------------------------------------------------------
// 2) Consolidated border zero for all three padded buffers in ONE launch.
// ---------------------------------------------------------------------------
__device__ __forceinline__ void border_body(
    unsigned short* __restrict__ base, int Hp, int Wp, int CPG, int pad,
    int sampleStride, int nborder, int idx, int total)
{
    if (idx >= total) return;
    int c8 = idx % CPG;
    int t  = idx / CPG;
    int bi = t % nborder;
    int nl = t / nborder;

    int topN = pad * Wp;
    int y, x;
    if (bi < topN) {
        y = bi / Wp; x = bi - y * Wp;
    } else if (bi < 2 * topN) {
        int b2 = bi - topN;
        y = Hp - pad + b2 / Wp; x = b2 % Wp;
    } else {
        int mid = bi - 2 * topN;
        int rowlen = 2 * pad;
        y = pad + mid / rowlen;
        int r = mid % rowlen;
        x = r < pad ? r : Wp - pad + (r - pad);
    }
    uint4 z = make_uint4(0, 0, 0, 0);
    *reinterpret_cast<uint4*>(
        &base[((size_t)nl * sampleStride) +
              ((size_t)y * Wp + x) * (CPG * 8) + c8 * 8]) = z;
}

__global__ __launch_bounds__(256) void border3_k(
    unsigned short* __restrict__ bufA, unsigned short* __restrict__ bufC,
    int A_SS, int C_SS, int nb1, int nb2, int Bc)
{
    int b = blockIdx.x;
    int t = threadIdx.x;
    if (b < nb1) {
        border_body(bufA, 76, 76, 5, 2, A_SS, 592, b * 256 + t, Bc * 592 * 5);
    } else if (b < nb2) {
        border_body(bufC, 37, 37, 8, 1, C_SS, 144, (b - nb1) * 256 + t,
                    Bc * 144 * 8);
    } else {
        border_body(bufC + 87616, 19, 19, 16, 1, C_SS, 72,
                    (b - nb2) * 256 + t, Bc * 72 * 16);
    }
}

// ---------------------------------------------------------------------------
// 3) Encode, banded HWC. v5: 512 threads (8 waves) + unroll-2 room walk.
// ---------------------------------------------------------------------------
__global__ __launch_bounds__(512) void encode_k(
    const int* __restrict__ X, const unsigned long long* __restrict__ masks,
    const float* __restrict__ emb, unsigned short* __restrict__ G,
    int n0, int sampleStride)
{
    __shared__ float tile[4][72][33];
    __shared__ unsigned s_pos[RR];
    __shared__ unsigned long long s_mask[RR];
    __shared__ unsigned short s_list[320];
    __shared__ float s_emb[64 * 33];
    __shared__ int s_woff[8];
    __shared__ int s_cnt;

    const int nl = blockIdx.x, band = blockIdx.y;
    const int by = band * 4;
    const int n  = n0 + nl;
    const int tid = threadIdx.x;

    float* tf = &tile[0][0][0];
    for (int i = tid; i < 4 * 72 * 33; i += 512) tf[i] = 0.0f;

    const int2* Xp = reinterpret_cast<const int2*>(X);
    bool hot = false;
    if (tid < RR) {
        int2 pos = Xp[n * RR + tid];
        s_pos[tid]  = (unsigned)pos.x | ((unsigned)pos.y << 16);
        s_mask[tid] = masks[tid];
        hot = (pos.y <= by + 3) && (pos.y + 7 >= by);
    }
    unsigned long long bal = __ballot(hot);
    if ((tid & 63) == 0) s_woff[tid >> 6] = (int)__popcll(bal);
    __syncthreads();
    if (tid == 0) {
        int acc = 0;
        #pragma unroll
        for (int w = 0; w < 8; ++w) { int c = s_woff[w]; s_woff[w] = acc; acc += c; }
        s_cnt = acc;
    }
    __syncthreads();
    if (hot) {
        int w = tid >> 6, b = tid & 63;
        unsigned long long before = (b == 0) ? 0ull : (bal & ((1ull << b) - 1ull));
        s_list[s_woff[w] + (int)__popcll(before)] = (unsigned short)tid;
    }
    __syncthreads();

    const int lane = tid & 63;
    const int wvi  = tid >> 6;          // 0..7
    const int dx   = lane >> 3;         // 0..7
    const int c0   = (lane & 7) * 5;    // channels [c0, c0+5) ∩ [0,33)
    const int cnt  = s_cnt;

    for (int base = 0; base < cnt; base += 64) {
        int cn = cnt - base; if (cn > 64) cn = 64;
        for (int i = tid; i < cn * 33; i += 512) {
            int hi = i / 33, cc = i - hi * 33;
            int r = s_list[base + hi];
            s_emb[i] = (cc == 0) ? 1.0f : emb[r * EMB + cc - 1];
        }
        __syncthreads();

        int j = wvi;
        for (; j + 8 < cn; j += 16) {
            int rA = s_list[base + j];
            int rB = s_list[base + j + 8];
            unsigned pA = s_pos[rA], pB = s_pos[rB];
            unsigned long long mA = s_mask[rA] >> (dx * 8);
            unsigned long long mB = s_mask[rB] >> (dx * 8);
            int xA = (pA & 0xffff) + dx, yA = pA >> 16;
            int xB = (pB & 0xffff) + dx, yB = pB >> 16;
            float eA[5], eB[5];
            #pragma unroll
            for (int q = 0; q < 5; ++q) {
                eA[q] = (c0 + q < 33) ? s_emb[j * 33 + c0 + q] : 0.0f;
                eB[q] = (c0 + q < 33) ? s_emb[(j + 8) * 33 + c0 + q] : 0.0f;
            }
            #pragma unroll
            for (int dyb = 0; dyb < 4; ++dyb) {
                int dA = by + dyb - yA;
                if ((unsigned)dA < 8u && ((mA >> dA) & 1ull)) {
                    #pragma unroll
                    for (int q = 0; q < 5; ++q)
                        if (c0 + q < 33)
                            atomicAdd(&tile[dyb][xA][c0 + q], eA[q]);
                }
                int dB = by + dyb - yB;
                if ((unsigned)dB < 8u && ((mB >> dB) & 1ull)) {
                    #pragma unroll
                    for (int q = 0; q < 5; ++q)
                        if (c0 + q < 33)
                            atomicAdd(&tile[dyb][xB][c0 + q], eB[q]);
                }
            }
        }
        for (; j < cn; j += 8) {
            int r = s_list[base + j];
            unsigned pxy = s_pos[r];
            int px = pxy & 0xffff, py = pxy >> 16;
            unsigned long long mm = s_mask[r] >> (dx * 8);
            int x = px + dx;
            float ev[5];
            #pragma unroll
            for (int q = 0; q < 5; ++q)
                ev[q] = (c0 + q < 33) ? s_emb[j * 33 + c0 + q] : 0.0f;
            #pragma unroll
            for (int dyb = 0; dyb < 4; ++dyb) {
                int dyr = by + dyb - py;
                if ((unsigned)dyr < 8u && ((mm >> dyr) & 1ull)) {
                    #pragma unroll
                    for (int q = 0; q < 5; ++q)
                        if (c0 + q < 33)
                            atomicAdd(&tile[dyb][x][c0 + q], ev[q]);
                }
            }
        }
        __syncthreads();
    }
    __syncthreads();

    unsigned short* Gn = G + (size_t)nl * sampleStride;
    for (int i = tid; i < 4 * 72 * 10; i += 512) {
        int cc = i % 10;
        int t  = i / 10;
        int x  = t % 72;
        int dyb = t / 72;
        int c0w = cc * 4;
        unsigned short r[4];
        #pragma unroll
        for (int j = 0; j < 4; ++j)
            r[j] = (c0w + j < 33) ? f2bf(tile[dyb][x][c0w + j]) : 0;
        uint2 pk;
        pk.x = (unsigned)r[0] | ((unsigned)r[1] << 16);
        pk.y = (unsigned)r[2] | ((unsigned)r[3] << 16);
        *reinterpret_cast<uint2*>(
            &Gn[((size_t)(by + dyb + 2) * 76 + (x + 2)) * 40 + c0w]) = pk;
    }
}

// ---------------------------------------------------------------------------
// 4a) conv0: 24x16-spatial-tile implicit-GEMM, bf16 MFMA 16x16x32.
// ---------------------------------------------------------------------------
template<int KSTEPS>
__global__ __launch_bounds__(256, 3) void conv0_tile_k(
    const unsigned short* __restrict__ inP,   // [B][76][76][40] bf16
    const unsigned short* __restrict__ wPT,   // [KSTEPS][64][32] bf16
    const int* __restrict__ ktab,             // [KSTEPS*4] LDS offsets
    const float* __restrict__ bias,
    unsigned short* __restrict__ out,         // [B][5184][64] bf16
    int inSS, int outSS)
{
    constexpr int CL = 40;
    constexpr int LP = 72;
    __shared__ __align__(16) unsigned short slab[28 * 20 * CL];  // 44800 B
    __shared__ int s_kt[KSTEPS * 4];
    unsigned short* s_c = slab;

    const int tid = threadIdx.x;
    const int tl  = blockIdx.x;           // 0..14
    const int nl  = blockIdx.y;
    const int tyi = tl / 5, txi = tl % 5;
    const int y0 = tyi * 24;
    const int x0 = txi < 4 ? txi * 16 : 56;

    const int lane = tid & 63, wv = tid >> 6, frow = lane & 15, fq = lane >> 4;

    if (tid < KSTEPS * 4) s_kt[tid] = ktab[tid];

    const unsigned short* in_n = inP + (size_t)nl * inSS;
    {
        const uint4* src = reinterpret_cast<const uint4*>(in_n);
        uint4* dst = reinterpret_cast<uint4*>(slab);
        #pragma unroll
        for (int it = 0; it < 11; ++it) {
            int q = tid + it * 256;
            if (q < 2800) {
                int r = q / 100, c = q - r * 100;
                dst[q] = src[((y0 + r) * 76 + x0) * 5 + c];
            }
        }
    }

    int ldsb[6];
    #pragma unroll
    for (int mf = 0; mf < 6; ++mf)
        ldsb[mf] = ((mf * 4 + wv) * 20 + frow) * CL;

    const unsigned short* wbase = wPT + (size_t)frow * 32 + fq * 8;

    f32x4 acc[6][4];
    #pragma unroll
    for (int a = 0; a < 6; ++a)
        #pragma unroll
        for (int b = 0; b < 4; ++b) acc[a][b] = (f32x4){0.f, 0.f, 0.f, 0.f};

    __syncthreads();

    #pragma unroll 2
    for (int kb = 0; kb < KSTEPS; ++kb) {
        int go = s_kt[kb * 4 + fq];
        bf16x8 af[6];
        #pragma unroll
        for (int mf = 0; mf < 6; ++mf)
            af[mf] = *reinterpret_cast<const bf16x8*>(&slab[ldsb[mf] + go]);
        const unsigned short* wk = wbase + (size_t)kb * 64 * 32;
        #pragma unroll
        for (int ng = 0; ng < 4; ++ng) {
            bf16x8 bf = *reinterpret_cast<const bf16x8*>(wk + ng * 16 * 32);
            #pragma unroll
            for (int mf = 0; mf < 6; ++mf)
                acc[mf][ng] = __builtin_amdgcn_mfma_f32_16x16x32_bf16(
                    af[mf], bf, acc[mf][ng], 0, 0, 0);
        }
    }

    unsigned short* out_n = out + (size_t)nl * outSS;
    const int erow = tid >> 2, eseg = tid & 3;
    #pragma unroll
    for (int mf = 0; mf < 6; ++mf) {
        __syncthreads();
        #pragma unroll
        for (int ng = 0; ng < 4; ++ng) {
            float bv = bias[ng * 16 + frow];
            #pragma unroll
            for (int j = 0; j < 4; ++j)
                s_c[(wv * 16 + fq * 4 + j) * LP + ng * 16 + frow] =
                    f2bf(fmaxf(acc[mf][ng][j] + bv, 0.0f));
        }
        __syncthreads();
        {
            int ty = mf * 4 + (erow >> 4);
            int tx = erow & 15;
            int pos = (y0 + ty) * 72 + (x0 + tx);
            ushort8 v0 = *reinterpret_cast<const ushort8*>(
                &s_c[erow * LP + eseg * 16]);
            ushort8 v1 = *reinterpret_cast<const ushort8*>(
                &s_c[erow * LP + eseg * 16 + 8]);
            unsigned short* op = out_n + (size_t)pos * 64 + eseg * 16;
            *reinterpret_cast<ushort8*>(op) = v0;
            *reinterpret_cast<ushort8*>(op + 8) = v1;
        }
    }
}

// ---------------------------------------------------------------------------
// 4b) Generic row-slab implicit-GEMM conv (conv1/conv2), bf16 MFMA 16x16x32.
// ---------------------------------------------------------------------------
template<int MFRAG, int NG, int KH, int CPG, int CL, int SLAB, int KSTEPS>
__global__ __launch_bounds__(256, 2) void conv_mfma_k(
    const unsigned short* __restrict__ inP,
    const unsigned short* __restrict__ wPT,
    const int* __restrict__ ktab,
    const float* __restrict__ bias,
    unsigned short* __restrict__ out,
    int W, int Wp, int Mtot, int inSS, int outSS, int COUT)
{
    constexpr int Mblk = MFRAG * 64;
    constexpr int NOC  = NG * 16;
    constexpr int SEGS = NOC / 16;
    constexpr int LP   = NOC + 8;
    constexpr int CP   = CPG * 8;
    constexpr int SMEM = (SLAB * 2 > 64 * LP * 2) ? SLAB * 2 : 64 * LP * 2;
    __shared__ __align__(16) char smem[SMEM];
    __shared__ int s_kt[KSTEPS * 4];
    unsigned short* slab = reinterpret_cast<unsigned short*>(smem);
    unsigned short* s_c  = reinterpret_cast<unsigned short*>(smem);

    const int tid  = threadIdx.x;
    const int mb   = blockIdx.x;
    const int ocb  = blockIdx.y;
    const int nl   = blockIdx.z;
    const int lane = tid & 63;
    const int wv   = tid >> 6;
    const int frow = lane & 15;
    const int fq   = lane >> 4;

    if (tid < KSTEPS * 4) s_kt[tid] = ktab[tid];

    const int p0    = mb * Mblk;
    const int y0    = p0 / W;
    const int plast = (p0 + Mblk < Mtot ? p0 + Mblk : Mtot) - 1;
    const int rows  = plast / W - y0 + KH;

    const unsigned short* in_n =
        inP + (size_t)nl * inSS + (size_t)y0 * Wp * CP;
    const int nchunks = rows * Wp * CPG;
    for (int q = tid; q < nchunks; q += 256) {
        int pix = q / CPG, c8 = q - pix * CPG;
        uint4 v = reinterpret_cast<const uint4*>(in_n)[q];
        *reinterpret_cast<uint4*>(&slab[pix * CL + c8 * 8]) = v;
    }

    int ldsb[MFRAG];
    #pragma unroll
    for (int mf = 0; mf < MFRAG; ++mf) {
        int p  = p0 + mf * 64 + wv * 16 + frow;
        int pc = p < Mtot ? p : (Mtot - 1);
        int y  = pc / W;
        int x  = pc - y * W;
        ldsb[mf] = ((y - y0) * Wp + x) * CL;
    }
    const unsigned short* wbase =
        wPT + ((size_t)(ocb * NOC + frow)) * 32 + fq * 8;

    f32x4 acc[MFRAG][NG];
    #pragma unroll
    for (int mf = 0; mf < MFRAG; ++mf)
        #pragma unroll
        for (int ng = 0; ng < NG; ++ng)
            acc[mf][ng] = (f32x4){0.f, 0.f, 0.f, 0.f};

    __syncthreads();

    for (int kb = 0; kb < KSTEPS; ++kb) {
        int go = s_kt[kb * 4 + fq];
        bf16x8 af[MFRAG];
        #pragma unroll
        for (int mf = 0; mf < MFRAG; ++mf)
            af[mf] = *reinterpret_cast<const bf16x8*>(&slab[ldsb[mf] + go]);
        const unsigned short* wk = wbase + (size_t)kb * COUT * 32;
        #pragma unroll
        for (int ng = 0; ng < NG; ++ng) {
            bf16x8 bf = *reinterpret_cast<const bf16x8*>(wk + ng * 16 * 32);
            #pragma unroll
            for (int mf = 0; mf < MFRAG; ++mf)
                acc[mf][ng] = __builtin_amdgcn_mfma_f32_16x16x32_bf16(
                    af[mf], bf, acc[mf][ng], 0, 0, 0);
        }
    }

    unsigned short* out_n = out + (size_t)nl * outSS;
    #pragma unroll
    for (int mf = 0; mf < MFRAG; ++mf) {
        __syncthreads();
        #pragma unroll
        for (int ng = 0; ng < NG; ++ng) {
            float bv = bias[ocb * NOC + ng * 16 + frow];
            #pragma unroll
            for (int j = 0; j < 4; ++j)
                s_c[(wv * 16 + fq * 4 + j) * LP + ng * 16 + frow] =
                    f2bf(fmaxf(acc[mf][ng][j] + bv, 0.0f));
        }
        __syncthreads();
        for (int t = tid; t < 64 * SEGS; t += 256) {
            int row = t / SEGS, seg = t % SEGS;
            int p = p0 + mf * 64 + row;
            if (p < Mtot) {
                ushort8 v0 = *reinterpret_cast<const ushort8*>(
                    &s_c[row * LP + seg * 16]);
                ushort8 v1 = *reinterpret_cast<const ushort8*>(
                    &s_c[row * LP + seg * 16 + 8]);
                unsigned short* op =
                    out_n + (size_t)p * COUT + ocb * NOC + seg * 16;
                *reinterpret_cast<ushort8*>(op) = v0;
                *reinterpret_cast<ushort8*>(op + 8) = v1;
            }
        }
    }
}

// ---------------------------------------------------------------------------
// 5) MaxPool 3x3 s2 VALID, HWC, ushort8 (post-ReLU: u16 max).
// ---------------------------------------------------------------------------
__global__ __launch_bounds__(256) void pool_k(
    const unsigned short* __restrict__ in, unsigned short* __restrict__ out,
    int CG, int C, int W, int inSS,
    int HO, int WO, int Wpo, int outSS, int total)
{
    int idx = blockIdx.x * 256 + threadIdx.x;
    if (idx >= total) return;
    int cg = idx % CG;
    int t  = idx / CG;
    int x  = t % WO;
    t /= WO;
    int y  = t % HO;
    int nl = t / HO;

    const unsigned short* pin = in + (size_t)nl * inSS + cg * 8;
    ushort8 mx = {0,0,0,0,0,0,0,0};
    #pragma unroll
    for (int dy = 0; dy < 3; ++dy)
        #pragma unroll
        for (int dx = 0; dx < 3; ++dx) {
            ushort8 v = *reinterpret_cast<const ushort8*>(
                pin + ((size_t)(2 * y + dy) * W + (2 * x + dx)) * C);
            #pragma unroll
            for (int j = 0; j < 8; ++j) mx[j] = v[j] > mx[j] ? v[j] : mx[j];
        }
    *reinterpret_cast<ushort8*>(
        out + (size_t)nl * outSS +
        ((size_t)(y + 1) * Wpo + (x + 1)) * C + cg * 8) = mx;
}

// ---------------------------------------------------------------------------
// 6) Fused pool2 (3x3 s2 on [17][17][256]) + global average pool -> fp32
// ---------------------------------------------------------------------------
__global__ __launch_bounds__(512) void pool2gap_k(
    const unsigned short* __restrict__ in, float* __restrict__ out,
    int inSS, int n0)
{
    __shared__ float part[256];
    const int nl = blockIdx.x;
    const int c    = threadIdx.x & 255;
    const int half = threadIdx.x >> 8;
    const unsigned short* p = in + (size_t)nl * inSS + c;
    float s = 0.0f;
    for (int w = half * 32; w < half * 32 + 32; ++w) {
        int y = w >> 3, x = w & 7;
        unsigned short mx = 0;
        #pragma unroll
        for (int dy = 0; dy < 3; ++dy)
            #pragma unroll
            for (int dx = 0; dx < 3; ++dx) {
                unsigned short v = p[((size_t)(2*y+dy) * 17 + (2*x+dx)) * 256];
                mx = v > mx ? v : mx;
            }
        s += bf2f(mx);
    }
    if (half) part[c] = s;
    __syncthreads();
    if (!half) out[(size_t)(n0 + nl) * 256 + c] = (s + part[c]) * (1.0f / 64.0f);
}

// ---------------------------------------------------------------------------
// 7) Fused 3-layer FC head (256->512->256->512), one block per sample
// ---------------------------------------------------------------------------
__global__ __launch_bounds__(256) void fc_fused_k(
    const float* __restrict__ in,
    const float* __restrict__ w0T, const float* __restrict__ b0,
    const float* __restrict__ w1T, const float* __restrict__ b1,
    const float* __restrict__ w2T, const float* __restrict__ b2,
    float* __restrict__ out)
{
    __shared__ float s_in[256], s_h0[512], s_h1[256];
    const int n = blockIdx.x, t = threadIdx.x;
    s_in[t] = in[(size_t)n * 256 + t];
    __syncthreads();
    float a0 = 0.f, a1 = 0.f;
    for (int i = 0; i < 256; ++i) {
        float v = s_in[i];
        a0 += v * w0T[i * 512 + t];
        a1 += v * w0T[i * 512 + t + 256];
    }
    s_h0[t]       = fmaxf(a0 + b0[t], 0.0f);
    s_h0[t + 256] = fmaxf(a1 + b0[t + 256], 0.0f);
    __syncthreads();
    float h = 0.f;
    for (int i = 0; i < 512; ++i) h += s_h0[i] * w1T[i * 256 + t];
    s_h1[t] = fmaxf(h + b1[t], 0.0f);
    __syncthreads();
    a0 = 0.f; a1 = 0.f;
    for (int i = 0; i < 256; ++i) {
        float v = s_h1[i];
        a0 += v * w2T[i * 512 + t];
        a1 += v * w2T[i * 512 + t + 256];
    }
    out[(size_t)n * 512 + t]       = a0 + b2[t];
    out[(size_t)n * 512 + t + 256] = a1 + b2[t + 256];
}

// ---------------------------------------------------------------------------
// Launch. 10 kernels/call (was 19).
// ---------------------------------------------------------------------------
extern "C" void kernel_launch(void* const* d_in, const int* in_sizes, int n_in,
                              void* d_out, int out_size, void* d_ws, size_t ws_size,
                              hipStream_t stream)
{
    const int*   X   = (const int*)d_in[0];
    const int*   rm  = (const int*)d_in[1];
    const float* emb = (const float*)d_in[2];
    const float* cw0 = (const float*)d_in[3];
    const float* cb0 = (const float*)d_in[4];
    const float* cw1 = (const float*)d_in[5];
    const float* cb1 = (const float*)d_in[6];
    const float* cw2 = (const float*)d_in[7];
    const float* cb2 = (const float*)d_in[8];
    const float* fw0 = (const float*)d_in[9];
    const float* fb0 = (const float*)d_in[10];
    const float* fw1 = (const float*)d_in[11];
    const float* fb1 = (const float*)d_in[12];
    const float* fw2 = (const float*)d_in[13];
    const float* fb2 = (const float*)d_in[14];
    float* out = (float*)d_out;

    char* p = (char*)d_ws;
    auto alloc = [&](size_t bytes) -> char* {
        char* r = p; p += (bytes + 255) & ~(size_t)255; return r;
    };
    unsigned short* WP0 = (unsigned short*)alloc((size_t)32 * 64 * 32 * 2);
    unsigned short* WP1 = (unsigned short*)alloc((size_t)18 * 128 * 32 * 2);
    unsigned short* WP2 = (unsigned short*)alloc((size_t)36 * 256 * 32 * 2);
    int* KT0 = (int*)alloc(128 * 4);
    int* KT1 = (int*)alloc(72 * 4);
    int* KT2 = (int*)alloc(144 * 4);
    unsigned long long* MASKS = (unsigned long long*)alloc(RR * 8);
    float* W0T  = (float*)alloc((size_t)256 * 512 * 4);
    float* W1T  = (float*)alloc((size_t)512 * 256 * 4);
    float* W2T  = (float*)alloc((size_t)256 * 512 * 4);
    float* GAPB = (float*)alloc((size_t)NB * 256 * 4);
    size_t fixed_bytes = (size_t)(p - (char*)d_ws);

    const size_t A_FL = 231040, B_FL = 331776, C_FL = 133824;   // u16
    const size_t per_sample = (A_FL + B_FL + C_FL) * 2 + 768;
    int Bc = 128;
    while (Bc > 1 && fixed_bytes + (size_t)Bc * per_sample > ws_size) Bc >>= 1;

    unsigned short* bufA = (unsigned short*)alloc((size_t)Bc * A_FL * 2);
    unsigned short* bufC = (unsigned short*)alloc((size_t)Bc * C_FL * 2);
    unsigned short* bufB = (unsigned short*)alloc((size_t)Bc * B_FL * 2);

    // ---- consolidated prep (1 launch) ----
    prep_k<<<3235, 256, 0, stream>>>(
        rm, MASKS, cw0, WP0, cw1, WP1, cw2, WP2,
        KT0, KT1, KT2, fw0, W0T, fw1, W1T, fw2, W2T);

    // ---- chunked pipeline ----
    for (int n0 = 0; n0 < NB; n0 += Bc) {
        // consolidated border zero (1 launch for all 3 buffers)
        int nb1 = (Bc * 592 * 5 + 255) / 256;
        int nbc1 = (Bc * 144 * 8 + 255) / 256;
        int nbc2 = (Bc * 72 * 16 + 255) / 256;
        border3_k<<<nb1 + nbc1 + nbc2, 256, 0, stream>>>(
            bufA, bufC, (int)A_FL, (int)C_FL, nb1, nb1 + nbc1, Bc);

        // encode -> A (HWC G [76][76][40], interior +2)
        encode_k<<<dim3(Bc, 18), 512, 0, stream>>>(X, MASKS, emb, bufA, n0, (int)A_FL);

        // conv0: A -> B  (15 24x16 tiles/sample, COUT=64, 32 ksteps)
        conv0_tile_k<32><<<dim3(15, Bc), 256, 0, stream>>>(
            bufA, WP0, KT0, cb0, bufB, (int)A_FL, (int)B_FL);
        // pool0: B [72][72][64] -> C P0p [37][37][64] interior +1
        pool_k<<<(Bc * 35 * 35 * 8 + 255) / 256, 256, 0, stream>>>(
            bufB, bufC, 8, 64, 72, (int)B_FL,
            35, 35, 37, (int)C_FL, Bc * 35 * 35 * 8);

        // conv1: C -> A  (M=1225, Mblk=256 -> 5 mblocks, COUT=128)
        conv_mfma_k<4, 8, 3, 8, 72, 29304, 18><<<dim3(5, 1, Bc), 256, 0, stream>>>(
            bufC, WP1, KT1, cb1, bufA, 35, 37,
            1225, (int)C_FL, (int)A_FL, 128);
        // pool1: A [35][35][128] -> C+87616 P1p [19][19][128] interior +1
        pool_k<<<(Bc * 17 * 17 * 16 + 255) / 256, 256, 0, stream>>>(
            bufA, bufC + 87616, 16, 128, 35, (int)A_FL,
            17, 17, 19, (int)C_FL, Bc * 17 * 17 * 16);

        // conv2: C+87616 -> B  (M=289, Mblk=128 -> 3 mblocks, 2 oc-blocks)
        conv_mfma_k<2, 8, 3, 16, 136, 28424, 36><<<dim3(3, 2, Bc), 256, 0, stream>>>(
            bufC + 87616, WP2, KT2, cb2, bufB, 17, 19,
            289, (int)C_FL, (int)B_FL, 256);

        // fused pool2 + GAP: B [17][17][256] -> GAPB fp32
        pool2gap_k<<<Bc, 512, 0, stream>>>(bufB, GAPB, (int)B_FL, n0);
    }

    // fused FC head
    fc_fused_k<<<NB, 256, 0, stream>>>(GAPB, W0T, fb0, W1T, fb1, W2T, fb2, out);
}